// Round 18
// baseline (622.448 us; speedup 1.0000x reference)
//
#include <hip/hip_runtime.h>
#include <math.h>

#define NN 100000
#define EE 500000
#define NNB  1563            // 64-node blocks (qkvpb/node)
#define NFB  3125            // 32-node blocks (final)
#define NWB  25000           // walk: 4 nodes/block * 25000 = 100000 exactly

typedef __attribute__((ext_vector_type(8))) short short8;
typedef __attribute__((ext_vector_type(4))) float f32x4;
#define Z4 (f32x4){0,0,0,0}

#define C16(row, ch) (((row)<<4) + ((ch) ^ ((row)&7)))
#define E16(row, col) ((C16((row),(col)>>3)<<3) + ((col)&7))

__device__ __forceinline__ f32x4 mfma16(short8 a, short8 b, f32x4 c){
    return __builtin_amdgcn_mfma_f32_16x16x32_bf16(a, b, c, 0, 0, 0);
}
__device__ __forceinline__ short f2bf(float f){
    union { float f; unsigned u; } v; v.f = f;
    unsigned r = v.u + 0x7fffu + ((v.u >> 16) & 1u);
    return (short)(r >> 16);
}
__device__ __forceinline__ float bf2f(short s){
    union { unsigned u; float f; } v; v.u = ((unsigned)(unsigned short)s) << 16;
    return v.f;
}
__device__ __forceinline__ short8 bfrag(const short* __restrict__ W, int K, int ct, int ks, int lane){
    return *(const short8*)(W + (long)(ct*16 + (lane&15))*K + ks*32 + (lane>>4)*8);
}

// ---------------- prep: bf16 weights ----------------
__global__ __launch_bounds__(256) void prep_kernel(
    const float* __restrict__ q_w, const float* __restrict__ k_w,
    const float* __restrict__ v_w, const float* __restrict__ out_w,
    const float* __restrict__ sp_w, const float* __restrict__ amp_w,
    const float* __restrict__ ph_w, short* __restrict__ dst)
{
    int i = blockIdx.x*256 + threadIdx.x;   // 90112
    float v;
    if      (i < 16384) v = q_w[i];
    else if (i < 32768) v = k_w[i-16384];
    else if (i < 49152) v = v_w[i-32768];
    else if (i < 65536) v = out_w[i-49152];
    else if (i < 81920) v = sp_w[i-65536];
    else if (i < 86016) v = amp_w[i-81920];
    else                v = ph_w[i-86016];
    dst[i] = f2bf(v);
}

// ---------------- combined weights: Wc[kk] = meas_w[kk] @ ent_w_half ----------------
__global__ __launch_bounds__(256) void combine_kernel(
    const float* __restrict__ ent_w, const float* __restrict__ meas_w,
    short* __restrict__ wCi, short* __restrict__ wCj)
{
    const int b = blockIdx.x;          // 512
    const int kk = b >> 7, half = (b >> 6) & 1, ot = (b >> 3) & 7, ct = b & 7;
    const int tid = threadIdx.x;
    const int o = ot*16 + (tid >> 4);
    const int c = ct*32 + (tid & 15)*2;
    const float* mrow  = meas_w + ((long)(kk*128 + o) << 7);
    const float* wbase = ent_w + (long)(half*128)*256 + c;
    float a0 = 0.f, a1 = 0.f;
    #pragma unroll 8
    for (int k = 0; k < 128; k++){
        float m = mrow[k];
        float2 wv = *(const float2*)(wbase + (long)k*256);
        a0 = fmaf(m, wv.x, a0);
        a1 = fmaf(m, wv.y, a1);
    }
    short* dst = (half ? wCj : wCi) + (long)kk*32768 + o*256 + c;
    dst[0] = f2bf(a0); dst[1] = f2bf(a1);
}
__global__ __launch_bounds__(256) void combine_bias_kernel(
    const float* __restrict__ meas_w, const float* __restrict__ ent_b,
    const float* __restrict__ meas_b,
    float* __restrict__ bci, float* __restrict__ bcj)
{
    int id = blockIdx.x*256 + threadIdx.x;  // 1024
    int kk = id >> 8, half = (id >> 7) & 1, o = id & 127;
    const float* mrow = meas_w + ((long)(kk*128 + o) << 7);
    const float* eb = ent_b + half*128;
    float a = meas_b[kk*128 + o];
    #pragma unroll 8
    for (int k = 0; k < 128; k++) a = fmaf(mrow[k], eb[k], a);
    (half ? bcj : bci)[kk*128 + o] = a;
}

// ---------------- counting sort by tgt (src list only) ----------------
__global__ __launch_bounds__(256) void hist_kernel(const int* __restrict__ eidx, int* __restrict__ hist){
    int i = blockIdx.x*256 + threadIdx.x;
    if (i < EE) atomicAdd(&hist[eidx[EE+i]], 1);
}
__global__ __launch_bounds__(512) void scanA_kernel(const int* __restrict__ hist,
                                                    int* __restrict__ scanv, int* __restrict__ bsum){
    __shared__ int s[512];
    const int tid = threadIdx.x;
    const int i = blockIdx.x*512 + tid;
    int v = hist[i];
    s[tid] = v;
    __syncthreads();
    #pragma unroll
    for (int d=1; d<512; d<<=1){
        int t = (tid>=d) ? s[tid-d] : 0;
        __syncthreads();
        s[tid] += t;
        __syncthreads();
    }
    scanv[i] = s[tid] - v;
    if (tid==511) bsum[blockIdx.x] = s[511];
}
__global__ __launch_bounds__(256) void scanB_kernel(const int* __restrict__ bsum, int* __restrict__ boff){
    __shared__ int s[256];
    const int tid = threadIdx.x;
    int v = (tid<196) ? bsum[tid] : 0;
    s[tid] = v;
    __syncthreads();
    #pragma unroll
    for (int d=1; d<256; d<<=1){
        int t = (tid>=d) ? s[tid-d] : 0;
        __syncthreads();
        s[tid] += t;
        __syncthreads();
    }
    if (tid<196) boff[tid] = s[tid] - v;
}
__global__ __launch_bounds__(256) void scatter_kernel(const int* __restrict__ eidx,
    const int* __restrict__ scanv, const int* __restrict__ boff, int* __restrict__ cnt,
    int* __restrict__ sSrc)
{
    int i = blockIdx.x*256 + threadIdx.x;
    if (i >= EE) return;
    int t = eidx[EE+i], sv = eidx[i];
    int r = atomicAdd(&cnt[t], 1);
    int pos = scanv[t] + boff[t>>9] + r;
    sSrc[pos] = sv;
}

// ---------------- Stage 1: node prep (proven) ----------------
__global__ __launch_bounds__(512) void node_kernel(
    const float* __restrict__ x,
    const short* __restrict__ wSP, const float* __restrict__ sp_b,
    const float* __restrict__ ln1_g, const float* __restrict__ ln1_b,
    const float* __restrict__ pg,
    const short* __restrict__ wA, const float* __restrict__ amp_b,
    const short* __restrict__ wP, const float* __restrict__ ph_b,
    short* __restrict__ qfb)
{
    __shared__ short xb[64*128];
    __shared__ float yb[64*132];
    __shared__ short qsb[64*128];
    __shared__ float pgs[64];

    const int tid = threadIdx.x;
    const int lane = tid & 63;
    const int w    = tid >> 6;
    const int l15  = lane & 15;
    const int lj   = (lane >> 4) << 2;
    const int n0   = blockIdx.x * 64;

    if (tid < 64){
        float s = 0.f;
        #pragma unroll
        for (int r=0;r<8;r++) s += pg[r*64 + tid];
        pgs[tid] = s;
    }
    for (int t = tid; t < 1024; t += 512){
        int e = t >> 4, c8 = t & 15;
        int n = n0 + e; if (n >= NN) n = NN-1;
        const float4* xg = (const float4*)(x + (long)n*128 + c8*8);
        float4 a = xg[0], b = xg[1];
        short8 sv;
        sv[0]=f2bf(a.x); sv[1]=f2bf(a.y); sv[2]=f2bf(a.z); sv[3]=f2bf(a.w);
        sv[4]=f2bf(b.x); sv[5]=f2bf(b.y); sv[6]=f2bf(b.z); sv[7]=f2bf(b.w);
        ((short8*)xb)[C16(e, c8)] = sv;
    }
    __syncthreads();

    const short8* xbv = (const short8*)xb;
    const int col = (w<<4) + l15;

    {
        f32x4 acc[4];
        #pragma unroll
        for (int r=0;r<4;r++) acc[r]=Z4;
        #pragma unroll
        for (int ks=0; ks<4; ks++){
            short8 bw = bfrag(wSP,128,w,ks,lane);
            #pragma unroll
            for (int r=0;r<4;r++){
                int row = r*16+l15;
                acc[r] = mfma16(xbv[(row<<4) + (((ks<<2)+(lane>>4)) ^ (row&7))], bw, acc[r]);
            }
        }
        float bias = sp_b[col];
        #pragma unroll
        for (int r=0;r<4;r++){
            #pragma unroll
            for (int j=0;j<4;j++)
                yb[(r*16+lj+j)*132 + col] = acc[r][j] + bias;
        }
    }
    __syncthreads();

    {
        const int row = tid >> 3, cs = tid & 7;
        float v[16];
        float s = 0.f, sq = 0.f;
        #pragma unroll
        for (int i=0;i<16;i++){
            v[i] = yb[row*132 + cs*16 + i];
            s += v[i]; sq += v[i]*v[i];
        }
        #pragma unroll
        for (int m=1;m<8;m<<=1){ s += __shfl_xor(s,m); sq += __shfl_xor(sq,m); }
        float mean = s*(1.0f/128.0f);
        float rstd = rsqrtf(sq*(1.0f/128.0f) - mean*mean + 1e-5f);
        short8 s0, s1;
        #pragma unroll
        for (int i=0;i<16;i++){
            int c = cs*16 + i;
            float q = tanhf((v[i]-mean)*rstd*ln1_g[c] + ln1_b[c]);
            if (i<8) s0[i] = f2bf(q); else s1[i-8] = f2bf(q);
        }
        ((short8*)qsb)[C16(row, cs*2  )] = s0;
        ((short8*)qsb)[C16(row, cs*2+1)] = s1;
    }
    __syncthreads();

    {
        const short8* qv = (const short8*)qsb;
        const int isPh = w >> 2;
        const int ct   = w & 3;
        f32x4 a4[4];
        #pragma unroll
        for (int r=0;r<4;r++) a4[r]=Z4;
        #pragma unroll
        for (int ks=0; ks<2; ks++){
            short8 bw = bfrag(isPh ? wP : wA, 64, ct, ks, lane);
            #pragma unroll
            for (int r=0;r<4;r++){
                int row = r*16+l15;
                int ch = isPh*8 + (ks<<2)+(lane>>4);
                a4[r] = mfma16(qv[(row<<4) + (ch ^ (row&7))], bw, a4[r]);
            }
        }
        const int oc = ct*16 + l15;
        float bs = isPh ? ph_b[oc] : amp_b[oc];
        #pragma unroll
        for (int r=0;r<4;r++){
            #pragma unroll
            for (int j=0;j<4;j++){
                float vv = a4[r][j] + bs;
                float ov = isPh ? tanhf(vv)*3.14159265358979323846f
                                : 1.0f/(1.0f+expf(-vv));
                yb[(r*16+lj+j)*132 + isPh*64 + oc] = ov;
            }
        }
    }
    __syncthreads();

    {
        const int row = tid >> 3, cs = tid & 7;
        const int n = n0 + row;
        short8 outc, outs;
        #pragma unroll
        for (int i=0;i<8;i++){
            int c = cs*8 + i;
            float amp  = yb[row*132 + c];
            float ph   = yb[row*132 + 64 + c];
            float real = bf2f(qsb[E16(row, c)]);
            float ang  = ph + real*pgs[c];
            outc[i] = f2bf(amp * cosf(ang));
            outs[i] = f2bf(amp * sinf(ang));
        }
        if (n < NN){
            *(short8*)(qfb + (long)n*128 + cs*8)      = outc;
            *(short8*)(qfb + (long)n*128 + 64 + cs*8) = outs;
        }
    }
}

// ---------------- node GEMMs -> packed knvp[n][512] = kn | vn | pb | qn ----------------
__global__ __launch_bounds__(512) void qkvpb_kernel(
    const short* __restrict__ qfb,
    const short* __restrict__ wK, const float* __restrict__ k_b,
    const short* __restrict__ wV, const float* __restrict__ v_b,
    const short* __restrict__ wQ, const float* __restrict__ q_b,
    const short* __restrict__ wCi, const short* __restrict__ wCj,
    short* __restrict__ knvp)
{
    __shared__ short a1[64*128];
    const int tid=threadIdx.x, lane=tid&63, w=tid>>6;
    const int l15=lane&15, lh=lane>>4, lj=lh<<2;
    const long n0=(long)blockIdx.x*64;
    for (int t=tid;t<1024;t+=512){
        int e=t>>4,c8=t&15;
        ((short8*)a1)[C16(e,c8)] = ((const short8*)(qfb+(n0+e)*128))[c8];
    }
    __syncthreads();
    short8 A[4][4];
    #pragma unroll
    for (int rt=0;rt<4;rt++)
        #pragma unroll
        for (int ks=0;ks<4;ks++)
            A[rt][ks] = ((const short8*)a1)[C16(rt*16+l15, (ks<<2)+lh)];
    const int col = (w<<4)+l15;

    // K
    {
        f32x4 acc[4];
        #pragma unroll
        for (int rt=0;rt<4;rt++) acc[rt]=Z4;
        #pragma unroll
        for (int ks=0;ks<4;ks++){
            short8 b = *(const short8*)(wK + (long)col*128 + ks*32 + lh*8);
            #pragma unroll
            for (int rt=0;rt<4;rt++) acc[rt]=mfma16(A[rt][ks],b,acc[rt]);
        }
        float bias=k_b[col];
        #pragma unroll
        for (int rt=0;rt<4;rt++)
            #pragma unroll
            for (int j=0;j<4;j++)
                knvp[(n0+rt*16+lj+j)*512 + col]=f2bf(acc[rt][j]+bias);
    }
    // V
    {
        f32x4 acc[4];
        #pragma unroll
        for (int rt=0;rt<4;rt++) acc[rt]=Z4;
        #pragma unroll
        for (int ks=0;ks<4;ks++){
            short8 b = *(const short8*)(wV + (long)col*128 + ks*32 + lh*8);
            #pragma unroll
            for (int rt=0;rt<4;rt++) acc[rt]=mfma16(A[rt][ks],b,acc[rt]);
        }
        float bias=v_b[col];
        #pragma unroll
        for (int rt=0;rt<4;rt++)
            #pragma unroll
            for (int j=0;j<4;j++)
                knvp[(n0+rt*16+lj+j)*512 + 128 + col]=f2bf(acc[rt][j]+bias);
    }
    // Q -> slot 384 (walk consumes it, then overwrites the slot with S)
    {
        f32x4 acc[4];
        #pragma unroll
        for (int rt=0;rt<4;rt++) acc[rt]=Z4;
        #pragma unroll
        for (int ks=0;ks<4;ks++){
            short8 b = *(const short8*)(wQ + (long)col*128 + ks*32 + lh*8);
            #pragma unroll
            for (int rt=0;rt<4;rt++) acc[rt]=mfma16(A[rt][ks],b,acc[rt]);
        }
        float bias=q_b[col];
        #pragma unroll
        for (int rt=0;rt<4;rt++)
            #pragma unroll
            for (int j=0;j<4;j++)
                knvp[(n0+rt*16+lj+j)*512 + 384 + col]=f2bf(acc[rt][j]+bias);
    }
    // PB = sum_kk Bi ⊙ Bj  (b-slices of wCi/wCj: cols 128:256)
    {
        f32x4 pbacc[4];
        #pragma unroll
        for (int rt=0;rt<4;rt++) pbacc[rt]=Z4;
        #pragma unroll 1
        for (int kk=0;kk<4;kk++){
            short8 bi[4], bj[4];
            #pragma unroll
            for (int ks=0;ks<4;ks++){
                bi[ks] = *(const short8*)(wCi + (long)kk*32768 + (long)col*256 + 128 + ks*32 + lh*8);
                bj[ks] = *(const short8*)(wCj + (long)kk*32768 + (long)col*256 + 128 + ks*32 + lh*8);
            }
            #pragma unroll
            for (int rt=0;rt<4;rt++){
                f32x4 ai=Z4, aj=Z4;
                #pragma unroll
                for (int ks=0;ks<4;ks++){
                    ai = mfma16(A[rt][ks], bi[ks], ai);
                    aj = mfma16(A[rt][ks], bj[ks], aj);
                }
                #pragma unroll
                for (int j=0;j<4;j++) pbacc[rt][j] += ai[j]*aj[j];
            }
        }
        #pragma unroll
        for (int rt=0;rt<4;rt++)
            #pragma unroll
            for (int j=0;j<4;j++)
                knvp[(n0+rt*16+lj+j)*512 + 256 + col]=f2bf(pbacc[rt][j]);
    }
}

// ---------------- walk: 1 node/wave, ZERO LDS, max occupancy ----------------
// Outputs: AQM|PB bf16 packed into d_out (aqmpb[n*256 + c] / [n*256+128+c]); S bf16 into knvp slot 384.
__global__ __launch_bounds__(256) void walk_kernel(
    const short* __restrict__ qfb, short* __restrict__ knvp,
    const int* __restrict__ sSrc, const int* __restrict__ hist,
    const int* __restrict__ scanv, const int* __restrict__ boff,
    short* __restrict__ aqmpb)
{
    const int tid=threadIdx.x, lane=tid&63, w=tid>>6;
    const int n = blockIdx.x*4 + w;          // 100000 = 25000*4 exact
    const int g = lane >> 4;                 // edge slot 0..3
    const int cl = (lane & 15) * 8;          // cols cl..cl+7
    const float sc = 0.17677669529663688f;

    const int rp0 = scanv[n] + boff[n>>9];
    const int dg  = hist[n];

    float q8[8];
    {
        short8 qv = *(const short8*)(knvp + (long)n*512 + 384 + cl);
        #pragma unroll
        for (int i=0;i<8;i++) q8[i]=bf2f(qv[i]);
    }
    float aq[8], s[8], p[8];
    #pragma unroll
    for (int i=0;i<8;i++){ aq[i]=0.f; s[i]=0.f; p[i]=0.f; }

    // prologue: group 0
    bool vCur = (g < dg);
    int  sCur = vCur ? sSrc[rp0+g] : 0;
    const short* bCur = knvp + (long)sCur*512;
    short8 k8 = *(const short8*)(bCur + cl);
    short8 v8 = *(const short8*)(bCur + 128 + cl);
    short8 p8 = *(const short8*)(bCur + 256 + cl);
    short8 f8 = *(const short8*)(qfb + (long)sCur*128 + cl);

    #pragma unroll 1
    for (int e=0; e<dg; e+=4){
        const int en = e + 4 + g;
        const bool vN = (en < dg);
        const int  sN = vN ? sSrc[rp0+en] : 0;
        const short* bN = knvp + (long)sN*512;
        short8 kN = *(const short8*)(bN + cl);
        short8 vN8= *(const short8*)(bN + 128 + cl);
        short8 pN = *(const short8*)(bN + 256 + cl);
        short8 fN = *(const short8*)(qfb + (long)sN*128 + cl);

        float d = 0.f;
        #pragma unroll
        for (int i=0;i<8;i++) d += q8[i]*bf2f(k8[i]);
        d += __shfl_xor(d,1); d += __shfl_xor(d,2);      // head sum
        d *= sc;
        float mx = fmaxf(d, __shfl_xor(d,4));
        mx = fmaxf(mx, __shfl_xor(mx,8));                 // max over heads
        float eh = expf(d - mx);
        float den = eh;
        den += __shfl_xor(den,4); den += __shfl_xor(den,8);
        float wgt = vCur ? (eh/den) : 0.f;
        float mv  = vCur ? 1.f : 0.f;
        #pragma unroll
        for (int i=0;i<8;i++){
            aq[i] += wgt * bf2f(v8[i]);
            s[i]  += mv  * bf2f(f8[i]);
            p[i]  += mv  * bf2f(p8[i]);
        }
        k8=kN; v8=vN8; p8=pN; f8=fN; vCur=vN;
    }
    // combine the 4 edge-slot groups
    #pragma unroll
    for (int i=0;i<8;i++){
        aq[i] += __shfl_xor(aq[i],16); aq[i] += __shfl_xor(aq[i],32);
        s[i]  += __shfl_xor(s[i],16);  s[i]  += __shfl_xor(s[i],32);
        p[i]  += __shfl_xor(p[i],16);  p[i]  += __shfl_xor(p[i],32);
    }
    if (lane < 16){
        short8 av, pv, sv;
        #pragma unroll
        for (int i=0;i<8;i++){ av[i]=f2bf(aq[i]); pv[i]=f2bf(p[i]); sv[i]=f2bf(s[i]); }
        *(short8*)(aqmpb + (long)n*256 + cl)       = av;
        *(short8*)(aqmpb + (long)n*256 + 128 + cl) = pv;
        *(short8*)(knvp  + (long)n*512 + 384 + cl) = sv;   // S over dead qn slot
    }
}

// ---------------- final: GEMM-only; 32 nodes/block, 256 thr, 32.9 KB LDS ----------------
__global__ __launch_bounds__(256) void final_kernel(
    const short* __restrict__ qfb, const short* __restrict__ knvp,
    const int* __restrict__ hist,
    const short* __restrict__ wCi, const short* __restrict__ wCj,
    const float* __restrict__ bci, const float* __restrict__ bcj,
    const short* __restrict__ wO, const float* __restrict__ out_b,
    const float* __restrict__ g2, const float* __restrict__ b2,
    const short* __restrict__ aqmpb, float* __restrict__ outp)
{
    __shared__ __align__(16) char smem[32768];
    __shared__ int degs[32];
    short* a1  = (short*)smem;            // 8 KB qf tile (swz); msgb overlay
    short* Sbf = (short*)(smem + 8192);   // 8 KB S bf16 (swz), from knvp slot 384
    float* yb  = (float*)(smem + 16384);  // 16 KB OUT result

    const int tid=threadIdx.x, lane=tid&63, w=tid>>6;
    const int l15=lane&15, lh=lane>>4, lj=lh<<2;
    const long n0=(long)blockIdx.x*32;

    if (tid < 32) degs[tid] = hist[n0+tid];
    for (int t=tid;t<512;t+=256){
        int e=t>>4,c8=t&15;
        ((short8*)a1)[C16(e,c8)]  = ((const short8*)(qfb+(n0+e)*128))[c8];
        ((short8*)Sbf)[C16(e,c8)] = *(const short8*)(knvp + (n0+e)*512 + 384 + c8*8);
    }
    __syncthreads();                                       // B1

    short8 FQ[2][4], FS[2][4];
    #pragma unroll
    for (int rt=0;rt<2;rt++)
        #pragma unroll
        for (int ks=0;ks<4;ks++){
            FQ[rt][ks] = ((const short8*)a1)[C16(rt*16+l15,(ks<<2)+lh)];
            FS[rt][ks] = ((const short8*)Sbf)[C16(rt*16+l15,(ks<<2)+lh)];
        }
    __syncthreads();                                       // B2 (frag reads done before msgb overlay)

    // ---- cross GEMMs ----
    f32x4 tt[2][2], cr[2][2];
    #pragma unroll
    for (int ci=0;ci<2;ci++){ tt[ci][0]=Z4; tt[ci][1]=Z4; cr[ci][0]=Z4; cr[ci][1]=Z4; }
    #pragma unroll 1
    for (int kk=0;kk<4;kk++){
        #pragma unroll
        for (int ci=0;ci<2;ci++){
            const int col = (2*w+ci)*16 + l15;
            const long wbase = (long)kk*32768 + (long)col*256;
            short8 Bia[4],Bja[4],Bib[4],Bjb[4];
            #pragma unroll
            for (int ks=0;ks<4;ks++){
                Bia[ks] = *(const short8*)(wCi + wbase + ks*32 + lh*8);
                Bja[ks] = *(const short8*)(wCj + wbase + ks*32 + lh*8);
                Bib[ks] = *(const short8*)(wCi + wbase + 128 + ks*32 + lh*8);
                Bjb[ks] = *(const short8*)(wCj + wbase + 128 + ks*32 + lh*8);
            }
            f32x4 ai[2],aj[2],sbi[2],sbj[2];
            #pragma unroll
            for (int rt=0;rt<2;rt++){ ai[rt]=Z4; aj[rt]=Z4; sbi[rt]=Z4; sbj[rt]=Z4; }
            #pragma unroll
            for (int ks=0;ks<4;ks++){
                #pragma unroll
                for (int rt=0;rt<2;rt++){
                    ai[rt]  = mfma16(FQ[rt][ks], Bia[ks], ai[rt]);
                    aj[rt]  = mfma16(FQ[rt][ks], Bja[ks], aj[rt]);
                    sbi[rt] = mfma16(FS[rt][ks], Bib[ks], sbi[rt]);
                    sbj[rt] = mfma16(FS[rt][ks], Bjb[ks], sbj[rt]);
                }
            }
            float ci_ = bci[kk*128+col], cj_ = bcj[kk*128+col];
            #pragma unroll
            for (int rt=0;rt<2;rt++){
                #pragma unroll
                for (int j=0;j<4;j++){
                    float AI = ai[rt][j]+ci_, AJ = aj[rt][j]+cj_;
                    tt[ci][rt][j] += AI*AJ;
                    cr[ci][rt][j] += AI*sbj[rt][j] + sbi[rt][j]*AJ;
                }
            }
        }
    }
    // ---- msum (AQM/PB read from global bf16), write msgb over a1 ----
    short* msgb = a1;
    #pragma unroll
    for (int ci=0;ci<2;ci++){
        const int col = (2*w+ci)*16 + l15;
        #pragma unroll
        for (int rt=0;rt<2;rt++){
            #pragma unroll
            for (int j=0;j<4;j++){
                int row = rt*16+lj+j;
                long nb = (n0+row)*256;
                float ms = bf2f(aqmpb[nb + col])
                         + 0.25f*((float)degs[row]*tt[ci][rt][j] + cr[ci][rt][j]
                                  + bf2f(aqmpb[nb + 128 + col]));
                msgb[(C16(row, col>>3)<<3) + (col&7)] = f2bf(ms);
            }
        }
    }
    __syncthreads();                                       // B3

    // ---- OUT GEMM -> yb ----
    short8 FM[2][4];
    #pragma unroll
    for (int rt=0;rt<2;rt++)
        #pragma unroll
        for (int ks=0;ks<4;ks++)
            FM[rt][ks] = ((const short8*)msgb)[C16(rt*16+l15,(ks<<2)+lh)];
    #pragma unroll
    for (int ci=0; ci<2; ci++){
        const int col = (2*w+ci)*16 + l15;
        f32x4 ao[2]; ao[0]=Z4; ao[1]=Z4;
        #pragma unroll
        for (int ks=0;ks<4;ks++){
            short8 b = *(const short8*)(wO + (long)col*128 + ks*32 + lh*8);
            ao[0]=mfma16(FM[0][ks],b,ao[0]);
            ao[1]=mfma16(FM[1][ks],b,ao[1]);
        }
        float ob = out_b[col];
        #pragma unroll
        for (int rt=0;rt<2;rt++)
            #pragma unroll
            for (int j=0;j<4;j++){
                int row = rt*16+lj+j;
                yb[(row<<7) + (col ^ (row&31))] = ao[rt][j] + (float)degs[row]*ob;
            }
    }
    __syncthreads();                                       // B4

    // ---- LN + exact gelu ----
    {
        const int row=tid>>3, cs=tid&7;
        const long n=n0+row;
        float v[16]; float sum=0.f, sq=0.f;
        #pragma unroll
        for (int i=0;i<16;i++){
            v[i]=yb[(row<<7)+((cs*16+i)^(row&31))];
            sum+=v[i]; sq+=v[i]*v[i];
        }
        #pragma unroll
        for (int m=1;m<8;m<<=1){ sum+=__shfl_xor(sum,m); sq+=__shfl_xor(sq,m); }
        float mean=sum*(1.0f/128.0f);
        float rstd=rsqrtf(sq*(1.0f/128.0f)-mean*mean+1e-5f);
        float o[16];
        #pragma unroll
        for (int i=0;i<16;i++){
            int c=cs*16+i;
            float y=(v[i]-mean)*rstd*g2[c]+b2[c];
            o[i]=0.5f*y*(1.0f+erff(y*0.70710678118f));
        }
        float* dst = outp + n*128 + cs*16;
        #pragma unroll
        for (int i=0;i<4;i++)
            ((float4*)dst)[i] = (float4){o[i*4],o[i*4+1],o[i*4+2],o[i*4+3]};
    }
}

extern "C" void kernel_launch(void* const* d_in, const int* in_sizes, int n_in,
                              void* d_out, int out_size, void* d_ws, size_t ws_size,
                              hipStream_t stream)
{
    const float* x      = (const float*)d_in[0];
    const int*   eidx   = (const int*)  d_in[1];
    const float* sp_w   = (const float*)d_in[2];
    const float* sp_b   = (const float*)d_in[3];
    const float* ln1_g  = (const float*)d_in[4];
    const float* ln1_b  = (const float*)d_in[5];
    const float* pg     = (const float*)d_in[6];
    const float* amp_w  = (const float*)d_in[7];
    const float* amp_b  = (const float*)d_in[8];
    const float* ph_w   = (const float*)d_in[9];
    const float* ph_b   = (const float*)d_in[10];
    const float* ent_w  = (const float*)d_in[11];
    const float* ent_b  = (const float*)d_in[12];
    const float* q_w    = (const float*)d_in[13];
    const float* q_b    = (const float*)d_in[14];
    const float* k_w    = (const float*)d_in[15];
    const float* k_b    = (const float*)d_in[16];
    const float* v_w    = (const float*)d_in[17];
    const float* v_b    = (const float*)d_in[18];
    const float* meas_w = (const float*)d_in[19];
    const float* meas_b = (const float*)d_in[20];
    const float* out_w  = (const float*)d_in[21];
    const float* out_b  = (const float*)d_in[22];
    const float* ln2_g  = (const float*)d_in[23];
    const float* ln2_b  = (const float*)d_in[24];

    char* wsb = (char*)d_ws;
    short* qfb  = (short*)(wsb + 0);               //  25,608,192
    short* knvp = (short*)(wsb + 25608192);        // 102,432,768
    short* wAll = (short*)(wsb + 128040960);       //     180,224
    short* wCi  = (short*)(wsb + 128221184);       //     262,144
    short* wCj  = (short*)(wsb + 128483328);       //     262,144
    float* bci  = (float*)(wsb + 128745472);       //       2,048
    float* bcj  = (float*)(wsb + 128747520);       //       2,048
    int* hist   = (int*)(wsb + 128749568);         //     401,408
    int* cnt    = (int*)(wsb + 129150976);         //     401,408
    int* scanv  = (int*)(wsb + 129552384);         //     401,408
    int* bsum   = (int*)(wsb + 129953792);         //       1,024
    int* boff   = (int*)(wsb + 129954816);         //       1,024
    int* sSrc   = (int*)(wsb + 129955840);         //   2,000,000 -> 131,955,840 total

    if (ws_size < 132000000ull) return;            // diagnostic guard

    short* wQ  = wAll;
    short* wK  = wAll + 16384;
    short* wV  = wAll + 32768;
    short* wO  = wAll + 49152;
    short* wSP = wAll + 65536;
    short* wA  = wAll + 81920;
    short* wP  = wAll + 86016;

    short* aqmpb = (short*)d_out;                  // bf16 AQM|PB packed in d_out

    hipMemsetAsync(hist, 0, 401408, stream);
    hipMemsetAsync(cnt,  0, 401408, stream);

    prep_kernel<<<352, 256, 0, stream>>>(q_w, k_w, v_w, out_w, sp_w, amp_w, ph_w, wAll);
    combine_kernel<<<512, 256, 0, stream>>>(ent_w, meas_w, wCi, wCj);
    combine_bias_kernel<<<4, 256, 0, stream>>>(meas_w, ent_b, meas_b, bci, bcj);
    node_kernel<<<NNB, 512, 0, stream>>>(x, wSP, sp_b, ln1_g, ln1_b, pg,
                                         wA, amp_b, wP, ph_b, qfb);
    hist_kernel<<<(EE+255)/256, 256, 0, stream>>>(eidx, hist);
    scanA_kernel<<<196, 512, 0, stream>>>(hist, scanv, bsum);
    scanB_kernel<<<1, 256, 0, stream>>>(bsum, boff);
    scatter_kernel<<<(EE+255)/256, 256, 0, stream>>>(eidx, scanv, boff, cnt, sSrc);
    qkvpb_kernel<<<NNB, 512, 0, stream>>>(qfb, wK, k_b, wV, v_b, wQ, q_b,
                                          wCi, wCj, knvp);
    walk_kernel<<<NWB, 256, 0, stream>>>(qfb, knvp, sSrc, hist, scanv, boff, aqmpb);
    final_kernel<<<NFB, 256, 0, stream>>>(qfb, knvp, hist,
                                          wCi, wCj, bci, bcj, wO, out_b,
                                          ln2_g, ln2_b, aqmpb, (float*)d_out);
}

// Round 19
// 621.217 us; speedup vs baseline: 1.0020x; 1.0020x over previous
//
#include <hip/hip_runtime.h>
#include <math.h>

#define NN 100000
#define EE 500000
#define NNB  1563            // 64-node blocks (qkvpb/node)
#define NFB  3125            // 32-node blocks (final)
#define NWB  25000           // walk: 4 nodes/block * 25000 = 100000 exactly

typedef __attribute__((ext_vector_type(8))) short short8;
typedef __attribute__((ext_vector_type(4))) float f32x4;
#define Z4 (f32x4){0,0,0,0}

#define C16(row, ch) (((row)<<4) + ((ch) ^ ((row)&7)))
#define E16(row, col) ((C16((row),(col)>>3)<<3) + ((col)&7))

__device__ __forceinline__ f32x4 mfma16(short8 a, short8 b, f32x4 c){
    return __builtin_amdgcn_mfma_f32_16x16x32_bf16(a, b, c, 0, 0, 0);
}
__device__ __forceinline__ short f2bf(float f){
    union { float f; unsigned u; } v; v.f = f;
    unsigned r = v.u + 0x7fffu + ((v.u >> 16) & 1u);
    return (short)(r >> 16);
}
__device__ __forceinline__ float bf2f(short s){
    union { unsigned u; float f; } v; v.u = ((unsigned)(unsigned short)s) << 16;
    return v.f;
}
__device__ __forceinline__ short8 bfrag(const short* __restrict__ W, int K, int ct, int ks, int lane){
    return *(const short8*)(W + (long)(ct*16 + (lane&15))*K + ks*32 + (lane>>4)*8);
}

// ---------------- prep: bf16 weights ----------------
__global__ __launch_bounds__(256) void prep_kernel(
    const float* __restrict__ q_w, const float* __restrict__ k_w,
    const float* __restrict__ v_w, const float* __restrict__ out_w,
    const float* __restrict__ sp_w, const float* __restrict__ amp_w,
    const float* __restrict__ ph_w, short* __restrict__ dst)
{
    int i = blockIdx.x*256 + threadIdx.x;   // 90112
    float v;
    if      (i < 16384) v = q_w[i];
    else if (i < 32768) v = k_w[i-16384];
    else if (i < 49152) v = v_w[i-32768];
    else if (i < 65536) v = out_w[i-49152];
    else if (i < 81920) v = sp_w[i-65536];
    else if (i < 86016) v = amp_w[i-81920];
    else                v = ph_w[i-86016];
    dst[i] = f2bf(v);
}

// ---------------- combined weights: Wc[kk] = meas_w[kk] @ ent_w_half ----------------
__global__ __launch_bounds__(256) void combine_kernel(
    const float* __restrict__ ent_w, const float* __restrict__ meas_w,
    short* __restrict__ wCi, short* __restrict__ wCj)
{
    const int b = blockIdx.x;          // 512
    const int kk = b >> 7, half = (b >> 6) & 1, ot = (b >> 3) & 7, ct = b & 7;
    const int tid = threadIdx.x;
    const int o = ot*16 + (tid >> 4);
    const int c = ct*32 + (tid & 15)*2;
    const float* mrow  = meas_w + ((long)(kk*128 + o) << 7);
    const float* wbase = ent_w + (long)(half*128)*256 + c;
    float a0 = 0.f, a1 = 0.f;
    #pragma unroll 8
    for (int k = 0; k < 128; k++){
        float m = mrow[k];
        float2 wv = *(const float2*)(wbase + (long)k*256);
        a0 = fmaf(m, wv.x, a0);
        a1 = fmaf(m, wv.y, a1);
    }
    short* dst = (half ? wCj : wCi) + (long)kk*32768 + o*256 + c;
    dst[0] = f2bf(a0); dst[1] = f2bf(a1);
}
__global__ __launch_bounds__(256) void combine_bias_kernel(
    const float* __restrict__ meas_w, const float* __restrict__ ent_b,
    const float* __restrict__ meas_b,
    float* __restrict__ bci, float* __restrict__ bcj)
{
    int id = blockIdx.x*256 + threadIdx.x;  // 1024
    int kk = id >> 8, half = (id >> 7) & 1, o = id & 127;
    const float* mrow = meas_w + ((long)(kk*128 + o) << 7);
    const float* eb = ent_b + half*128;
    float a = meas_b[kk*128 + o];
    #pragma unroll 8
    for (int k = 0; k < 128; k++) a = fmaf(mrow[k], eb[k], a);
    (half ? bcj : bci)[kk*128 + o] = a;
}

// ---------------- counting sort by tgt (src list only) ----------------
__global__ __launch_bounds__(256) void hist_kernel(const int* __restrict__ eidx, int* __restrict__ hist){
    int i = blockIdx.x*256 + threadIdx.x;
    if (i < EE) atomicAdd(&hist[eidx[EE+i]], 1);
}
__global__ __launch_bounds__(512) void scanA_kernel(const int* __restrict__ hist,
                                                    int* __restrict__ scanv, int* __restrict__ bsum){
    __shared__ int s[512];
    const int tid = threadIdx.x;
    const int i = blockIdx.x*512 + tid;
    int v = hist[i];
    s[tid] = v;
    __syncthreads();
    #pragma unroll
    for (int d=1; d<512; d<<=1){
        int t = (tid>=d) ? s[tid-d] : 0;
        __syncthreads();
        s[tid] += t;
        __syncthreads();
    }
    scanv[i] = s[tid] - v;
    if (tid==511) bsum[blockIdx.x] = s[511];
}
__global__ __launch_bounds__(256) void scanB_kernel(const int* __restrict__ bsum, int* __restrict__ boff){
    __shared__ int s[256];
    const int tid = threadIdx.x;
    int v = (tid<196) ? bsum[tid] : 0;
    s[tid] = v;
    __syncthreads();
    #pragma unroll
    for (int d=1; d<256; d<<=1){
        int t = (tid>=d) ? s[tid-d] : 0;
        __syncthreads();
        s[tid] += t;
        __syncthreads();
    }
    if (tid<196) boff[tid] = s[tid] - v;
}
__global__ __launch_bounds__(256) void scatter_kernel(const int* __restrict__ eidx,
    const int* __restrict__ scanv, const int* __restrict__ boff, int* __restrict__ cnt,
    int* __restrict__ sSrc)
{
    int i = blockIdx.x*256 + threadIdx.x;
    if (i >= EE) return;
    int t = eidx[EE+i], sv = eidx[i];
    int r = atomicAdd(&cnt[t], 1);
    int pos = scanv[t] + boff[t>>9] + r;
    sSrc[pos] = sv;
}

// ---------------- Stage 1: node prep (proven) ----------------
__global__ __launch_bounds__(512) void node_kernel(
    const float* __restrict__ x,
    const short* __restrict__ wSP, const float* __restrict__ sp_b,
    const float* __restrict__ ln1_g, const float* __restrict__ ln1_b,
    const float* __restrict__ pg,
    const short* __restrict__ wA, const float* __restrict__ amp_b,
    const short* __restrict__ wP, const float* __restrict__ ph_b,
    short* __restrict__ qfb)
{
    __shared__ short xb[64*128];
    __shared__ float yb[64*132];
    __shared__ short qsb[64*128];
    __shared__ float pgs[64];

    const int tid = threadIdx.x;
    const int lane = tid & 63;
    const int w    = tid >> 6;
    const int l15  = lane & 15;
    const int lj   = (lane >> 4) << 2;
    const int n0   = blockIdx.x * 64;

    if (tid < 64){
        float s = 0.f;
        #pragma unroll
        for (int r=0;r<8;r++) s += pg[r*64 + tid];
        pgs[tid] = s;
    }
    for (int t = tid; t < 1024; t += 512){
        int e = t >> 4, c8 = t & 15;
        int n = n0 + e; if (n >= NN) n = NN-1;
        const float4* xg = (const float4*)(x + (long)n*128 + c8*8);
        float4 a = xg[0], b = xg[1];
        short8 sv;
        sv[0]=f2bf(a.x); sv[1]=f2bf(a.y); sv[2]=f2bf(a.z); sv[3]=f2bf(a.w);
        sv[4]=f2bf(b.x); sv[5]=f2bf(b.y); sv[6]=f2bf(b.z); sv[7]=f2bf(b.w);
        ((short8*)xb)[C16(e, c8)] = sv;
    }
    __syncthreads();

    const short8* xbv = (const short8*)xb;
    const int col = (w<<4) + l15;

    {
        f32x4 acc[4];
        #pragma unroll
        for (int r=0;r<4;r++) acc[r]=Z4;
        #pragma unroll
        for (int ks=0; ks<4; ks++){
            short8 bw = bfrag(wSP,128,w,ks,lane);
            #pragma unroll
            for (int r=0;r<4;r++){
                int row = r*16+l15;
                acc[r] = mfma16(xbv[(row<<4) + (((ks<<2)+(lane>>4)) ^ (row&7))], bw, acc[r]);
            }
        }
        float bias = sp_b[col];
        #pragma unroll
        for (int r=0;r<4;r++){
            #pragma unroll
            for (int j=0;j<4;j++)
                yb[(r*16+lj+j)*132 + col] = acc[r][j] + bias;
        }
    }
    __syncthreads();

    {
        const int row = tid >> 3, cs = tid & 7;
        float v[16];
        float s = 0.f, sq = 0.f;
        #pragma unroll
        for (int i=0;i<16;i++){
            v[i] = yb[row*132 + cs*16 + i];
            s += v[i]; sq += v[i]*v[i];
        }
        #pragma unroll
        for (int m=1;m<8;m<<=1){ s += __shfl_xor(s,m); sq += __shfl_xor(sq,m); }
        float mean = s*(1.0f/128.0f);
        float rstd = rsqrtf(sq*(1.0f/128.0f) - mean*mean + 1e-5f);
        short8 s0, s1;
        #pragma unroll
        for (int i=0;i<16;i++){
            int c = cs*16 + i;
            float q = tanhf((v[i]-mean)*rstd*ln1_g[c] + ln1_b[c]);
            if (i<8) s0[i] = f2bf(q); else s1[i-8] = f2bf(q);
        }
        ((short8*)qsb)[C16(row, cs*2  )] = s0;
        ((short8*)qsb)[C16(row, cs*2+1)] = s1;
    }
    __syncthreads();

    {
        const short8* qv = (const short8*)qsb;
        const int isPh = w >> 2;
        const int ct   = w & 3;
        f32x4 a4[4];
        #pragma unroll
        for (int r=0;r<4;r++) a4[r]=Z4;
        #pragma unroll
        for (int ks=0; ks<2; ks++){
            short8 bw = bfrag(isPh ? wP : wA, 64, ct, ks, lane);
            #pragma unroll
            for (int r=0;r<4;r++){
                int row = r*16+l15;
                int ch = isPh*8 + (ks<<2)+(lane>>4);
                a4[r] = mfma16(qv[(row<<4) + (ch ^ (row&7))], bw, a4[r]);
            }
        }
        const int oc = ct*16 + l15;
        float bs = isPh ? ph_b[oc] : amp_b[oc];
        #pragma unroll
        for (int r=0;r<4;r++){
            #pragma unroll
            for (int j=0;j<4;j++){
                float vv = a4[r][j] + bs;
                float ov = isPh ? tanhf(vv)*3.14159265358979323846f
                                : 1.0f/(1.0f+expf(-vv));
                yb[(r*16+lj+j)*132 + isPh*64 + oc] = ov;
            }
        }
    }
    __syncthreads();

    {
        const int row = tid >> 3, cs = tid & 7;
        const int n = n0 + row;
        short8 outc, outs;
        #pragma unroll
        for (int i=0;i<8;i++){
            int c = cs*8 + i;
            float amp  = yb[row*132 + c];
            float ph   = yb[row*132 + 64 + c];
            float real = bf2f(qsb[E16(row, c)]);
            float ang  = ph + real*pgs[c];
            outc[i] = f2bf(amp * cosf(ang));
            outs[i] = f2bf(amp * sinf(ang));
        }
        if (n < NN){
            *(short8*)(qfb + (long)n*128 + cs*8)      = outc;
            *(short8*)(qfb + (long)n*128 + 64 + cs*8) = outs;
        }
    }
}

// ---------------- node GEMMs -> packed knvp[n][512] = kn | vn | pb | qn ----------------
__global__ __launch_bounds__(512) void qkvpb_kernel(
    const short* __restrict__ qfb,
    const short* __restrict__ wK, const float* __restrict__ k_b,
    const short* __restrict__ wV, const float* __restrict__ v_b,
    const short* __restrict__ wQ, const float* __restrict__ q_b,
    const short* __restrict__ wCi, const short* __restrict__ wCj,
    short* __restrict__ knvp)
{
    __shared__ short a1[64*128];
    const int tid=threadIdx.x, lane=tid&63, w=tid>>6;
    const int l15=lane&15, lh=lane>>4, lj=lh<<2;
    const long n0=(long)blockIdx.x*64;
    for (int t=tid;t<1024;t+=512){
        int e=t>>4,c8=t&15;
        ((short8*)a1)[C16(e,c8)] = ((const short8*)(qfb+(n0+e)*128))[c8];
    }
    __syncthreads();
    short8 A[4][4];
    #pragma unroll
    for (int rt=0;rt<4;rt++)
        #pragma unroll
        for (int ks=0;ks<4;ks++)
            A[rt][ks] = ((const short8*)a1)[C16(rt*16+l15, (ks<<2)+lh)];
    const int col = (w<<4)+l15;

    // K
    {
        f32x4 acc[4];
        #pragma unroll
        for (int rt=0;rt<4;rt++) acc[rt]=Z4;
        #pragma unroll
        for (int ks=0;ks<4;ks++){
            short8 b = *(const short8*)(wK + (long)col*128 + ks*32 + lh*8);
            #pragma unroll
            for (int rt=0;rt<4;rt++) acc[rt]=mfma16(A[rt][ks],b,acc[rt]);
        }
        float bias=k_b[col];
        #pragma unroll
        for (int rt=0;rt<4;rt++)
            #pragma unroll
            for (int j=0;j<4;j++)
                knvp[(n0+rt*16+lj+j)*512 + col]=f2bf(acc[rt][j]+bias);
    }
    // V
    {
        f32x4 acc[4];
        #pragma unroll
        for (int rt=0;rt<4;rt++) acc[rt]=Z4;
        #pragma unroll
        for (int ks=0;ks<4;ks++){
            short8 b = *(const short8*)(wV + (long)col*128 + ks*32 + lh*8);
            #pragma unroll
            for (int rt=0;rt<4;rt++) acc[rt]=mfma16(A[rt][ks],b,acc[rt]);
        }
        float bias=v_b[col];
        #pragma unroll
        for (int rt=0;rt<4;rt++)
            #pragma unroll
            for (int j=0;j<4;j++)
                knvp[(n0+rt*16+lj+j)*512 + 128 + col]=f2bf(acc[rt][j]+bias);
    }
    // Q -> slot 384 (walk consumes it, then overwrites the slot with S)
    {
        f32x4 acc[4];
        #pragma unroll
        for (int rt=0;rt<4;rt++) acc[rt]=Z4;
        #pragma unroll
        for (int ks=0;ks<4;ks++){
            short8 b = *(const short8*)(wQ + (long)col*128 + ks*32 + lh*8);
            #pragma unroll
            for (int rt=0;rt<4;rt++) acc[rt]=mfma16(A[rt][ks],b,acc[rt]);
        }
        float bias=q_b[col];
        #pragma unroll
        for (int rt=0;rt<4;rt++)
            #pragma unroll
            for (int j=0;j<4;j++)
                knvp[(n0+rt*16+lj+j)*512 + 384 + col]=f2bf(acc[rt][j]+bias);
    }
    // PB = sum_kk Bi ⊙ Bj  (b-slices of wCi/wCj: cols 128:256)
    {
        f32x4 pbacc[4];
        #pragma unroll
        for (int rt=0;rt<4;rt++) pbacc[rt]=Z4;
        #pragma unroll 1
        for (int kk=0;kk<4;kk++){
            short8 bi[4], bj[4];
            #pragma unroll
            for (int ks=0;ks<4;ks++){
                bi[ks] = *(const short8*)(wCi + (long)kk*32768 + (long)col*256 + 128 + ks*32 + lh*8);
                bj[ks] = *(const short8*)(wCj + (long)kk*32768 + (long)col*256 + 128 + ks*32 + lh*8);
            }
            #pragma unroll
            for (int rt=0;rt<4;rt++){
                f32x4 ai=Z4, aj=Z4;
                #pragma unroll
                for (int ks=0;ks<4;ks++){
                    ai = mfma16(A[rt][ks], bi[ks], ai);
                    aj = mfma16(A[rt][ks], bj[ks], aj);
                }
                #pragma unroll
                for (int j=0;j<4;j++) pbacc[rt][j] += ai[j]*aj[j];
            }
        }
        #pragma unroll
        for (int rt=0;rt<4;rt++)
            #pragma unroll
            for (int j=0;j<4;j++)
                knvp[(n0+rt*16+lj+j)*512 + 256 + col]=f2bf(pbacc[rt][j]);
    }
}

// ---------------- walk: 1 node/wave, ZERO LDS, max occupancy ----------------
__global__ __launch_bounds__(256) void walk_kernel(
    const short* __restrict__ qfb, short* __restrict__ knvp,
    const int* __restrict__ sSrc, const int* __restrict__ hist,
    const int* __restrict__ scanv, const int* __restrict__ boff,
    short* __restrict__ aqmpb)
{
    const int tid=threadIdx.x, lane=tid&63, w=tid>>6;
    const int n = blockIdx.x*4 + w;          // 100000 = 25000*4 exact
    const int g = lane >> 4;                 // edge slot 0..3
    const int cl = (lane & 15) * 8;          // cols cl..cl+7
    const float sc = 0.17677669529663688f;

    const int rp0 = scanv[n] + boff[n>>9];
    const int dg  = hist[n];

    float q8[8];
    {
        short8 qv = *(const short8*)(knvp + (long)n*512 + 384 + cl);
        #pragma unroll
        for (int i=0;i<8;i++) q8[i]=bf2f(qv[i]);
    }
    float aq[8], s[8], p[8];
    #pragma unroll
    for (int i=0;i<8;i++){ aq[i]=0.f; s[i]=0.f; p[i]=0.f; }

    bool vCur = (g < dg);
    int  sCur = vCur ? sSrc[rp0+g] : 0;
    const short* bCur = knvp + (long)sCur*512;
    short8 k8 = *(const short8*)(bCur + cl);
    short8 v8 = *(const short8*)(bCur + 128 + cl);
    short8 p8 = *(const short8*)(bCur + 256 + cl);
    short8 f8 = *(const short8*)(qfb + (long)sCur*128 + cl);

    #pragma unroll 1
    for (int e=0; e<dg; e+=4){
        const int en = e + 4 + g;
        const bool vN = (en < dg);
        const int  sN = vN ? sSrc[rp0+en] : 0;
        const short* bN = knvp + (long)sN*512;
        short8 kN = *(const short8*)(bN + cl);
        short8 vN8= *(const short8*)(bN + 128 + cl);
        short8 pN = *(const short8*)(bN + 256 + cl);
        short8 fN = *(const short8*)(qfb + (long)sN*128 + cl);

        float d = 0.f;
        #pragma unroll
        for (int i=0;i<8;i++) d += q8[i]*bf2f(k8[i]);
        d += __shfl_xor(d,1); d += __shfl_xor(d,2);      // head sum
        d *= sc;
        float mx = fmaxf(d, __shfl_xor(d,4));
        mx = fmaxf(mx, __shfl_xor(mx,8));                 // max over heads
        float eh = expf(d - mx);
        float den = eh;
        den += __shfl_xor(den,4); den += __shfl_xor(den,8);
        float wgt = vCur ? (eh/den) : 0.f;
        float mv  = vCur ? 1.f : 0.f;
        #pragma unroll
        for (int i=0;i<8;i++){
            aq[i] += wgt * bf2f(v8[i]);
            s[i]  += mv  * bf2f(f8[i]);
            p[i]  += mv  * bf2f(p8[i]);
        }
        k8=kN; v8=vN8; p8=pN; f8=fN; vCur=vN;
    }
    #pragma unroll
    for (int i=0;i<8;i++){
        aq[i] += __shfl_xor(aq[i],16); aq[i] += __shfl_xor(aq[i],32);
        s[i]  += __shfl_xor(s[i],16);  s[i]  += __shfl_xor(s[i],32);
        p[i]  += __shfl_xor(p[i],16);  p[i]  += __shfl_xor(p[i],32);
    }
    if (lane < 16){
        short8 av, pv, sv;
        #pragma unroll
        for (int i=0;i<8;i++){ av[i]=f2bf(aq[i]); pv[i]=f2bf(p[i]); sv[i]=f2bf(s[i]); }
        *(short8*)(aqmpb + (long)n*256 + cl)       = av;
        *(short8*)(aqmpb + (long)n*256 + 128 + cl) = pv;
        *(short8*)(knvp  + (long)n*512 + 384 + cl) = sv;   // S over dead qn slot
    }
}

// ---------------- final: GEMM-only; AQM/PB staged to LDS (coalesced) ----------------
__global__ __launch_bounds__(256) void final_kernel(
    const short* __restrict__ qfb, const short* __restrict__ knvp,
    const int* __restrict__ hist,
    const short* __restrict__ wCi, const short* __restrict__ wCj,
    const float* __restrict__ bci, const float* __restrict__ bcj,
    const short* __restrict__ wO, const float* __restrict__ out_b,
    const float* __restrict__ g2, const float* __restrict__ b2,
    const short* __restrict__ aqmpb, float* __restrict__ outp)
{
    __shared__ __align__(16) char smem[32768];
    __shared__ int degs[32];
    short* a1   = (short*)smem;            // 8 KB qf tile (swz); msgb overlay
    short* Sbf  = (short*)(smem + 8192);   // 8 KB S bf16 (swz)
    short* AQMb = (short*)(smem + 16384);  // 8 KB AQM bf16 [32][128] linear
    short* PBb  = (short*)(smem + 24576);  // 8 KB PB bf16 [32][128] linear
    float* yb   = (float*)(smem + 8192);   // 16 KB overlay (Sbf+AQMb) for OUT result

    const int tid=threadIdx.x, lane=tid&63, w=tid>>6;
    const int l15=lane&15, lh=lane>>4, lj=lh<<2;
    const long n0=(long)blockIdx.x*32;

    if (tid < 32) degs[tid] = hist[n0+tid];
    for (int t=tid;t<512;t+=256){
        int e=t>>4,c8=t&15;
        ((short8*)a1)[C16(e,c8)]  = ((const short8*)(qfb+(n0+e)*128))[c8];
        ((short8*)Sbf)[C16(e,c8)] = *(const short8*)(knvp + (n0+e)*512 + 384 + c8*8);
        *(short8*)(AQMb + e*128 + c8*8) = *(const short8*)(aqmpb + (n0+e)*256 + c8*8);
        *(short8*)(PBb  + e*128 + c8*8) = *(const short8*)(aqmpb + (n0+e)*256 + 128 + c8*8);
    }
    __syncthreads();                                       // B1

    short8 FQ[2][4], FS[2][4];
    #pragma unroll
    for (int rt=0;rt<2;rt++)
        #pragma unroll
        for (int ks=0;ks<4;ks++){
            FQ[rt][ks] = ((const short8*)a1)[C16(rt*16+l15,(ks<<2)+lh)];
            FS[rt][ks] = ((const short8*)Sbf)[C16(rt*16+l15,(ks<<2)+lh)];
        }
    __syncthreads();                                       // B2 (frag reads done before msgb overlay)

    // ---- cross GEMMs ----
    f32x4 tt[2][2], cr[2][2];
    #pragma unroll
    for (int ci=0;ci<2;ci++){ tt[ci][0]=Z4; tt[ci][1]=Z4; cr[ci][0]=Z4; cr[ci][1]=Z4; }
    #pragma unroll 1
    for (int kk=0;kk<4;kk++){
        #pragma unroll
        for (int ci=0;ci<2;ci++){
            const int col = (2*w+ci)*16 + l15;
            const long wbase = (long)kk*32768 + (long)col*256;
            short8 Bia[4],Bja[4],Bib[4],Bjb[4];
            #pragma unroll
            for (int ks=0;ks<4;ks++){
                Bia[ks] = *(const short8*)(wCi + wbase + ks*32 + lh*8);
                Bja[ks] = *(const short8*)(wCj + wbase + ks*32 + lh*8);
                Bib[ks] = *(const short8*)(wCi + wbase + 128 + ks*32 + lh*8);
                Bjb[ks] = *(const short8*)(wCj + wbase + 128 + ks*32 + lh*8);
            }
            f32x4 ai[2],aj[2],sbi[2],sbj[2];
            #pragma unroll
            for (int rt=0;rt<2;rt++){ ai[rt]=Z4; aj[rt]=Z4; sbi[rt]=Z4; sbj[rt]=Z4; }
            #pragma unroll
            for (int ks=0;ks<4;ks++){
                #pragma unroll
                for (int rt=0;rt<2;rt++){
                    ai[rt]  = mfma16(FQ[rt][ks], Bia[ks], ai[rt]);
                    aj[rt]  = mfma16(FQ[rt][ks], Bja[ks], aj[rt]);
                    sbi[rt] = mfma16(FS[rt][ks], Bib[ks], sbi[rt]);
                    sbj[rt] = mfma16(FS[rt][ks], Bjb[ks], sbj[rt]);
                }
            }
            float ci_ = bci[kk*128+col], cj_ = bcj[kk*128+col];
            #pragma unroll
            for (int rt=0;rt<2;rt++){
                #pragma unroll
                for (int j=0;j<4;j++){
                    float AI = ai[rt][j]+ci_, AJ = aj[rt][j]+cj_;
                    tt[ci][rt][j] += AI*AJ;
                    cr[ci][rt][j] += AI*sbj[rt][j] + sbi[rt][j]*AJ;
                }
            }
        }
    }
    // ---- msum (AQM/PB from LDS), write msgb over a1 ----
    short* msgb = a1;
    #pragma unroll
    for (int ci=0;ci<2;ci++){
        const int col = (2*w+ci)*16 + l15;
        #pragma unroll
        for (int rt=0;rt<2;rt++){
            #pragma unroll
            for (int j=0;j<4;j++){
                int row = rt*16+lj+j;
                float ms = bf2f(AQMb[row*128 + col])
                         + 0.25f*((float)degs[row]*tt[ci][rt][j] + cr[ci][rt][j]
                                  + bf2f(PBb[row*128 + col]));
                msgb[(C16(row, col>>3)<<3) + (col&7)] = f2bf(ms);
            }
        }
    }
    __syncthreads();                                       // B3 (AQMb reads done; yb may overlay)

    // ---- OUT GEMM -> yb (overlays Sbf+AQMb) ----
    short8 FM[2][4];
    #pragma unroll
    for (int rt=0;rt<2;rt++)
        #pragma unroll
        for (int ks=0;ks<4;ks++)
            FM[rt][ks] = ((const short8*)msgb)[C16(rt*16+l15,(ks<<2)+lh)];
    #pragma unroll
    for (int ci=0; ci<2; ci++){
        const int col = (2*w+ci)*16 + l15;
        f32x4 ao[2]; ao[0]=Z4; ao[1]=Z4;
        #pragma unroll
        for (int ks=0;ks<4;ks++){
            short8 b = *(const short8*)(wO + (long)col*128 + ks*32 + lh*8);
            ao[0]=mfma16(FM[0][ks],b,ao[0]);
            ao[1]=mfma16(FM[1][ks],b,ao[1]);
        }
        float ob = out_b[col];
        #pragma unroll
        for (int rt=0;rt<2;rt++)
            #pragma unroll
            for (int j=0;j<4;j++){
                int row = rt*16+lj+j;
                yb[(row<<7) + (col ^ (row&31))] = ao[rt][j] + (float)degs[row]*ob;
            }
    }
    __syncthreads();                                       // B4

    // ---- LN + exact gelu ----
    {
        const int row=tid>>3, cs=tid&7;
        const long n=n0+row;
        float v[16]; float sum=0.f, sq=0.f;
        #pragma unroll
        for (int i=0;i<16;i++){
            v[i]=yb[(row<<7)+((cs*16+i)^(row&31))];
            sum+=v[i]; sq+=v[i]*v[i];
        }
        #pragma unroll
        for (int m=1;m<8;m<<=1){ sum+=__shfl_xor(sum,m); sq+=__shfl_xor(sq,m); }
        float mean=sum*(1.0f/128.0f);
        float rstd=rsqrtf(sq*(1.0f/128.0f)-mean*mean+1e-5f);
        float o[16];
        #pragma unroll
        for (int i=0;i<16;i++){
            int c=cs*16+i;
            float y=(v[i]-mean)*rstd*g2[c]+b2[c];
            o[i]=0.5f*y*(1.0f+erff(y*0.70710678118f));
        }
        float* dst = outp + n*128 + cs*16;
        #pragma unroll
        for (int i=0;i<4;i++)
            ((float4*)dst)[i] = (float4){o[i*4],o[i*4+1],o[i*4+2],o[i*4+3]};
    }
}

extern "C" void kernel_launch(void* const* d_in, const int* in_sizes, int n_in,
                              void* d_out, int out_size, void* d_ws, size_t ws_size,
                              hipStream_t stream)
{
    const float* x      = (const float*)d_in[0];
    const int*   eidx   = (const int*)  d_in[1];
    const float* sp_w   = (const float*)d_in[2];
    const float* sp_b   = (const float*)d_in[3];
    const float* ln1_g  = (const float*)d_in[4];
    const float* ln1_b  = (const float*)d_in[5];
    const float* pg     = (const float*)d_in[6];
    const float* amp_w  = (const float*)d_in[7];
    const float* amp_b  = (const float*)d_in[8];
    const float* ph_w   = (const float*)d_in[9];
    const float* ph_b   = (const float*)d_in[10];
    const float* ent_w  = (const float*)d_in[11];
    const float* ent_b  = (const float*)d_in[12];
    const float* q_w    = (const float*)d_in[13];
    const float* q_b    = (const float*)d_in[14];
    const float* k_w    = (const float*)d_in[15];
    const float* k_b    = (const float*)d_in[16];
    const float* v_w    = (const float*)d_in[17];
    const float* v_b    = (const float*)d_in[18];
    const float* meas_w = (const float*)d_in[19];
    const float* meas_b = (const float*)d_in[20];
    const float* out_w  = (const float*)d_in[21];
    const float* out_b  = (const float*)d_in[22];
    const float* ln2_g  = (const float*)d_in[23];
    const float* ln2_b  = (const float*)d_in[24];

    char* wsb = (char*)d_ws;
    short* qfb  = (short*)(wsb + 0);               //  25,608,192
    short* knvp = (short*)(wsb + 25608192);        // 102,432,768
    short* wAll = (short*)(wsb + 128040960);       //     180,224
    short* wCi  = (short*)(wsb + 128221184);       //     262,144
    short* wCj  = (short*)(wsb + 128483328);       //     262,144
    float* bci  = (float*)(wsb + 128745472);       //       2,048
    float* bcj  = (float*)(wsb + 128747520);       //       2,048
    int* hist   = (int*)(wsb + 128749568);         //     401,408
    int* cnt    = (int*)(wsb + 129150976);         //     401,408
    int* scanv  = (int*)(wsb + 129552384);         //     401,408
    int* bsum   = (int*)(wsb + 129953792);         //       1,024
    int* boff   = (int*)(wsb + 129954816);         //       1,024
    int* sSrc   = (int*)(wsb + 129955840);         //   2,000,000 -> 131,955,840 total

    if (ws_size < 132000000ull) return;            // diagnostic guard

    short* wQ  = wAll;
    short* wK  = wAll + 16384;
    short* wV  = wAll + 32768;
    short* wO  = wAll + 49152;
    short* wSP = wAll + 65536;
    short* wA  = wAll + 81920;
    short* wP  = wAll + 86016;

    short* aqmpb = (short*)d_out;                  // bf16 AQM|PB packed in d_out

    hipMemsetAsync(hist, 0, 401408, stream);
    hipMemsetAsync(cnt,  0, 401408, stream);

    prep_kernel<<<352, 256, 0, stream>>>(q_w, k_w, v_w, out_w, sp_w, amp_w, ph_w, wAll);
    combine_kernel<<<512, 256, 0, stream>>>(ent_w, meas_w, wCi, wCj);
    combine_bias_kernel<<<4, 256, 0, stream>>>(meas_w, ent_b, meas_b, bci, bcj);
    node_kernel<<<NNB, 512, 0, stream>>>(x, wSP, sp_b, ln1_g, ln1_b, pg,
                                         wA, amp_b, wP, ph_b, qfb);
    hist_kernel<<<(EE+255)/256, 256, 0, stream>>>(eidx, hist);
    scanA_kernel<<<196, 512, 0, stream>>>(hist, scanv, bsum);
    scanB_kernel<<<1, 256, 0, stream>>>(bsum, boff);
    scatter_kernel<<<(EE+255)/256, 256, 0, stream>>>(eidx, scanv, boff, cnt, sSrc);
    qkvpb_kernel<<<NNB, 512, 0, stream>>>(qfb, wK, k_b, wV, v_b, wQ, q_b,
                                          wCi, wCj, knvp);
    walk_kernel<<<NWB, 256, 0, stream>>>(qfb, knvp, sSrc, hist, scanv, boff, aqmpb);
    final_kernel<<<NFB, 256, 0, stream>>>(qfb, knvp, hist,
                                          wCi, wCj, bci, bcj, wO, out_b,
                                          ln2_g, ln2_b, aqmpb, (float*)d_out);
}

// Round 20
// 610.637 us; speedup vs baseline: 1.0193x; 1.0173x over previous
//
#include <hip/hip_runtime.h>
#include <math.h>

#define NN 100000
#define EE 500000
#define NNB  1563            // 64-node blocks (qkvpb/node)
#define NFB  3125            // 32-node blocks (final)
#define NWB  25000           // walk: 4 nodes/block * 25000 = 100000 exactly

typedef __attribute__((ext_vector_type(8))) short short8;
typedef __attribute__((ext_vector_type(4))) float f32x4;
#define Z4 (f32x4){0,0,0,0}

#define C16(row, ch) (((row)<<4) + ((ch) ^ ((row)&7)))
#define E16(row, col) ((C16((row),(col)>>3)<<3) + ((col)&7))

__device__ __forceinline__ f32x4 mfma16(short8 a, short8 b, f32x4 c){
    return __builtin_amdgcn_mfma_f32_16x16x32_bf16(a, b, c, 0, 0, 0);
}
__device__ __forceinline__ short f2bf(float f){
    union { float f; unsigned u; } v; v.f = f;
    unsigned r = v.u + 0x7fffu + ((v.u >> 16) & 1u);
    return (short)(r >> 16);
}
__device__ __forceinline__ float bf2f(short s){
    union { unsigned u; float f; } v; v.u = ((unsigned)(unsigned short)s) << 16;
    return v.f;
}
__device__ __forceinline__ short8 bfrag(const short* __restrict__ W, int K, int ct, int ks, int lane){
    return *(const short8*)(W + (long)(ct*16 + (lane&15))*K + ks*32 + (lane>>4)*8);
}

// ---------------- prep: bf16 weights ----------------
__global__ __launch_bounds__(256) void prep_kernel(
    const float* __restrict__ q_w, const float* __restrict__ k_w,
    const float* __restrict__ v_w, const float* __restrict__ out_w,
    const float* __restrict__ sp_w, const float* __restrict__ amp_w,
    const float* __restrict__ ph_w, short* __restrict__ dst)
{
    int i = blockIdx.x*256 + threadIdx.x;   // 90112
    float v;
    if      (i < 16384) v = q_w[i];
    else if (i < 32768) v = k_w[i-16384];
    else if (i < 49152) v = v_w[i-32768];
    else if (i < 65536) v = out_w[i-49152];
    else if (i < 81920) v = sp_w[i-65536];
    else if (i < 86016) v = amp_w[i-81920];
    else                v = ph_w[i-86016];
    dst[i] = f2bf(v);
}

// ---------------- combined weights: Wc[kk] = meas_w[kk] @ ent_w_half ----------------
__global__ __launch_bounds__(256) void combine_kernel(
    const float* __restrict__ ent_w, const float* __restrict__ meas_w,
    short* __restrict__ wCi, short* __restrict__ wCj)
{
    const int b = blockIdx.x;          // 512
    const int kk = b >> 7, half = (b >> 6) & 1, ot = (b >> 3) & 7, ct = b & 7;
    const int tid = threadIdx.x;
    const int o = ot*16 + (tid >> 4);
    const int c = ct*32 + (tid & 15)*2;
    const float* mrow  = meas_w + ((long)(kk*128 + o) << 7);
    const float* wbase = ent_w + (long)(half*128)*256 + c;
    float a0 = 0.f, a1 = 0.f;
    #pragma unroll 8
    for (int k = 0; k < 128; k++){
        float m = mrow[k];
        float2 wv = *(const float2*)(wbase + (long)k*256);
        a0 = fmaf(m, wv.x, a0);
        a1 = fmaf(m, wv.y, a1);
    }
    short* dst = (half ? wCj : wCi) + (long)kk*32768 + o*256 + c;
    dst[0] = f2bf(a0); dst[1] = f2bf(a1);
}
__global__ __launch_bounds__(256) void combine_bias_kernel(
    const float* __restrict__ meas_w, const float* __restrict__ ent_b,
    const float* __restrict__ meas_b,
    float* __restrict__ bci, float* __restrict__ bcj)
{
    int id = blockIdx.x*256 + threadIdx.x;  // 1024
    int kk = id >> 8, half = (id >> 7) & 1, o = id & 127;
    const float* mrow = meas_w + ((long)(kk*128 + o) << 7);
    const float* eb = ent_b + half*128;
    float a = meas_b[kk*128 + o];
    #pragma unroll 8
    for (int k = 0; k < 128; k++) a = fmaf(mrow[k], eb[k], a);
    (half ? bcj : bci)[kk*128 + o] = a;
}

// ---------------- counting sort by tgt (src list only) ----------------
__global__ __launch_bounds__(256) void hist_kernel(const int* __restrict__ eidx, int* __restrict__ hist){
    int i = blockIdx.x*256 + threadIdx.x;
    if (i < EE) atomicAdd(&hist[eidx[EE+i]], 1);
}
__global__ __launch_bounds__(512) void scanA_kernel(const int* __restrict__ hist,
                                                    int* __restrict__ scanv, int* __restrict__ bsum){
    __shared__ int s[512];
    const int tid = threadIdx.x;
    const int i = blockIdx.x*512 + tid;
    int v = hist[i];
    s[tid] = v;
    __syncthreads();
    #pragma unroll
    for (int d=1; d<512; d<<=1){
        int t = (tid>=d) ? s[tid-d] : 0;
        __syncthreads();
        s[tid] += t;
        __syncthreads();
    }
    scanv[i] = s[tid] - v;
    if (tid==511) bsum[blockIdx.x] = s[511];
}
__global__ __launch_bounds__(256) void scanB_kernel(const int* __restrict__ bsum, int* __restrict__ boff){
    __shared__ int s[256];
    const int tid = threadIdx.x;
    int v = (tid<196) ? bsum[tid] : 0;
    s[tid] = v;
    __syncthreads();
    #pragma unroll
    for (int d=1; d<256; d<<=1){
        int t = (tid>=d) ? s[tid-d] : 0;
        __syncthreads();
        s[tid] += t;
        __syncthreads();
    }
    if (tid<196) boff[tid] = s[tid] - v;
}
__global__ __launch_bounds__(256) void scatter_kernel(const int* __restrict__ eidx,
    const int* __restrict__ scanv, const int* __restrict__ boff, int* __restrict__ cnt,
    int* __restrict__ sSrc)
{
    int i = blockIdx.x*256 + threadIdx.x;
    if (i >= EE) return;
    int t = eidx[EE+i], sv = eidx[i];
    int r = atomicAdd(&cnt[t], 1);
    int pos = scanv[t] + boff[t>>9] + r;
    sSrc[pos] = sv;
}

// ---------------- Stage 1: node prep (proven) ----------------
__global__ __launch_bounds__(512) void node_kernel(
    const float* __restrict__ x,
    const short* __restrict__ wSP, const float* __restrict__ sp_b,
    const float* __restrict__ ln1_g, const float* __restrict__ ln1_b,
    const float* __restrict__ pg,
    const short* __restrict__ wA, const float* __restrict__ amp_b,
    const short* __restrict__ wP, const float* __restrict__ ph_b,
    short* __restrict__ qfb)
{
    __shared__ short xb[64*128];
    __shared__ float yb[64*132];
    __shared__ short qsb[64*128];
    __shared__ float pgs[64];

    const int tid = threadIdx.x;
    const int lane = tid & 63;
    const int w    = tid >> 6;
    const int l15  = lane & 15;
    const int lj   = (lane >> 4) << 2;
    const int n0   = blockIdx.x * 64;

    if (tid < 64){
        float s = 0.f;
        #pragma unroll
        for (int r=0;r<8;r++) s += pg[r*64 + tid];
        pgs[tid] = s;
    }
    for (int t = tid; t < 1024; t += 512){
        int e = t >> 4, c8 = t & 15;
        int n = n0 + e; if (n >= NN) n = NN-1;
        const float4* xg = (const float4*)(x + (long)n*128 + c8*8);
        float4 a = xg[0], b = xg[1];
        short8 sv;
        sv[0]=f2bf(a.x); sv[1]=f2bf(a.y); sv[2]=f2bf(a.z); sv[3]=f2bf(a.w);
        sv[4]=f2bf(b.x); sv[5]=f2bf(b.y); sv[6]=f2bf(b.z); sv[7]=f2bf(b.w);
        ((short8*)xb)[C16(e, c8)] = sv;
    }
    __syncthreads();

    const short8* xbv = (const short8*)xb;
    const int col = (w<<4) + l15;

    {
        f32x4 acc[4];
        #pragma unroll
        for (int r=0;r<4;r++) acc[r]=Z4;
        #pragma unroll
        for (int ks=0; ks<4; ks++){
            short8 bw = bfrag(wSP,128,w,ks,lane);
            #pragma unroll
            for (int r=0;r<4;r++){
                int row = r*16+l15;
                acc[r] = mfma16(xbv[(row<<4) + (((ks<<2)+(lane>>4)) ^ (row&7))], bw, acc[r]);
            }
        }
        float bias = sp_b[col];
        #pragma unroll
        for (int r=0;r<4;r++){
            #pragma unroll
            for (int j=0;j<4;j++)
                yb[(r*16+lj+j)*132 + col] = acc[r][j] + bias;
        }
    }
    __syncthreads();

    {
        const int row = tid >> 3, cs = tid & 7;
        float v[16];
        float s = 0.f, sq = 0.f;
        #pragma unroll
        for (int i=0;i<16;i++){
            v[i] = yb[row*132 + cs*16 + i];
            s += v[i]; sq += v[i]*v[i];
        }
        #pragma unroll
        for (int m=1;m<8;m<<=1){ s += __shfl_xor(s,m); sq += __shfl_xor(sq,m); }
        float mean = s*(1.0f/128.0f);
        float rstd = rsqrtf(sq*(1.0f/128.0f) - mean*mean + 1e-5f);
        short8 s0, s1;
        #pragma unroll
        for (int i=0;i<16;i++){
            int c = cs*16 + i;
            float q = tanhf((v[i]-mean)*rstd*ln1_g[c] + ln1_b[c]);
            if (i<8) s0[i] = f2bf(q); else s1[i-8] = f2bf(q);
        }
        ((short8*)qsb)[C16(row, cs*2  )] = s0;
        ((short8*)qsb)[C16(row, cs*2+1)] = s1;
    }
    __syncthreads();

    {
        const short8* qv = (const short8*)qsb;
        const int isPh = w >> 2;
        const int ct   = w & 3;
        f32x4 a4[4];
        #pragma unroll
        for (int r=0;r<4;r++) a4[r]=Z4;
        #pragma unroll
        for (int ks=0; ks<2; ks++){
            short8 bw = bfrag(isPh ? wP : wA, 64, ct, ks, lane);
            #pragma unroll
            for (int r=0;r<4;r++){
                int row = r*16+l15;
                int ch = isPh*8 + (ks<<2)+(lane>>4);
                a4[r] = mfma16(qv[(row<<4) + (ch ^ (row&7))], bw, a4[r]);
            }
        }
        const int oc = ct*16 + l15;
        float bs = isPh ? ph_b[oc] : amp_b[oc];
        #pragma unroll
        for (int r=0;r<4;r++){
            #pragma unroll
            for (int j=0;j<4;j++){
                float vv = a4[r][j] + bs;
                float ov = isPh ? tanhf(vv)*3.14159265358979323846f
                                : 1.0f/(1.0f+expf(-vv));
                yb[(r*16+lj+j)*132 + isPh*64 + oc] = ov;
            }
        }
    }
    __syncthreads();

    {
        const int row = tid >> 3, cs = tid & 7;
        const int n = n0 + row;
        short8 outc, outs;
        #pragma unroll
        for (int i=0;i<8;i++){
            int c = cs*8 + i;
            float amp  = yb[row*132 + c];
            float ph   = yb[row*132 + 64 + c];
            float real = bf2f(qsb[E16(row, c)]);
            float ang  = ph + real*pgs[c];
            outc[i] = f2bf(amp * cosf(ang));
            outs[i] = f2bf(amp * sinf(ang));
        }
        if (n < NN){
            *(short8*)(qfb + (long)n*128 + cs*8)      = outc;
            *(short8*)(qfb + (long)n*128 + 64 + cs*8) = outs;
        }
    }
}

// ---------------- node GEMMs -> packed knvp[n][512] = kn | vn | pb | qn ----------------
__global__ __launch_bounds__(512) void qkvpb_kernel(
    const short* __restrict__ qfb,
    const short* __restrict__ wK, const float* __restrict__ k_b,
    const short* __restrict__ wV, const float* __restrict__ v_b,
    const short* __restrict__ wQ, const float* __restrict__ q_b,
    const short* __restrict__ wCi, const short* __restrict__ wCj,
    short* __restrict__ knvp)
{
    __shared__ short a1[64*128];
    const int tid=threadIdx.x, lane=tid&63, w=tid>>6;
    const int l15=lane&15, lh=lane>>4, lj=lh<<2;
    const long n0=(long)blockIdx.x*64;
    for (int t=tid;t<1024;t+=512){
        int e=t>>4,c8=t&15;
        ((short8*)a1)[C16(e,c8)] = ((const short8*)(qfb+(n0+e)*128))[c8];
    }
    __syncthreads();
    short8 A[4][4];
    #pragma unroll
    for (int rt=0;rt<4;rt++)
        #pragma unroll
        for (int ks=0;ks<4;ks++)
            A[rt][ks] = ((const short8*)a1)[C16(rt*16+l15, (ks<<2)+lh)];
    const int col = (w<<4)+l15;

    // K
    {
        f32x4 acc[4];
        #pragma unroll
        for (int rt=0;rt<4;rt++) acc[rt]=Z4;
        #pragma unroll
        for (int ks=0;ks<4;ks++){
            short8 b = *(const short8*)(wK + (long)col*128 + ks*32 + lh*8);
            #pragma unroll
            for (int rt=0;rt<4;rt++) acc[rt]=mfma16(A[rt][ks],b,acc[rt]);
        }
        float bias=k_b[col];
        #pragma unroll
        for (int rt=0;rt<4;rt++)
            #pragma unroll
            for (int j=0;j<4;j++)
                knvp[(n0+rt*16+lj+j)*512 + col]=f2bf(acc[rt][j]+bias);
    }
    // V
    {
        f32x4 acc[4];
        #pragma unroll
        for (int rt=0;rt<4;rt++) acc[rt]=Z4;
        #pragma unroll
        for (int ks=0;ks<4;ks++){
            short8 b = *(const short8*)(wV + (long)col*128 + ks*32 + lh*8);
            #pragma unroll
            for (int rt=0;rt<4;rt++) acc[rt]=mfma16(A[rt][ks],b,acc[rt]);
        }
        float bias=v_b[col];
        #pragma unroll
        for (int rt=0;rt<4;rt++)
            #pragma unroll
            for (int j=0;j<4;j++)
                knvp[(n0+rt*16+lj+j)*512 + 128 + col]=f2bf(acc[rt][j]+bias);
    }
    // Q -> slot 384 (walk consumes it, then overwrites the slot with S)
    {
        f32x4 acc[4];
        #pragma unroll
        for (int rt=0;rt<4;rt++) acc[rt]=Z4;
        #pragma unroll
        for (int ks=0;ks<4;ks++){
            short8 b = *(const short8*)(wQ + (long)col*128 + ks*32 + lh*8);
            #pragma unroll
            for (int rt=0;rt<4;rt++) acc[rt]=mfma16(A[rt][ks],b,acc[rt]);
        }
        float bias=q_b[col];
        #pragma unroll
        for (int rt=0;rt<4;rt++)
            #pragma unroll
            for (int j=0;j<4;j++)
                knvp[(n0+rt*16+lj+j)*512 + 384 + col]=f2bf(acc[rt][j]+bias);
    }
    // PB = sum_kk Bi ⊙ Bj  (b-slices of wCi/wCj: cols 128:256)
    {
        f32x4 pbacc[4];
        #pragma unroll
        for (int rt=0;rt<4;rt++) pbacc[rt]=Z4;
        #pragma unroll 1
        for (int kk=0;kk<4;kk++){
            short8 bi[4], bj[4];
            #pragma unroll
            for (int ks=0;ks<4;ks++){
                bi[ks] = *(const short8*)(wCi + (long)kk*32768 + (long)col*256 + 128 + ks*32 + lh*8);
                bj[ks] = *(const short8*)(wCj + (long)kk*32768 + (long)col*256 + 128 + ks*32 + lh*8);
            }
            #pragma unroll
            for (int rt=0;rt<4;rt++){
                f32x4 ai=Z4, aj=Z4;
                #pragma unroll
                for (int ks=0;ks<4;ks++){
                    ai = mfma16(A[rt][ks], bi[ks], ai);
                    aj = mfma16(A[rt][ks], bj[ks], aj);
                }
                #pragma unroll
                for (int j=0;j<4;j++) pbacc[rt][j] += ai[j]*aj[j];
            }
        }
        #pragma unroll
        for (int rt=0;rt<4;rt++)
            #pragma unroll
            for (int j=0;j<4;j++)
                knvp[(n0+rt*16+lj+j)*512 + 256 + col]=f2bf(pbacc[rt][j]);
    }
}

// ---------------- walk: 1 node/wave, ZERO LDS, max occupancy ----------------
__global__ __launch_bounds__(256) void walk_kernel(
    const short* __restrict__ qfb, short* __restrict__ knvp,
    const int* __restrict__ sSrc, const int* __restrict__ hist,
    const int* __restrict__ scanv, const int* __restrict__ boff,
    short* __restrict__ aqmpb)
{
    const int tid=threadIdx.x, lane=tid&63, w=tid>>6;
    const int n = blockIdx.x*4 + w;          // 100000 = 25000*4 exact
    const int g = lane >> 4;                 // edge slot 0..3
    const int cl = (lane & 15) * 8;          // cols cl..cl+7
    const float sc = 0.17677669529663688f;

    const int rp0 = scanv[n] + boff[n>>9];
    const int dg  = hist[n];

    float q8[8];
    {
        short8 qv = *(const short8*)(knvp + (long)n*512 + 384 + cl);
        #pragma unroll
        for (int i=0;i<8;i++) q8[i]=bf2f(qv[i]);
    }
    float aq[8], s[8], p[8];
    #pragma unroll
    for (int i=0;i<8;i++){ aq[i]=0.f; s[i]=0.f; p[i]=0.f; }

    bool vCur = (g < dg);
    int  sCur = vCur ? sSrc[rp0+g] : 0;
    const short* bCur = knvp + (long)sCur*512;
    short8 k8 = *(const short8*)(bCur + cl);
    short8 v8 = *(const short8*)(bCur + 128 + cl);
    short8 p8 = *(const short8*)(bCur + 256 + cl);
    short8 f8 = *(const short8*)(qfb + (long)sCur*128 + cl);

    #pragma unroll 1
    for (int e=0; e<dg; e+=4){
        const int en = e + 4 + g;
        const bool vN = (en < dg);
        const int  sN = vN ? sSrc[rp0+en] : 0;
        const short* bN = knvp + (long)sN*512;
        short8 kN = *(const short8*)(bN + cl);
        short8 vN8= *(const short8*)(bN + 128 + cl);
        short8 pN = *(const short8*)(bN + 256 + cl);
        short8 fN = *(const short8*)(qfb + (long)sN*128 + cl);

        float d = 0.f;
        #pragma unroll
        for (int i=0;i<8;i++) d += q8[i]*bf2f(k8[i]);
        d += __shfl_xor(d,1); d += __shfl_xor(d,2);      // head sum
        d *= sc;
        float mx = fmaxf(d, __shfl_xor(d,4));
        mx = fmaxf(mx, __shfl_xor(mx,8));                 // max over heads
        float eh = expf(d - mx);
        float den = eh;
        den += __shfl_xor(den,4); den += __shfl_xor(den,8);
        float wgt = vCur ? (eh/den) : 0.f;
        float mv  = vCur ? 1.f : 0.f;
        #pragma unroll
        for (int i=0;i<8;i++){
            aq[i] += wgt * bf2f(v8[i]);
            s[i]  += mv  * bf2f(f8[i]);
            p[i]  += mv  * bf2f(p8[i]);
        }
        k8=kN; v8=vN8; p8=pN; f8=fN; vCur=vN;
    }
    #pragma unroll
    for (int i=0;i<8;i++){
        aq[i] += __shfl_xor(aq[i],16); aq[i] += __shfl_xor(aq[i],32);
        s[i]  += __shfl_xor(s[i],16);  s[i]  += __shfl_xor(s[i],32);
        p[i]  += __shfl_xor(p[i],16);  p[i]  += __shfl_xor(p[i],32);
    }
    if (lane < 16){
        short8 av, pv, sv;
        #pragma unroll
        for (int i=0;i<8;i++){ av[i]=f2bf(aq[i]); pv[i]=f2bf(p[i]); sv[i]=f2bf(s[i]); }
        *(short8*)(aqmpb + (long)n*256 + cl)       = av;
        *(short8*)(aqmpb + (long)n*256 + 128 + cl) = pv;
        *(short8*)(knvp  + (long)n*512 + 384 + cl) = sv;   // S over dead qn slot
    }
}

// ---------------- final: GEMM-only; double-buffered B-frag pipeline ----------------
__global__ __launch_bounds__(256) void final_kernel(
    const short* __restrict__ qfb, const short* __restrict__ knvp,
    const int* __restrict__ hist,
    const short* __restrict__ wCi, const short* __restrict__ wCj,
    const float* __restrict__ bci, const float* __restrict__ bcj,
    const short* __restrict__ wO, const float* __restrict__ out_b,
    const float* __restrict__ g2, const float* __restrict__ b2,
    const short* __restrict__ aqmpb, float* __restrict__ outp)
{
    __shared__ __align__(16) char smem[32768];
    __shared__ int degs[32];
    short* a1   = (short*)smem;            // 8 KB qf tile (swz); msgb overlay
    short* Sbf  = (short*)(smem + 8192);   // 8 KB S bf16 (swz)
    short* AQMb = (short*)(smem + 16384);  // 8 KB AQM bf16 [32][128] linear
    short* PBb  = (short*)(smem + 24576);  // 8 KB PB bf16 [32][128] linear
    float* yb   = (float*)(smem + 8192);   // 16 KB overlay (Sbf+AQMb) for OUT result

    const int tid=threadIdx.x, lane=tid&63, w=tid>>6;
    const int l15=lane&15, lh=lane>>4, lj=lh<<2;
    const long n0=(long)blockIdx.x*32;

    if (tid < 32) degs[tid] = hist[n0+tid];
    for (int t=tid;t<512;t+=256){
        int e=t>>4,c8=t&15;
        ((short8*)a1)[C16(e,c8)]  = ((const short8*)(qfb+(n0+e)*128))[c8];
        ((short8*)Sbf)[C16(e,c8)] = *(const short8*)(knvp + (n0+e)*512 + 384 + c8*8);
        *(short8*)(AQMb + e*128 + c8*8) = *(const short8*)(aqmpb + (n0+e)*256 + c8*8);
        *(short8*)(PBb  + e*128 + c8*8) = *(const short8*)(aqmpb + (n0+e)*256 + 128 + c8*8);
    }
    __syncthreads();                                       // B1

    short8 FQ[2][4], FS[2][4];
    #pragma unroll
    for (int rt=0;rt<2;rt++)
        #pragma unroll
        for (int ks=0;ks<4;ks++){
            FQ[rt][ks] = ((const short8*)a1)[C16(rt*16+l15,(ks<<2)+lh)];
            FS[rt][ks] = ((const short8*)Sbf)[C16(rt*16+l15,(ks<<2)+lh)];
        }
    __syncthreads();                                       // B2 (frag reads done before msgb overlay)

    // ---- cross GEMMs: explicit double-buffered B-frag pipeline ----
    const int col0 = (2*w)*16 + l15;
    const int col1 = (2*w+1)*16 + l15;
    f32x4 tt0[2], cr0[2], tt1[2], cr1[2];
    tt0[0]=Z4; tt0[1]=Z4; cr0[0]=Z4; cr0[1]=Z4;
    tt1[0]=Z4; tt1[1]=Z4; cr1[0]=Z4; cr1[1]=Z4;

    short8 Pa[4], Pj[4], Qa[4], Qj[4];
    {   // preload kk=0, ci=0, a-half
        const long wb = (long)col0*256;
        #pragma unroll
        for (int ks=0;ks<4;ks++){
            Pa[ks] = *(const short8*)(wCi + wb + ks*32 + lh*8);
            Pj[ks] = *(const short8*)(wCj + wb + ks*32 + lh*8);
        }
    }
    #pragma unroll 1
    for (int kk=0; kk<4; kk++){
        const long wb0 = (long)kk*32768 + (long)col0*256;
        const long wb1 = (long)kk*32768 + (long)col1*256;
        // ===== ci = 0 =====
        #pragma unroll
        for (int ks=0;ks<4;ks++){
            Qa[ks] = *(const short8*)(wCi + wb0 + 128 + ks*32 + lh*8);
            Qj[ks] = *(const short8*)(wCj + wb0 + 128 + ks*32 + lh*8);
        }
        f32x4 ai0=Z4, ai1=Z4, aj0=Z4, aj1=Z4;
        #pragma unroll
        for (int ks=0;ks<4;ks++){
            ai0=mfma16(FQ[0][ks],Pa[ks],ai0); ai1=mfma16(FQ[1][ks],Pa[ks],ai1);
            aj0=mfma16(FQ[0][ks],Pj[ks],aj0); aj1=mfma16(FQ[1][ks],Pj[ks],aj1);
        }
        #pragma unroll
        for (int ks=0;ks<4;ks++){   // prefetch ci=1 a-half (overlaps sbi/sbj MFMAs)
            Pa[ks] = *(const short8*)(wCi + wb1 + ks*32 + lh*8);
            Pj[ks] = *(const short8*)(wCj + wb1 + ks*32 + lh*8);
        }
        f32x4 sbi0=Z4, sbi1=Z4, sbj0=Z4, sbj1=Z4;
        #pragma unroll
        for (int ks=0;ks<4;ks++){
            sbi0=mfma16(FS[0][ks],Qa[ks],sbi0); sbi1=mfma16(FS[1][ks],Qa[ks],sbi1);
            sbj0=mfma16(FS[0][ks],Qj[ks],sbj0); sbj1=mfma16(FS[1][ks],Qj[ks],sbj1);
        }
        {
            float ci_=bci[kk*128+col0], cj_=bcj[kk*128+col0];
            #pragma unroll
            for (int j=0;j<4;j++){
                float AI0=ai0[j]+ci_, AJ0=aj0[j]+cj_;
                float AI1=ai1[j]+ci_, AJ1=aj1[j]+cj_;
                tt0[0][j]+=AI0*AJ0; cr0[0][j]+=AI0*sbj0[j]+sbi0[j]*AJ0;
                tt0[1][j]+=AI1*AJ1; cr0[1][j]+=AI1*sbj1[j]+sbi1[j]*AJ1;
            }
        }
        // ===== ci = 1 =====
        #pragma unroll
        for (int ks=0;ks<4;ks++){
            Qa[ks] = *(const short8*)(wCi + wb1 + 128 + ks*32 + lh*8);
            Qj[ks] = *(const short8*)(wCj + wb1 + 128 + ks*32 + lh*8);
        }
        ai0=Z4; ai1=Z4; aj0=Z4; aj1=Z4;
        #pragma unroll
        for (int ks=0;ks<4;ks++){
            ai0=mfma16(FQ[0][ks],Pa[ks],ai0); ai1=mfma16(FQ[1][ks],Pa[ks],ai1);
            aj0=mfma16(FQ[0][ks],Pj[ks],aj0); aj1=mfma16(FQ[1][ks],Pj[ks],aj1);
        }
        if (kk < 3){
            const long wbn = (long)(kk+1)*32768 + (long)col0*256;
            #pragma unroll
            for (int ks=0;ks<4;ks++){   // prefetch next kk ci=0 a-half
                Pa[ks] = *(const short8*)(wCi + wbn + ks*32 + lh*8);
                Pj[ks] = *(const short8*)(wCj + wbn + ks*32 + lh*8);
            }
        }
        sbi0=Z4; sbi1=Z4; sbj0=Z4; sbj1=Z4;
        #pragma unroll
        for (int ks=0;ks<4;ks++){
            sbi0=mfma16(FS[0][ks],Qa[ks],sbi0); sbi1=mfma16(FS[1][ks],Qa[ks],sbi1);
            sbj0=mfma16(FS[0][ks],Qj[ks],sbj0); sbj1=mfma16(FS[1][ks],Qj[ks],sbj1);
        }
        {
            float ci_=bci[kk*128+col1], cj_=bcj[kk*128+col1];
            #pragma unroll
            for (int j=0;j<4;j++){
                float AI0=ai0[j]+ci_, AJ0=aj0[j]+cj_;
                float AI1=ai1[j]+ci_, AJ1=aj1[j]+cj_;
                tt1[0][j]+=AI0*AJ0; cr1[0][j]+=AI0*sbj0[j]+sbi0[j]*AJ0;
                tt1[1][j]+=AI1*AJ1; cr1[1][j]+=AI1*sbj1[j]+sbi1[j]*AJ1;
            }
        }
    }
    // ---- msum (AQM/PB from LDS), write msgb over a1 ----
    short* msgb = a1;
    #pragma unroll
    for (int rt=0;rt<2;rt++){
        #pragma unroll
        for (int j=0;j<4;j++){
            int row = rt*16+lj+j;
            float ms0 = bf2f(AQMb[row*128 + col0])
                      + 0.25f*((float)degs[row]*tt0[rt][j] + cr0[rt][j]
                               + bf2f(PBb[row*128 + col0]));
            float ms1 = bf2f(AQMb[row*128 + col1])
                      + 0.25f*((float)degs[row]*tt1[rt][j] + cr1[rt][j]
                               + bf2f(PBb[row*128 + col1]));
            msgb[(C16(row, col0>>3)<<3) + (col0&7)] = f2bf(ms0);
            msgb[(C16(row, col1>>3)<<3) + (col1&7)] = f2bf(ms1);
        }
    }
    __syncthreads();                                       // B3

    // ---- OUT GEMM -> yb (overlays Sbf+AQMb) ----
    short8 FM[2][4];
    #pragma unroll
    for (int rt=0;rt<2;rt++)
        #pragma unroll
        for (int ks=0;ks<4;ks++)
            FM[rt][ks] = ((const short8*)msgb)[C16(rt*16+l15,(ks<<2)+lh)];
    #pragma unroll
    for (int ci=0; ci<2; ci++){
        const int col = (2*w+ci)*16 + l15;
        f32x4 ao[2]; ao[0]=Z4; ao[1]=Z4;
        #pragma unroll
        for (int ks=0;ks<4;ks++){
            short8 b = *(const short8*)(wO + (long)col*128 + ks*32 + lh*8);
            ao[0]=mfma16(FM[0][ks],b,ao[0]);
            ao[1]=mfma16(FM[1][ks],b,ao[1]);
        }
        float ob = out_b[col];
        #pragma unroll
        for (int rt=0;rt<2;rt++)
            #pragma unroll
            for (int j=0;j<4;j++){
                int row = rt*16+lj+j;
                yb[(row<<7) + (col ^ (row&31))] = ao[rt][j] + (float)degs[row]*ob;
            }
    }
    __syncthreads();                                       // B4

    // ---- LN + exact gelu ----
    {
        const int row=tid>>3, cs=tid&7;
        const long n=n0+row;
        float v[16]; float sum=0.f, sq=0.f;
        #pragma unroll
        for (int i=0;i<16;i++){
            v[i]=yb[(row<<7)+((cs*16+i)^(row&31))];
            sum+=v[i]; sq+=v[i]*v[i];
        }
        #pragma unroll
        for (int m=1;m<8;m<<=1){ sum+=__shfl_xor(sum,m); sq+=__shfl_xor(sq,m); }
        float mean=sum*(1.0f/128.0f);
        float rstd=rsqrtf(sq*(1.0f/128.0f)-mean*mean+1e-5f);
        float o[16];
        #pragma unroll
        for (int i=0;i<16;i++){
            int c=cs*16+i;
            float y=(v[i]-mean)*rstd*g2[c]+b2[c];
            o[i]=0.5f*y*(1.0f+erff(y*0.70710678118f));
        }
        float* dst = outp + n*128 + cs*16;
        #pragma unroll
        for (int i=0;i<4;i++)
            ((float4*)dst)[i] = (float4){o[i*4],o[i*4+1],o[i*4+2],o[i*4+3]};
    }
}

extern "C" void kernel_launch(void* const* d_in, const int* in_sizes, int n_in,
                              void* d_out, int out_size, void* d_ws, size_t ws_size,
                              hipStream_t stream)
{
    const float* x      = (const float*)d_in[0];
    const int*   eidx   = (const int*)  d_in[1];
    const float* sp_w   = (const float*)d_in[2];
    const float* sp_b   = (const float*)d_in[3];
    const float* ln1_g  = (const float*)d_in[4];
    const float* ln1_b  = (const float*)d_in[5];
    const float* pg     = (const float*)d_in[6];
    const float* amp_w  = (const float*)d_in[7];
    const float* amp_b  = (const float*)d_in[8];
    const float* ph_w   = (const float*)d_in[9];
    const float* ph_b   = (const float*)d_in[10];
    const float* ent_w  = (const float*)d_in[11];
    const float* ent_b  = (const float*)d_in[12];
    const float* q_w    = (const float*)d_in[13];
    const float* q_b    = (const float*)d_in[14];
    const float* k_w    = (const float*)d_in[15];
    const float* k_b    = (const float*)d_in[16];
    const float* v_w    = (const float*)d_in[17];
    const float* v_b    = (const float*)d_in[18];
    const float* meas_w = (const float*)d_in[19];
    const float* meas_b = (const float*)d_in[20];
    const float* out_w  = (const float*)d_in[21];
    const float* out_b  = (const float*)d_in[22];
    const float* ln2_g  = (const float*)d_in[23];
    const float* ln2_b  = (const float*)d_in[24];

    char* wsb = (char*)d_ws;
    short* qfb  = (short*)(wsb + 0);               //  25,608,192
    short* knvp = (short*)(wsb + 25608192);        // 102,432,768
    short* wAll = (short*)(wsb + 128040960);       //     180,224
    short* wCi  = (short*)(wsb + 128221184);       //     262,144
    short* wCj  = (short*)(wsb + 128483328);       //     262,144
    float* bci  = (float*)(wsb + 128745472);       //       2,048
    float* bcj  = (float*)(wsb + 128747520);       //       2,048
    int* hist   = (int*)(wsb + 128749568);         //     401,408
    int* cnt    = (int*)(wsb + 129150976);         //     401,408
    int* scanv  = (int*)(wsb + 129552384);         //     401,408
    int* bsum   = (int*)(wsb + 129953792);         //       1,024
    int* boff   = (int*)(wsb + 129954816);         //       1,024
    int* sSrc   = (int*)(wsb + 129955840);         //   2,000,000 -> 131,955,840 total

    if (ws_size < 132000000ull) return;            // diagnostic guard

    short* wQ  = wAll;
    short* wK  = wAll + 16384;
    short* wV  = wAll + 32768;
    short* wO  = wAll + 49152;
    short* wSP = wAll + 65536;
    short* wA  = wAll + 81920;
    short* wP  = wAll + 86016;

    short* aqmpb = (short*)d_out;                  // bf16 AQM|PB packed in d_out

    hipMemsetAsync(hist, 0, 401408, stream);
    hipMemsetAsync(cnt,  0, 401408, stream);

    prep_kernel<<<352, 256, 0, stream>>>(q_w, k_w, v_w, out_w, sp_w, amp_w, ph_w, wAll);
    combine_kernel<<<512, 256, 0, stream>>>(ent_w, meas_w, wCi, wCj);
    combine_bias_kernel<<<4, 256, 0, stream>>>(meas_w, ent_b, meas_b, bci, bcj);
    node_kernel<<<NNB, 512, 0, stream>>>(x, wSP, sp_b, ln1_g, ln1_b, pg,
                                         wA, amp_b, wP, ph_b, qfb);
    hist_kernel<<<(EE+255)/256, 256, 0, stream>>>(eidx, hist);
    scanA_kernel<<<196, 512, 0, stream>>>(hist, scanv, bsum);
    scanB_kernel<<<1, 256, 0, stream>>>(bsum, boff);
    scatter_kernel<<<(EE+255)/256, 256, 0, stream>>>(eidx, scanv, boff, cnt, sSrc);
    qkvpb_kernel<<<NNB, 512, 0, stream>>>(qfb, wK, k_b, wV, v_b, wQ, q_b,
                                          wCi, wCj, knvp);
    walk_kernel<<<NWB, 256, 0, stream>>>(qfb, knvp, sSrc, hist, scanv, boff, aqmpb);
    final_kernel<<<NFB, 256, 0, stream>>>(qfb, knvp, hist,
                                          wCi, wCj, bci, bcj, wO, out_b,
                                          ln2_g, ln2_b, aqmpb, (float*)d_out);
}

// Round 21
// 516.278 us; speedup vs baseline: 1.2056x; 1.1828x over previous
//
#include <hip/hip_runtime.h>
#include <math.h>

#define NN 100000
#define EE 500000
#define NNB  1563            // 64-node blocks (qkvpb/node)
#define NFB2 1563            // final: 64 nodes/block (64*1563 = 100032 >= NN)
#define NWB  25000           // walk: 4 nodes/block * 25000 = 100000 exactly

typedef __attribute__((ext_vector_type(8))) short short8;
typedef __attribute__((ext_vector_type(4))) float f32x4;
#define Z4 (f32x4){0,0,0,0}

#define C16(row, ch) (((row)<<4) + ((ch) ^ ((row)&7)))
#define E16(row, col) ((C16((row),(col)>>3)<<3) + ((col)&7))

__device__ __forceinline__ f32x4 mfma16(short8 a, short8 b, f32x4 c){
    return __builtin_amdgcn_mfma_f32_16x16x32_bf16(a, b, c, 0, 0, 0);
}
__device__ __forceinline__ short f2bf(float f){
    union { float f; unsigned u; } v; v.f = f;
    unsigned r = v.u + 0x7fffu + ((v.u >> 16) & 1u);
    return (short)(r >> 16);
}
__device__ __forceinline__ float bf2f(short s){
    union { unsigned u; float f; } v; v.u = ((unsigned)(unsigned short)s) << 16;
    return v.f;
}
__device__ __forceinline__ short8 bfrag(const short* __restrict__ W, int K, int ct, int ks, int lane){
    return *(const short8*)(W + (long)(ct*16 + (lane&15))*K + ks*32 + (lane>>4)*8);
}

// ---------------- prep: bf16 weights ----------------
__global__ __launch_bounds__(256) void prep_kernel(
    const float* __restrict__ q_w, const float* __restrict__ k_w,
    const float* __restrict__ v_w, const float* __restrict__ out_w,
    const float* __restrict__ sp_w, const float* __restrict__ amp_w,
    const float* __restrict__ ph_w, short* __restrict__ dst)
{
    int i = blockIdx.x*256 + threadIdx.x;   // 90112
    float v;
    if      (i < 16384) v = q_w[i];
    else if (i < 32768) v = k_w[i-16384];
    else if (i < 49152) v = v_w[i-32768];
    else if (i < 65536) v = out_w[i-49152];
    else if (i < 81920) v = sp_w[i-65536];
    else if (i < 86016) v = amp_w[i-81920];
    else                v = ph_w[i-86016];
    dst[i] = f2bf(v);
}

// ---------------- combined weights: Wc[kk] = meas_w[kk] @ ent_w_half ----------------
__global__ __launch_bounds__(256) void combine_kernel(
    const float* __restrict__ ent_w, const float* __restrict__ meas_w,
    short* __restrict__ wCi, short* __restrict__ wCj)
{
    const int b = blockIdx.x;          // 512
    const int kk = b >> 7, half = (b >> 6) & 1, ot = (b >> 3) & 7, ct = b & 7;
    const int tid = threadIdx.x;
    const int o = ot*16 + (tid >> 4);
    const int c = ct*32 + (tid & 15)*2;
    const float* mrow  = meas_w + ((long)(kk*128 + o) << 7);
    const float* wbase = ent_w + (long)(half*128)*256 + c;
    float a0 = 0.f, a1 = 0.f;
    #pragma unroll 8
    for (int k = 0; k < 128; k++){
        float m = mrow[k];
        float2 wv = *(const float2*)(wbase + (long)k*256);
        a0 = fmaf(m, wv.x, a0);
        a1 = fmaf(m, wv.y, a1);
    }
    short* dst = (half ? wCj : wCi) + (long)kk*32768 + o*256 + c;
    dst[0] = f2bf(a0); dst[1] = f2bf(a1);
}
__global__ __launch_bounds__(256) void combine_bias_kernel(
    const float* __restrict__ meas_w, const float* __restrict__ ent_b,
    const float* __restrict__ meas_b,
    float* __restrict__ bci, float* __restrict__ bcj)
{
    int id = blockIdx.x*256 + threadIdx.x;  // 1024
    int kk = id >> 8, half = (id >> 7) & 1, o = id & 127;
    const float* mrow = meas_w + ((long)(kk*128 + o) << 7);
    const float* eb = ent_b + half*128;
    float a = meas_b[kk*128 + o];
    #pragma unroll 8
    for (int k = 0; k < 128; k++) a = fmaf(mrow[k], eb[k], a);
    (half ? bcj : bci)[kk*128 + o] = a;
}

// ---------------- counting sort by tgt (src list only) ----------------
__global__ __launch_bounds__(256) void hist_kernel(const int* __restrict__ eidx, int* __restrict__ hist){
    int i = blockIdx.x*256 + threadIdx.x;
    if (i < EE) atomicAdd(&hist[eidx[EE+i]], 1);
}
__global__ __launch_bounds__(512) void scanA_kernel(const int* __restrict__ hist,
                                                    int* __restrict__ scanv, int* __restrict__ bsum){
    __shared__ int s[512];
    const int tid = threadIdx.x;
    const int i = blockIdx.x*512 + tid;
    int v = hist[i];
    s[tid] = v;
    __syncthreads();
    #pragma unroll
    for (int d=1; d<512; d<<=1){
        int t = (tid>=d) ? s[tid-d] : 0;
        __syncthreads();
        s[tid] += t;
        __syncthreads();
    }
    scanv[i] = s[tid] - v;
    if (tid==511) bsum[blockIdx.x] = s[511];
}
__global__ __launch_bounds__(256) void scanB_kernel(const int* __restrict__ bsum, int* __restrict__ boff){
    __shared__ int s[256];
    const int tid = threadIdx.x;
    int v = (tid<196) ? bsum[tid] : 0;
    s[tid] = v;
    __syncthreads();
    #pragma unroll
    for (int d=1; d<256; d<<=1){
        int t = (tid>=d) ? s[tid-d] : 0;
        __syncthreads();
        s[tid] += t;
        __syncthreads();
    }
    if (tid<196) boff[tid] = s[tid] - v;
}
__global__ __launch_bounds__(256) void scatter_kernel(const int* __restrict__ eidx,
    const int* __restrict__ scanv, const int* __restrict__ boff, int* __restrict__ cnt,
    int* __restrict__ sSrc)
{
    int i = blockIdx.x*256 + threadIdx.x;
    if (i >= EE) return;
    int t = eidx[EE+i], sv = eidx[i];
    int r = atomicAdd(&cnt[t], 1);
    int pos = scanv[t] + boff[t>>9] + r;
    sSrc[pos] = sv;
}

// ---------------- Stage 1: node prep (proven) ----------------
__global__ __launch_bounds__(512) void node_kernel(
    const float* __restrict__ x,
    const short* __restrict__ wSP, const float* __restrict__ sp_b,
    const float* __restrict__ ln1_g, const float* __restrict__ ln1_b,
    const float* __restrict__ pg,
    const short* __restrict__ wA, const float* __restrict__ amp_b,
    const short* __restrict__ wP, const float* __restrict__ ph_b,
    short* __restrict__ qfb)
{
    __shared__ short xb[64*128];
    __shared__ float yb[64*132];
    __shared__ short qsb[64*128];
    __shared__ float pgs[64];

    const int tid = threadIdx.x;
    const int lane = tid & 63;
    const int w    = tid >> 6;
    const int l15  = lane & 15;
    const int lj   = (lane >> 4) << 2;
    const int n0   = blockIdx.x * 64;

    if (tid < 64){
        float s = 0.f;
        #pragma unroll
        for (int r=0;r<8;r++) s += pg[r*64 + tid];
        pgs[tid] = s;
    }
    for (int t = tid; t < 1024; t += 512){
        int e = t >> 4, c8 = t & 15;
        int n = n0 + e; if (n >= NN) n = NN-1;
        const float4* xg = (const float4*)(x + (long)n*128 + c8*8);
        float4 a = xg[0], b = xg[1];
        short8 sv;
        sv[0]=f2bf(a.x); sv[1]=f2bf(a.y); sv[2]=f2bf(a.z); sv[3]=f2bf(a.w);
        sv[4]=f2bf(b.x); sv[5]=f2bf(b.y); sv[6]=f2bf(b.z); sv[7]=f2bf(b.w);
        ((short8*)xb)[C16(e, c8)] = sv;
    }
    __syncthreads();

    const short8* xbv = (const short8*)xb;
    const int col = (w<<4) + l15;

    {
        f32x4 acc[4];
        #pragma unroll
        for (int r=0;r<4;r++) acc[r]=Z4;
        #pragma unroll
        for (int ks=0; ks<4; ks++){
            short8 bw = bfrag(wSP,128,w,ks,lane);
            #pragma unroll
            for (int r=0;r<4;r++){
                int row = r*16+l15;
                acc[r] = mfma16(xbv[(row<<4) + (((ks<<2)+(lane>>4)) ^ (row&7))], bw, acc[r]);
            }
        }
        float bias = sp_b[col];
        #pragma unroll
        for (int r=0;r<4;r++){
            #pragma unroll
            for (int j=0;j<4;j++)
                yb[(r*16+lj+j)*132 + col] = acc[r][j] + bias;
        }
    }
    __syncthreads();

    {
        const int row = tid >> 3, cs = tid & 7;
        float v[16];
        float s = 0.f, sq = 0.f;
        #pragma unroll
        for (int i=0;i<16;i++){
            v[i] = yb[row*132 + cs*16 + i];
            s += v[i]; sq += v[i]*v[i];
        }
        #pragma unroll
        for (int m=1;m<8;m<<=1){ s += __shfl_xor(s,m); sq += __shfl_xor(sq,m); }
        float mean = s*(1.0f/128.0f);
        float rstd = rsqrtf(sq*(1.0f/128.0f) - mean*mean + 1e-5f);
        short8 s0, s1;
        #pragma unroll
        for (int i=0;i<16;i++){
            int c = cs*16 + i;
            float q = tanhf((v[i]-mean)*rstd*ln1_g[c] + ln1_b[c]);
            if (i<8) s0[i] = f2bf(q); else s1[i-8] = f2bf(q);
        }
        ((short8*)qsb)[C16(row, cs*2  )] = s0;
        ((short8*)qsb)[C16(row, cs*2+1)] = s1;
    }
    __syncthreads();

    {
        const short8* qv = (const short8*)qsb;
        const int isPh = w >> 2;
        const int ct   = w & 3;
        f32x4 a4[4];
        #pragma unroll
        for (int r=0;r<4;r++) a4[r]=Z4;
        #pragma unroll
        for (int ks=0; ks<2; ks++){
            short8 bw = bfrag(isPh ? wP : wA, 64, ct, ks, lane);
            #pragma unroll
            for (int r=0;r<4;r++){
                int row = r*16+l15;
                int ch = isPh*8 + (ks<<2)+(lane>>4);
                a4[r] = mfma16(qv[(row<<4) + (ch ^ (row&7))], bw, a4[r]);
            }
        }
        const int oc = ct*16 + l15;
        float bs = isPh ? ph_b[oc] : amp_b[oc];
        #pragma unroll
        for (int r=0;r<4;r++){
            #pragma unroll
            for (int j=0;j<4;j++){
                float vv = a4[r][j] + bs;
                float ov = isPh ? tanhf(vv)*3.14159265358979323846f
                                : 1.0f/(1.0f+expf(-vv));
                yb[(r*16+lj+j)*132 + isPh*64 + oc] = ov;
            }
        }
    }
    __syncthreads();

    {
        const int row = tid >> 3, cs = tid & 7;
        const int n = n0 + row;
        short8 outc, outs;
        #pragma unroll
        for (int i=0;i<8;i++){
            int c = cs*8 + i;
            float amp  = yb[row*132 + c];
            float ph   = yb[row*132 + 64 + c];
            float real = bf2f(qsb[E16(row, c)]);
            float ang  = ph + real*pgs[c];
            outc[i] = f2bf(amp * cosf(ang));
            outs[i] = f2bf(amp * sinf(ang));
        }
        if (n < NN){
            *(short8*)(qfb + (long)n*128 + cs*8)      = outc;
            *(short8*)(qfb + (long)n*128 + 64 + cs*8) = outs;
        }
    }
}

// ---------------- node GEMMs -> packed knvp[n][512] = kn | vn | pb | qn ----------------
__global__ __launch_bounds__(512) void qkvpb_kernel(
    const short* __restrict__ qfb,
    const short* __restrict__ wK, const float* __restrict__ k_b,
    const short* __restrict__ wV, const float* __restrict__ v_b,
    const short* __restrict__ wQ, const float* __restrict__ q_b,
    const short* __restrict__ wCi, const short* __restrict__ wCj,
    short* __restrict__ knvp)
{
    __shared__ short a1[64*128];
    const int tid=threadIdx.x, lane=tid&63, w=tid>>6;
    const int l15=lane&15, lh=lane>>4, lj=lh<<2;
    const long n0=(long)blockIdx.x*64;
    for (int t=tid;t<1024;t+=512){
        int e=t>>4,c8=t&15;
        ((short8*)a1)[C16(e,c8)] = ((const short8*)(qfb+(n0+e)*128))[c8];
    }
    __syncthreads();
    short8 A[4][4];
    #pragma unroll
    for (int rt=0;rt<4;rt++)
        #pragma unroll
        for (int ks=0;ks<4;ks++)
            A[rt][ks] = ((const short8*)a1)[C16(rt*16+l15, (ks<<2)+lh)];
    const int col = (w<<4)+l15;

    // K
    {
        f32x4 acc[4];
        #pragma unroll
        for (int rt=0;rt<4;rt++) acc[rt]=Z4;
        #pragma unroll
        for (int ks=0;ks<4;ks++){
            short8 b = *(const short8*)(wK + (long)col*128 + ks*32 + lh*8);
            #pragma unroll
            for (int rt=0;rt<4;rt++) acc[rt]=mfma16(A[rt][ks],b,acc[rt]);
        }
        float bias=k_b[col];
        #pragma unroll
        for (int rt=0;rt<4;rt++)
            #pragma unroll
            for (int j=0;j<4;j++)
                knvp[(n0+rt*16+lj+j)*512 + col]=f2bf(acc[rt][j]+bias);
    }
    // V
    {
        f32x4 acc[4];
        #pragma unroll
        for (int rt=0;rt<4;rt++) acc[rt]=Z4;
        #pragma unroll
        for (int ks=0;ks<4;ks++){
            short8 b = *(const short8*)(wV + (long)col*128 + ks*32 + lh*8);
            #pragma unroll
            for (int rt=0;rt<4;rt++) acc[rt]=mfma16(A[rt][ks],b,acc[rt]);
        }
        float bias=v_b[col];
        #pragma unroll
        for (int rt=0;rt<4;rt++)
            #pragma unroll
            for (int j=0;j<4;j++)
                knvp[(n0+rt*16+lj+j)*512 + 128 + col]=f2bf(acc[rt][j]+bias);
    }
    // Q -> slot 384 (walk consumes it, then overwrites the slot with S)
    {
        f32x4 acc[4];
        #pragma unroll
        for (int rt=0;rt<4;rt++) acc[rt]=Z4;
        #pragma unroll
        for (int ks=0;ks<4;ks++){
            short8 b = *(const short8*)(wQ + (long)col*128 + ks*32 + lh*8);
            #pragma unroll
            for (int rt=0;rt<4;rt++) acc[rt]=mfma16(A[rt][ks],b,acc[rt]);
        }
        float bias=q_b[col];
        #pragma unroll
        for (int rt=0;rt<4;rt++)
            #pragma unroll
            for (int j=0;j<4;j++)
                knvp[(n0+rt*16+lj+j)*512 + 384 + col]=f2bf(acc[rt][j]+bias);
    }
    // PB = sum_kk Bi ⊙ Bj  (b-slices of wCi/wCj: cols 128:256)
    {
        f32x4 pbacc[4];
        #pragma unroll
        for (int rt=0;rt<4;rt++) pbacc[rt]=Z4;
        #pragma unroll 1
        for (int kk=0;kk<4;kk++){
            short8 bi[4], bj[4];
            #pragma unroll
            for (int ks=0;ks<4;ks++){
                bi[ks] = *(const short8*)(wCi + (long)kk*32768 + (long)col*256 + 128 + ks*32 + lh*8);
                bj[ks] = *(const short8*)(wCj + (long)kk*32768 + (long)col*256 + 128 + ks*32 + lh*8);
            }
            #pragma unroll
            for (int rt=0;rt<4;rt++){
                f32x4 ai=Z4, aj=Z4;
                #pragma unroll
                for (int ks=0;ks<4;ks++){
                    ai = mfma16(A[rt][ks], bi[ks], ai);
                    aj = mfma16(A[rt][ks], bj[ks], aj);
                }
                #pragma unroll
                for (int j=0;j<4;j++) pbacc[rt][j] += ai[j]*aj[j];
            }
        }
        #pragma unroll
        for (int rt=0;rt<4;rt++)
            #pragma unroll
            for (int j=0;j<4;j++)
                knvp[(n0+rt*16+lj+j)*512 + 256 + col]=f2bf(pbacc[rt][j]);
    }
}

// ---------------- walk: 1 node/wave, ZERO LDS, max occupancy ----------------
__global__ __launch_bounds__(256) void walk_kernel(
    const short* __restrict__ qfb, short* __restrict__ knvp,
    const int* __restrict__ sSrc, const int* __restrict__ hist,
    const int* __restrict__ scanv, const int* __restrict__ boff,
    short* __restrict__ aqmpb)
{
    const int tid=threadIdx.x, lane=tid&63, w=tid>>6;
    const int n = blockIdx.x*4 + w;          // 100000 = 25000*4 exact
    const int g = lane >> 4;                 // edge slot 0..3
    const int cl = (lane & 15) * 8;          // cols cl..cl+7
    const float sc = 0.17677669529663688f;

    const int rp0 = scanv[n] + boff[n>>9];
    const int dg  = hist[n];

    float q8[8];
    {
        short8 qv = *(const short8*)(knvp + (long)n*512 + 384 + cl);
        #pragma unroll
        for (int i=0;i<8;i++) q8[i]=bf2f(qv[i]);
    }
    float aq[8], s[8], p[8];
    #pragma unroll
    for (int i=0;i<8;i++){ aq[i]=0.f; s[i]=0.f; p[i]=0.f; }

    bool vCur = (g < dg);
    int  sCur = vCur ? sSrc[rp0+g] : 0;
    const short* bCur = knvp + (long)sCur*512;
    short8 k8 = *(const short8*)(bCur + cl);
    short8 v8 = *(const short8*)(bCur + 128 + cl);
    short8 p8 = *(const short8*)(bCur + 256 + cl);
    short8 f8 = *(const short8*)(qfb + (long)sCur*128 + cl);

    #pragma unroll 1
    for (int e=0; e<dg; e+=4){
        const int en = e + 4 + g;
        const bool vN = (en < dg);
        const int  sN = vN ? sSrc[rp0+en] : 0;
        const short* bN = knvp + (long)sN*512;
        short8 kN = *(const short8*)(bN + cl);
        short8 vN8= *(const short8*)(bN + 128 + cl);
        short8 pN = *(const short8*)(bN + 256 + cl);
        short8 fN = *(const short8*)(qfb + (long)sN*128 + cl);

        float d = 0.f;
        #pragma unroll
        for (int i=0;i<8;i++) d += q8[i]*bf2f(k8[i]);
        d += __shfl_xor(d,1); d += __shfl_xor(d,2);      // head sum
        d *= sc;
        float mx = fmaxf(d, __shfl_xor(d,4));
        mx = fmaxf(mx, __shfl_xor(mx,8));                 // max over heads
        float eh = expf(d - mx);
        float den = eh;
        den += __shfl_xor(den,4); den += __shfl_xor(den,8);
        float wgt = vCur ? (eh/den) : 0.f;
        float mv  = vCur ? 1.f : 0.f;
        #pragma unroll
        for (int i=0;i<8;i++){
            aq[i] += wgt * bf2f(v8[i]);
            s[i]  += mv  * bf2f(f8[i]);
            p[i]  += mv  * bf2f(p8[i]);
        }
        k8=kN; v8=vN8; p8=pN; f8=fN; vCur=vN;
    }
    #pragma unroll
    for (int i=0;i<8;i++){
        aq[i] += __shfl_xor(aq[i],16); aq[i] += __shfl_xor(aq[i],32);
        s[i]  += __shfl_xor(s[i],16);  s[i]  += __shfl_xor(s[i],32);
        p[i]  += __shfl_xor(p[i],16);  p[i]  += __shfl_xor(p[i],32);
    }
    if (lane < 16){
        short8 av, pv, sv;
        #pragma unroll
        for (int i=0;i<8;i++){ av[i]=f2bf(aq[i]); pv[i]=f2bf(p[i]); sv[i]=f2bf(s[i]); }
        *(short8*)(aqmpb + (long)n*256 + cl)       = av;
        *(short8*)(aqmpb + (long)n*256 + 128 + cl) = pv;
        *(short8*)(knvp  + (long)n*512 + 384 + cl) = sv;   // S over dead qn slot
    }
}

// ---------------- final: 64 nodes/block; weight loads amortized over 4 row-tiles ----------------
__global__ __launch_bounds__(256) void final_kernel(
    const short* __restrict__ qfb, const short* __restrict__ knvp,
    const int* __restrict__ hist,
    const short* __restrict__ wCi, const short* __restrict__ wCj,
    const float* __restrict__ bci, const float* __restrict__ bcj,
    const short* __restrict__ wO, const float* __restrict__ out_b,
    const float* __restrict__ g2, const float* __restrict__ b2,
    const short* __restrict__ aqmpb, float* __restrict__ outp)
{
    __shared__ __align__(16) char smem[65536];
    __shared__ int degs[64];
    short* a1   = (short*)smem;            // 16 KB qf tile (swz); msgb overlay
    short* Sbf  = (short*)(smem + 16384);  // 16 KB S bf16 (swz)
    short* AQMb = (short*)(smem + 32768);  // 16 KB AQM bf16 [64][128] linear
    short* PBb  = (short*)(smem + 49152);  // 16 KB PB bf16 [64][128] linear
    float* yb   = (float*)(smem + 16384);  // 32 KB overlay (Sbf+AQMb) for OUT result

    const int tid=threadIdx.x, lane=tid&63, w=tid>>6;   // 4 waves
    const int l15=lane&15, lh=lane>>4, lj=lh<<2;
    const long n0=(long)blockIdx.x*64;

    if (tid < 64) degs[tid] = hist[n0+tid];
    for (int t=tid;t<1024;t+=256){
        int e=t>>4,c8=t&15;
        long n = n0+e; if (n >= NN) n = NN-1;
        ((short8*)a1)[C16(e,c8)]  = ((const short8*)(qfb+n*128))[c8];
        ((short8*)Sbf)[C16(e,c8)] = *(const short8*)(knvp + n*512 + 384 + c8*8);
        *(short8*)(AQMb + e*128 + c8*8) = *(const short8*)(aqmpb + n*256 + c8*8);
        *(short8*)(PBb  + e*128 + c8*8) = *(const short8*)(aqmpb + n*256 + 128 + c8*8);
    }
    __syncthreads();                                       // B1

    const short8* a1v = (const short8*)a1;
    const short8* sfv = (const short8*)Sbf;
    const int col0 = (2*w)*16 + l15;
    const int col1 = (2*w+1)*16 + l15;

    // ---- cross GEMMs: A/S frags from LDS, 4 row-tiles per B-frag batch ----
    f32x4 tt[2][4], cr[2][4];
    #pragma unroll
    for (int ci=0;ci<2;ci++)
        #pragma unroll
        for (int rt=0;rt<4;rt++){ tt[ci][rt]=Z4; cr[ci][rt]=Z4; }

    #pragma unroll 1
    for (int kk=0; kk<4; kk++){
        #pragma unroll
        for (int ci=0; ci<2; ci++){
            const int col = ci ? col1 : col0;
            const long wb = (long)kk*32768 + (long)col*256;
            short8 Pa[4], Pj[4];
            #pragma unroll
            for (int ks=0;ks<4;ks++){
                Pa[ks] = *(const short8*)(wCi + wb + ks*32 + lh*8);
                Pj[ks] = *(const short8*)(wCj + wb + ks*32 + lh*8);
            }
            f32x4 aiA[4], ajA[4];
            #pragma unroll
            for (int rt=0;rt<4;rt++){
                f32x4 ai=Z4, aj=Z4;
                #pragma unroll
                for (int ks=0;ks<4;ks++){
                    short8 fq = a1v[C16(rt*16+l15,(ks<<2)+lh)];
                    ai = mfma16(fq, Pa[ks], ai);
                    aj = mfma16(fq, Pj[ks], aj);
                }
                aiA[rt]=ai; ajA[rt]=aj;
            }
            short8 Qa[4], Qj[4];
            #pragma unroll
            for (int ks=0;ks<4;ks++){
                Qa[ks] = *(const short8*)(wCi + wb + 128 + ks*32 + lh*8);
                Qj[ks] = *(const short8*)(wCj + wb + 128 + ks*32 + lh*8);
            }
            float ci_=bci[kk*128+col], cj_=bcj[kk*128+col];
            #pragma unroll
            for (int rt=0;rt<4;rt++){
                f32x4 sbi=Z4, sbj=Z4;
                #pragma unroll
                for (int ks=0;ks<4;ks++){
                    short8 fs = sfv[C16(rt*16+l15,(ks<<2)+lh)];
                    sbi = mfma16(fs, Qa[ks], sbi);
                    sbj = mfma16(fs, Qj[ks], sbj);
                }
                #pragma unroll
                for (int j=0;j<4;j++){
                    float AI = aiA[rt][j]+ci_, AJ = ajA[rt][j]+cj_;
                    tt[ci][rt][j] += AI*AJ;
                    cr[ci][rt][j] += AI*sbj[j] + sbi[j]*AJ;
                }
            }
        }
    }
    __syncthreads();                                       // B2 (a1/Sbf reads done)

    // ---- msum (AQM/PB from LDS), write msgb over a1 ----
    short* msgb = a1;
    #pragma unroll
    for (int ci=0;ci<2;ci++){
        const int col = ci ? col1 : col0;
        #pragma unroll
        for (int rt=0;rt<4;rt++){
            #pragma unroll
            for (int j=0;j<4;j++){
                int row = rt*16+lj+j;
                float ms = bf2f(AQMb[row*128 + col])
                         + 0.25f*((float)degs[row]*tt[ci][rt][j] + cr[ci][rt][j]
                                  + bf2f(PBb[row*128 + col]));
                msgb[(C16(row, col>>3)<<3) + (col&7)] = f2bf(ms);
            }
        }
    }
    __syncthreads();                                       // B3

    // ---- OUT GEMM -> yb (overlays Sbf+AQMb) ----
    const short8* mbv = (const short8*)msgb;
    #pragma unroll
    for (int ci=0; ci<2; ci++){
        const int col = ci ? col1 : col0;
        short8 bo[4];
        #pragma unroll
        for (int ks=0;ks<4;ks++)
            bo[ks] = *(const short8*)(wO + (long)col*128 + ks*32 + lh*8);
        float ob = out_b[col];
        #pragma unroll
        for (int rt=0;rt<4;rt++){
            f32x4 ao=Z4;
            #pragma unroll
            for (int ks=0;ks<4;ks++)
                ao = mfma16(mbv[C16(rt*16+l15,(ks<<2)+lh)], bo[ks], ao);
            #pragma unroll
            for (int j=0;j<4;j++){
                int row = rt*16+lj+j;
                yb[(row<<7) + (col ^ (row&31))] = ao[j] + (float)degs[row]*ob;
            }
        }
    }
    __syncthreads();                                       // B4

    // ---- LN + exact gelu (two 32-row halves) ----
    #pragma unroll
    for (int half=0; half<2; half++){
        const int row = half*32 + (tid>>3), cs = tid&7;
        const long n = n0+row;
        float v[16]; float sum=0.f, sq=0.f;
        #pragma unroll
        for (int i=0;i<16;i++){
            v[i]=yb[(row<<7)+((cs*16+i)^(row&31))];
            sum+=v[i]; sq+=v[i]*v[i];
        }
        #pragma unroll
        for (int m=1;m<8;m<<=1){ sum+=__shfl_xor(sum,m); sq+=__shfl_xor(sq,m); }
        float mean=sum*(1.0f/128.0f);
        float rstd=rsqrtf(sq*(1.0f/128.0f)-mean*mean+1e-5f);
        if (n < NN){
            float o[16];
            #pragma unroll
            for (int i=0;i<16;i++){
                int c=cs*16+i;
                float y=(v[i]-mean)*rstd*g2[c]+b2[c];
                o[i]=0.5f*y*(1.0f+erff(y*0.70710678118f));
            }
            float* dst = outp + n*128 + cs*16;
            #pragma unroll
            for (int i=0;i<4;i++)
                ((float4*)dst)[i] = (float4){o[i*4],o[i*4+1],o[i*4+2],o[i*4+3]};
        }
    }
}

extern "C" void kernel_launch(void* const* d_in, const int* in_sizes, int n_in,
                              void* d_out, int out_size, void* d_ws, size_t ws_size,
                              hipStream_t stream)
{
    const float* x      = (const float*)d_in[0];
    const int*   eidx   = (const int*)  d_in[1];
    const float* sp_w   = (const float*)d_in[2];
    const float* sp_b   = (const float*)d_in[3];
    const float* ln1_g  = (const float*)d_in[4];
    const float* ln1_b  = (const float*)d_in[5];
    const float* pg     = (const float*)d_in[6];
    const float* amp_w  = (const float*)d_in[7];
    const float* amp_b  = (const float*)d_in[8];
    const float* ph_w   = (const float*)d_in[9];
    const float* ph_b   = (const float*)d_in[10];
    const float* ent_w  = (const float*)d_in[11];
    const float* ent_b  = (const float*)d_in[12];
    const float* q_w    = (const float*)d_in[13];
    const float* q_b    = (const float*)d_in[14];
    const float* k_w    = (const float*)d_in[15];
    const float* k_b    = (const float*)d_in[16];
    const float* v_w    = (const float*)d_in[17];
    const float* v_b    = (const float*)d_in[18];
    const float* meas_w = (const float*)d_in[19];
    const float* meas_b = (const float*)d_in[20];
    const float* out_w  = (const float*)d_in[21];
    const float* out_b  = (const float*)d_in[22];
    const float* ln2_g  = (const float*)d_in[23];
    const float* ln2_b  = (const float*)d_in[24];

    char* wsb = (char*)d_ws;
    short* qfb  = (short*)(wsb + 0);               //  25,608,192
    short* knvp = (short*)(wsb + 25608192);        // 102,432,768
    short* wAll = (short*)(wsb + 128040960);       //     180,224
    short* wCi  = (short*)(wsb + 128221184);       //     262,144
    short* wCj  = (short*)(wsb + 128483328);       //     262,144
    float* bci  = (float*)(wsb + 128745472);       //       2,048
    float* bcj  = (float*)(wsb + 128747520);       //       2,048
    int* hist   = (int*)(wsb + 128749568);         //     401,408
    int* cnt    = (int*)(wsb + 129150976);         //     401,408
    int* scanv  = (int*)(wsb + 129552384);         //     401,408
    int* bsum   = (int*)(wsb + 129953792);         //       1,024
    int* boff   = (int*)(wsb + 129954816);         //       1,024
    int* sSrc   = (int*)(wsb + 129955840);         //   2,000,000 -> 131,955,840 total

    if (ws_size < 132000000ull) return;            // diagnostic guard

    short* wQ  = wAll;
    short* wK  = wAll + 16384;
    short* wV  = wAll + 32768;
    short* wO  = wAll + 49152;
    short* wSP = wAll + 65536;
    short* wA  = wAll + 81920;
    short* wP  = wAll + 86016;

    short* aqmpb = (short*)d_out;                  // bf16 AQM|PB packed in d_out

    hipMemsetAsync(hist, 0, 401408, stream);
    hipMemsetAsync(cnt,  0, 401408, stream);

    prep_kernel<<<352, 256, 0, stream>>>(q_w, k_w, v_w, out_w, sp_w, amp_w, ph_w, wAll);
    combine_kernel<<<512, 256, 0, stream>>>(ent_w, meas_w, wCi, wCj);
    combine_bias_kernel<<<4, 256, 0, stream>>>(meas_w, ent_b, meas_b, bci, bcj);
    node_kernel<<<NNB, 512, 0, stream>>>(x, wSP, sp_b, ln1_g, ln1_b, pg,
                                         wA, amp_b, wP, ph_b, qfb);
    hist_kernel<<<(EE+255)/256, 256, 0, stream>>>(eidx, hist);
    scanA_kernel<<<196, 512, 0, stream>>>(hist, scanv, bsum);
    scanB_kernel<<<1, 256, 0, stream>>>(bsum, boff);
    scatter_kernel<<<(EE+255)/256, 256, 0, stream>>>(eidx, scanv, boff, cnt, sSrc);
    qkvpb_kernel<<<NNB, 512, 0, stream>>>(qfb, wK, k_b, wV, v_b, wQ, q_b,
                                          wCi, wCj, knvp);
    walk_kernel<<<NWB, 256, 0, stream>>>(qfb, knvp, sSrc, hist, scanv, boff, aqmpb);
    final_kernel<<<NFB2, 256, 0, stream>>>(qfb, knvp, hist,
                                           wCi, wCj, bci, bcj, wO, out_b,
                                           ln2_g, ln2_b, aqmpb, (float*)d_out);
}

// Round 22
// 452.239 us; speedup vs baseline: 1.3764x; 1.1416x over previous
//
#include <hip/hip_runtime.h>
#include <math.h>

#define NN 100000
#define EE 500000
#define NNB  1563            // 64-node blocks (qkvpb/node)
#define NFB2 1563            // final: 64 nodes/block
#define NWB  25000           // walk: 4 nodes/block

typedef __attribute__((ext_vector_type(8))) short short8;
typedef __attribute__((ext_vector_type(4))) float f32x4;
#define Z4 (f32x4){0,0,0,0}

#define C16(row, ch) (((row)<<4) + ((ch) ^ ((row)&7)))
#define E16(row, col) ((C16((row),(col)>>3)<<3) + ((col)&7))

__device__ __forceinline__ f32x4 mfma16(short8 a, short8 b, f32x4 c){
    return __builtin_amdgcn_mfma_f32_16x16x32_bf16(a, b, c, 0, 0, 0);
}
__device__ __forceinline__ short f2bf(float f){
    union { float f; unsigned u; } v; v.f = f;
    unsigned r = v.u + 0x7fffu + ((v.u >> 16) & 1u);
    return (short)(r >> 16);
}
__device__ __forceinline__ float bf2f(short s){
    union { unsigned u; float f; } v; v.u = ((unsigned)(unsigned short)s) << 16;
    return v.f;
}
__device__ __forceinline__ short8 bfrag(const short* __restrict__ W, int K, int ct, int ks, int lane){
    return *(const short8*)(W + (long)(ct*16 + (lane&15))*K + ks*32 + (lane>>4)*8);
}
// fragment-order index for a [128][128] weight: load = 1KB contiguous per wave
__device__ __forceinline__ int fragmap(int o, int k){
    return (((o>>4)*4 + (k>>5))*64 + (((k>>3)&3)*16 + (o&15)))*8 + (k&7);
}

// ---------------- prep: bf16 weights (q/k/v/out frag-ordered; sp/amp/ph linear) ----------------
__global__ __launch_bounds__(256) void prep_kernel(
    const float* __restrict__ q_w, const float* __restrict__ k_w,
    const float* __restrict__ v_w, const float* __restrict__ out_w,
    const float* __restrict__ sp_w, const float* __restrict__ amp_w,
    const float* __restrict__ ph_w, short* __restrict__ dst)
{
    int i = blockIdx.x*256 + threadIdx.x;   // 90112
    if (i >= 90112) return;
    float v; int base = -1, loc = 0;
    if      (i < 16384){ v = q_w[i];         base = 0;     loc = i; }
    else if (i < 32768){ v = k_w[i-16384];   base = 16384; loc = i-16384; }
    else if (i < 49152){ v = v_w[i-32768];   base = 32768; loc = i-32768; }
    else if (i < 65536){ v = out_w[i-49152]; base = 49152; loc = i-49152; }
    else if (i < 81920) v = sp_w[i-65536];
    else if (i < 86016) v = amp_w[i-81920];
    else                v = ph_w[i-86016];
    if (base >= 0) dst[base + fragmap(loc>>7, loc&127)] = f2bf(v);
    else           dst[i] = f2bf(v);
}

// ---------------- combined weights (frag-ordered): idx(kk,o,c) ----------------
__global__ __launch_bounds__(256) void combine_kernel(
    const float* __restrict__ ent_w, const float* __restrict__ meas_w,
    short* __restrict__ wCi, short* __restrict__ wCj)
{
    const int b = blockIdx.x;          // 512
    const int kk = b >> 7, half = (b >> 6) & 1, ot = (b >> 3) & 7, ct = b & 7;
    const int tid = threadIdx.x;
    const int o = ot*16 + (tid >> 4);
    const int c = ct*32 + (tid & 15)*2;
    const float* mrow  = meas_w + ((long)(kk*128 + o) << 7);
    const float* wbase = ent_w + (long)(half*128)*256 + c;
    float a0 = 0.f, a1 = 0.f;
    #pragma unroll 8
    for (int k = 0; k < 128; k++){
        float m = mrow[k];
        float2 wv = *(const float2*)(wbase + (long)k*256);
        a0 = fmaf(m, wv.x, a0);
        a1 = fmaf(m, wv.y, a1);
    }
    // fragment-order: (((kk*8+ct_o)*2+halfc)*4+ks)*512 + lane*8 + ii
    const int ct_o = o>>4, l15o = o&15;
    const int halfc = c>>7, cr = c&127;
    const int ksn = cr>>5, lhn = (cr>>3)&3, iin = cr&7;
    const long idx = ((((long)(kk*8 + ct_o)*2 + halfc)*4 + ksn)*64 + (lhn*16 + l15o))*8 + iin;
    short* dst = (half ? wCj : wCi) + idx;
    dst[0] = f2bf(a0); dst[1] = f2bf(a1);
}
__global__ __launch_bounds__(256) void combine_bias_kernel(
    const float* __restrict__ meas_w, const float* __restrict__ ent_b,
    const float* __restrict__ meas_b,
    float* __restrict__ bci, float* __restrict__ bcj)
{
    int id = blockIdx.x*256 + threadIdx.x;  // 1024
    int kk = id >> 8, half = (id >> 7) & 1, o = id & 127;
    const float* mrow = meas_w + ((long)(kk*128 + o) << 7);
    const float* eb = ent_b + half*128;
    float a = meas_b[kk*128 + o];
    #pragma unroll 8
    for (int k = 0; k < 128; k++) a = fmaf(mrow[k], eb[k], a);
    (half ? bcj : bci)[kk*128 + o] = a;
}

// ---------------- counting sort by tgt (src list only) ----------------
__global__ __launch_bounds__(256) void hist_kernel(const int* __restrict__ eidx, int* __restrict__ hist){
    int i = blockIdx.x*256 + threadIdx.x;
    if (i < EE) atomicAdd(&hist[eidx[EE+i]], 1);
}
__global__ __launch_bounds__(512) void scanA_kernel(const int* __restrict__ hist,
                                                    int* __restrict__ scanv, int* __restrict__ bsum){
    __shared__ int s[512];
    const int tid = threadIdx.x;
    const int i = blockIdx.x*512 + tid;
    int v = hist[i];
    s[tid] = v;
    __syncthreads();
    #pragma unroll
    for (int d=1; d<512; d<<=1){
        int t = (tid>=d) ? s[tid-d] : 0;
        __syncthreads();
        s[tid] += t;
        __syncthreads();
    }
    scanv[i] = s[tid] - v;
    if (tid==511) bsum[blockIdx.x] = s[511];
}
__global__ __launch_bounds__(256) void scanB_kernel(const int* __restrict__ bsum, int* __restrict__ boff){
    __shared__ int s[256];
    const int tid = threadIdx.x;
    int v = (tid<196) ? bsum[tid] : 0;
    s[tid] = v;
    __syncthreads();
    #pragma unroll
    for (int d=1; d<256; d<<=1){
        int t = (tid>=d) ? s[tid-d] : 0;
        __syncthreads();
        s[tid] += t;
        __syncthreads();
    }
    if (tid<196) boff[tid] = s[tid] - v;
}
__global__ __launch_bounds__(256) void scatter_kernel(const int* __restrict__ eidx,
    const int* __restrict__ scanv, const int* __restrict__ boff, int* __restrict__ cnt,
    int* __restrict__ sSrc)
{
    int i = blockIdx.x*256 + threadIdx.x;
    if (i >= EE) return;
    int t = eidx[EE+i], sv = eidx[i];
    int r = atomicAdd(&cnt[t], 1);
    int pos = scanv[t] + boff[t>>9] + r;
    sSrc[pos] = sv;
}

// ---------------- Stage 1: node prep (proven) ----------------
__global__ __launch_bounds__(512) void node_kernel(
    const float* __restrict__ x,
    const short* __restrict__ wSP, const float* __restrict__ sp_b,
    const float* __restrict__ ln1_g, const float* __restrict__ ln1_b,
    const float* __restrict__ pg,
    const short* __restrict__ wA, const float* __restrict__ amp_b,
    const short* __restrict__ wP, const float* __restrict__ ph_b,
    short* __restrict__ qfb)
{
    __shared__ short xb[64*128];
    __shared__ float yb[64*132];
    __shared__ short qsb[64*128];
    __shared__ float pgs[64];

    const int tid = threadIdx.x;
    const int lane = tid & 63;
    const int w    = tid >> 6;
    const int l15  = lane & 15;
    const int lj   = (lane >> 4) << 2;
    const int n0   = blockIdx.x * 64;

    if (tid < 64){
        float s = 0.f;
        #pragma unroll
        for (int r=0;r<8;r++) s += pg[r*64 + tid];
        pgs[tid] = s;
    }
    for (int t = tid; t < 1024; t += 512){
        int e = t >> 4, c8 = t & 15;
        int n = n0 + e; if (n >= NN) n = NN-1;
        const float4* xg = (const float4*)(x + (long)n*128 + c8*8);
        float4 a = xg[0], b = xg[1];
        short8 sv;
        sv[0]=f2bf(a.x); sv[1]=f2bf(a.y); sv[2]=f2bf(a.z); sv[3]=f2bf(a.w);
        sv[4]=f2bf(b.x); sv[5]=f2bf(b.y); sv[6]=f2bf(b.z); sv[7]=f2bf(b.w);
        ((short8*)xb)[C16(e, c8)] = sv;
    }
    __syncthreads();

    const short8* xbv = (const short8*)xb;
    const int col = (w<<4) + l15;

    {
        f32x4 acc[4];
        #pragma unroll
        for (int r=0;r<4;r++) acc[r]=Z4;
        #pragma unroll
        for (int ks=0; ks<4; ks++){
            short8 bw = bfrag(wSP,128,w,ks,lane);
            #pragma unroll
            for (int r=0;r<4;r++){
                int row = r*16+l15;
                acc[r] = mfma16(xbv[(row<<4) + (((ks<<2)+(lane>>4)) ^ (row&7))], bw, acc[r]);
            }
        }
        float bias = sp_b[col];
        #pragma unroll
        for (int r=0;r<4;r++){
            #pragma unroll
            for (int j=0;j<4;j++)
                yb[(r*16+lj+j)*132 + col] = acc[r][j] + bias;
        }
    }
    __syncthreads();

    {
        const int row = tid >> 3, cs = tid & 7;
        float v[16];
        float s = 0.f, sq = 0.f;
        #pragma unroll
        for (int i=0;i<16;i++){
            v[i] = yb[row*132 + cs*16 + i];
            s += v[i]; sq += v[i]*v[i];
        }
        #pragma unroll
        for (int m=1;m<8;m<<=1){ s += __shfl_xor(s,m); sq += __shfl_xor(sq,m); }
        float mean = s*(1.0f/128.0f);
        float rstd = rsqrtf(sq*(1.0f/128.0f) - mean*mean + 1e-5f);
        short8 s0, s1;
        #pragma unroll
        for (int i=0;i<16;i++){
            int c = cs*16 + i;
            float q = tanhf((v[i]-mean)*rstd*ln1_g[c] + ln1_b[c]);
            if (i<8) s0[i] = f2bf(q); else s1[i-8] = f2bf(q);
        }
        ((short8*)qsb)[C16(row, cs*2  )] = s0;
        ((short8*)qsb)[C16(row, cs*2+1)] = s1;
    }
    __syncthreads();

    {
        const short8* qv = (const short8*)qsb;
        const int isPh = w >> 2;
        const int ct   = w & 3;
        f32x4 a4[4];
        #pragma unroll
        for (int r=0;r<4;r++) a4[r]=Z4;
        #pragma unroll
        for (int ks=0; ks<2; ks++){
            short8 bw = bfrag(isPh ? wP : wA, 64, ct, ks, lane);
            #pragma unroll
            for (int r=0;r<4;r++){
                int row = r*16+l15;
                int ch = isPh*8 + (ks<<2)+(lane>>4);
                a4[r] = mfma16(qv[(row<<4) + (ch ^ (row&7))], bw, a4[r]);
            }
        }
        const int oc = ct*16 + l15;
        float bs = isPh ? ph_b[oc] : amp_b[oc];
        #pragma unroll
        for (int r=0;r<4;r++){
            #pragma unroll
            for (int j=0;j<4;j++){
                float vv = a4[r][j] + bs;
                float ov = isPh ? tanhf(vv)*3.14159265358979323846f
                                : 1.0f/(1.0f+expf(-vv));
                yb[(r*16+lj+j)*132 + isPh*64 + oc] = ov;
            }
        }
    }
    __syncthreads();

    {
        const int row = tid >> 3, cs = tid & 7;
        const int n = n0 + row;
        short8 outc, outs;
        #pragma unroll
        for (int i=0;i<8;i++){
            int c = cs*8 + i;
            float amp  = yb[row*132 + c];
            float ph   = yb[row*132 + 64 + c];
            float real = bf2f(qsb[E16(row, c)]);
            float ang  = ph + real*pgs[c];
            outc[i] = f2bf(amp * cosf(ang));
            outs[i] = f2bf(amp * sinf(ang));
        }
        if (n < NN){
            *(short8*)(qfb + (long)n*128 + cs*8)      = outc;
            *(short8*)(qfb + (long)n*128 + 64 + cs*8) = outs;
        }
    }
}

// ---------------- node GEMMs -> packed knvp[n][512] = kn | vn | pb | qn ----------------
__global__ __launch_bounds__(512) void qkvpb_kernel(
    const short* __restrict__ qfb,
    const short* __restrict__ wK, const float* __restrict__ k_b,
    const short* __restrict__ wV, const float* __restrict__ v_b,
    const short* __restrict__ wQ, const float* __restrict__ q_b,
    const short* __restrict__ wCi, const short* __restrict__ wCj,
    short* __restrict__ knvp)
{
    __shared__ short a1[64*128];
    const int tid=threadIdx.x, lane=tid&63, w=tid>>6;
    const int l15=lane&15, lh=lane>>4, lj=lh<<2;
    const long n0=(long)blockIdx.x*64;
    for (int t=tid;t<1024;t+=512){
        int e=t>>4,c8=t&15;
        ((short8*)a1)[C16(e,c8)] = ((const short8*)(qfb+(n0+e)*128))[c8];
    }
    __syncthreads();
    short8 A[4][4];
    #pragma unroll
    for (int rt=0;rt<4;rt++)
        #pragma unroll
        for (int ks=0;ks<4;ks++)
            A[rt][ks] = ((const short8*)a1)[C16(rt*16+l15, (ks<<2)+lh)];
    const int col = (w<<4)+l15;

    // K (frag-ordered loads: 1KB contiguous per wave)
    {
        f32x4 acc[4];
        #pragma unroll
        for (int rt=0;rt<4;rt++) acc[rt]=Z4;
        #pragma unroll
        for (int ks=0;ks<4;ks++){
            short8 b = *(const short8*)(wK + ((w*4+ks)*64 + lane)*8);
            #pragma unroll
            for (int rt=0;rt<4;rt++) acc[rt]=mfma16(A[rt][ks],b,acc[rt]);
        }
        float bias=k_b[col];
        #pragma unroll
        for (int rt=0;rt<4;rt++)
            #pragma unroll
            for (int j=0;j<4;j++)
                knvp[(n0+rt*16+lj+j)*512 + col]=f2bf(acc[rt][j]+bias);
    }
    // V
    {
        f32x4 acc[4];
        #pragma unroll
        for (int rt=0;rt<4;rt++) acc[rt]=Z4;
        #pragma unroll
        for (int ks=0;ks<4;ks++){
            short8 b = *(const short8*)(wV + ((w*4+ks)*64 + lane)*8);
            #pragma unroll
            for (int rt=0;rt<4;rt++) acc[rt]=mfma16(A[rt][ks],b,acc[rt]);
        }
        float bias=v_b[col];
        #pragma unroll
        for (int rt=0;rt<4;rt++)
            #pragma unroll
            for (int j=0;j<4;j++)
                knvp[(n0+rt*16+lj+j)*512 + 128 + col]=f2bf(acc[rt][j]+bias);
    }
    // Q -> slot 384
    {
        f32x4 acc[4];
        #pragma unroll
        for (int rt=0;rt<4;rt++) acc[rt]=Z4;
        #pragma unroll
        for (int ks=0;ks<4;ks++){
            short8 b = *(const short8*)(wQ + ((w*4+ks)*64 + lane)*8);
            #pragma unroll
            for (int rt=0;rt<4;rt++) acc[rt]=mfma16(A[rt][ks],b,acc[rt]);
        }
        float bias=q_b[col];
        #pragma unroll
        for (int rt=0;rt<4;rt++)
            #pragma unroll
            for (int j=0;j<4;j++)
                knvp[(n0+rt*16+lj+j)*512 + 384 + col]=f2bf(acc[rt][j]+bias);
    }
    // PB = sum_kk Bi ⊙ Bj (b-halves, frag-ordered)
    {
        f32x4 pbacc[4];
        #pragma unroll
        for (int rt=0;rt<4;rt++) pbacc[rt]=Z4;
        #pragma unroll 1
        for (int kk=0;kk<4;kk++){
            short8 bi[4], bj[4];
            #pragma unroll
            for (int ks=0;ks<4;ks++){
                long fi = (((long)(kk*8 + w)*2 + 1)*4 + ks)*512 + lane*8;
                bi[ks] = *(const short8*)(wCi + fi);
                bj[ks] = *(const short8*)(wCj + fi);
            }
            #pragma unroll
            for (int rt=0;rt<4;rt++){
                f32x4 ai=Z4, aj=Z4;
                #pragma unroll
                for (int ks=0;ks<4;ks++){
                    ai = mfma16(A[rt][ks], bi[ks], ai);
                    aj = mfma16(A[rt][ks], bj[ks], aj);
                }
                #pragma unroll
                for (int j=0;j<4;j++) pbacc[rt][j] += ai[j]*aj[j];
            }
        }
        #pragma unroll
        for (int rt=0;rt<4;rt++)
            #pragma unroll
            for (int j=0;j<4;j++)
                knvp[(n0+rt*16+lj+j)*512 + 256 + col]=f2bf(pbacc[rt][j]);
    }
}

// ---------------- walk: 1 node/wave, ZERO LDS ----------------
__global__ __launch_bounds__(256) void walk_kernel(
    const short* __restrict__ qfb, short* __restrict__ knvp,
    const int* __restrict__ sSrc, const int* __restrict__ hist,
    const int* __restrict__ scanv, const int* __restrict__ boff,
    short* __restrict__ aqmpb)
{
    const int tid=threadIdx.x, lane=tid&63, w=tid>>6;
    const int n = blockIdx.x*4 + w;
    const int g = lane >> 4;
    const int cl = (lane & 15) * 8;
    const float sc = 0.17677669529663688f;

    const int rp0 = scanv[n] + boff[n>>9];
    const int dg  = hist[n];

    float q8[8];
    {
        short8 qv = *(const short8*)(knvp + (long)n*512 + 384 + cl);
        #pragma unroll
        for (int i=0;i<8;i++) q8[i]=bf2f(qv[i]);
    }
    float aq[8], s[8], p[8];
    #pragma unroll
    for (int i=0;i<8;i++){ aq[i]=0.f; s[i]=0.f; p[i]=0.f; }

    bool vCur = (g < dg);
    int  sCur = vCur ? sSrc[rp0+g] : 0;
    const short* bCur = knvp + (long)sCur*512;
    short8 k8 = *(const short8*)(bCur + cl);
    short8 v8 = *(const short8*)(bCur + 128 + cl);
    short8 p8 = *(const short8*)(bCur + 256 + cl);
    short8 f8 = *(const short8*)(qfb + (long)sCur*128 + cl);

    #pragma unroll 1
    for (int e=0; e<dg; e+=4){
        const int en = e + 4 + g;
        const bool vN = (en < dg);
        const int  sN = vN ? sSrc[rp0+en] : 0;
        const short* bN = knvp + (long)sN*512;
        short8 kN = *(const short8*)(bN + cl);
        short8 vN8= *(const short8*)(bN + 128 + cl);
        short8 pN = *(const short8*)(bN + 256 + cl);
        short8 fN = *(const short8*)(qfb + (long)sN*128 + cl);

        float d = 0.f;
        #pragma unroll
        for (int i=0;i<8;i++) d += q8[i]*bf2f(k8[i]);
        d += __shfl_xor(d,1); d += __shfl_xor(d,2);
        d *= sc;
        float mx = fmaxf(d, __shfl_xor(d,4));
        mx = fmaxf(mx, __shfl_xor(mx,8));
        float eh = expf(d - mx);
        float den = eh;
        den += __shfl_xor(den,4); den += __shfl_xor(den,8);
        float wgt = vCur ? (eh/den) : 0.f;
        float mv  = vCur ? 1.f : 0.f;
        #pragma unroll
        for (int i=0;i<8;i++){
            aq[i] += wgt * bf2f(v8[i]);
            s[i]  += mv  * bf2f(f8[i]);
            p[i]  += mv  * bf2f(p8[i]);
        }
        k8=kN; v8=vN8; p8=pN; f8=fN; vCur=vN;
    }
    #pragma unroll
    for (int i=0;i<8;i++){
        aq[i] += __shfl_xor(aq[i],16); aq[i] += __shfl_xor(aq[i],32);
        s[i]  += __shfl_xor(s[i],16);  s[i]  += __shfl_xor(s[i],32);
        p[i]  += __shfl_xor(p[i],16);  p[i]  += __shfl_xor(p[i],32);
    }
    if (lane < 16){
        short8 av, pv, sv;
        #pragma unroll
        for (int i=0;i<8;i++){ av[i]=f2bf(aq[i]); pv[i]=f2bf(p[i]); sv[i]=f2bf(s[i]); }
        *(short8*)(aqmpb + (long)n*256 + cl)       = av;
        *(short8*)(aqmpb + (long)n*256 + 128 + cl) = pv;
        *(short8*)(knvp  + (long)n*512 + 384 + cl) = sv;
    }
}

// ---------------- final: 64 nodes/block; frag-ordered weight loads ----------------
__global__ __launch_bounds__(256) void final_kernel(
    const short* __restrict__ qfb, const short* __restrict__ knvp,
    const int* __restrict__ hist,
    const short* __restrict__ wCi, const short* __restrict__ wCj,
    const float* __restrict__ bci, const float* __restrict__ bcj,
    const short* __restrict__ wO, const float* __restrict__ out_b,
    const float* __restrict__ g2, const float* __restrict__ b2,
    const short* __restrict__ aqmpb, float* __restrict__ outp)
{
    __shared__ __align__(16) char smem[65536];
    __shared__ int degs[64];
    short* a1   = (short*)smem;            // 16 KB qf tile (swz); msgb overlay
    short* Sbf  = (short*)(smem + 16384);  // 16 KB S bf16 (swz)
    short* AQMb = (short*)(smem + 32768);  // 16 KB AQM bf16 [64][128] linear
    short* PBb  = (short*)(smem + 49152);  // 16 KB PB bf16 [64][128] linear
    float* yb   = (float*)(smem + 16384);  // 32 KB overlay (Sbf+AQMb) for OUT result

    const int tid=threadIdx.x, lane=tid&63, w=tid>>6;
    const int l15=lane&15, lh=lane>>4, lj=lh<<2;
    const long n0=(long)blockIdx.x*64;

    if (tid < 64) degs[tid] = hist[n0+tid];
    for (int t=tid;t<1024;t+=256){
        int e=t>>4,c8=t&15;
        long n = n0+e; if (n >= NN) n = NN-1;
        ((short8*)a1)[C16(e,c8)]  = ((const short8*)(qfb+n*128))[c8];
        ((short8*)Sbf)[C16(e,c8)] = *(const short8*)(knvp + n*512 + 384 + c8*8);
        *(short8*)(AQMb + e*128 + c8*8) = *(const short8*)(aqmpb + n*256 + c8*8);
        *(short8*)(PBb  + e*128 + c8*8) = *(const short8*)(aqmpb + n*256 + 128 + c8*8);
    }
    __syncthreads();                                       // B1

    const short8* a1v = (const short8*)a1;
    const short8* sfv = (const short8*)Sbf;
    const int col0 = (2*w)*16 + l15;
    const int col1 = (2*w+1)*16 + l15;

    // ---- cross GEMMs: frag-ordered weight loads (contiguous 1KB/wave) ----
    f32x4 tt[2][4], cr[2][4];
    #pragma unroll
    for (int ci=0;ci<2;ci++)
        #pragma unroll
        for (int rt=0;rt<4;rt++){ tt[ci][rt]=Z4; cr[ci][rt]=Z4; }

    #pragma unroll 1
    for (int kk=0; kk<4; kk++){
        #pragma unroll
        for (int ci=0; ci<2; ci++){
            const int ctt = 2*w + ci;
            const int col = ci ? col1 : col0;
            const long fb = (long)(kk*8 + ctt)*8;   // 8 ks-blocks: [0..3]=a-half, [4..7]=b-half
            short8 Pa[4], Pj[4];
            #pragma unroll
            for (int ks=0;ks<4;ks++){
                Pa[ks] = *(const short8*)(wCi + (fb + ks)*512 + lane*8);
                Pj[ks] = *(const short8*)(wCj + (fb + ks)*512 + lane*8);
            }
            f32x4 aiA[4], ajA[4];
            #pragma unroll
            for (int rt=0;rt<4;rt++){
                f32x4 ai=Z4, aj=Z4;
                #pragma unroll
                for (int ks=0;ks<4;ks++){
                    short8 fq = a1v[C16(rt*16+l15,(ks<<2)+lh)];
                    ai = mfma16(fq, Pa[ks], ai);
                    aj = mfma16(fq, Pj[ks], aj);
                }
                aiA[rt]=ai; ajA[rt]=aj;
            }
            short8 Qa[4], Qj[4];
            #pragma unroll
            for (int ks=0;ks<4;ks++){
                Qa[ks] = *(const short8*)(wCi + (fb + 4 + ks)*512 + lane*8);
                Qj[ks] = *(const short8*)(wCj + (fb + 4 + ks)*512 + lane*8);
            }
            float ci_=bci[kk*128+col], cj_=bcj[kk*128+col];
            #pragma unroll
            for (int rt=0;rt<4;rt++){
                f32x4 sbi=Z4, sbj=Z4;
                #pragma unroll
                for (int ks=0;ks<4;ks++){
                    short8 fs = sfv[C16(rt*16+l15,(ks<<2)+lh)];
                    sbi = mfma16(fs, Qa[ks], sbi);
                    sbj = mfma16(fs, Qj[ks], sbj);
                }
                #pragma unroll
                for (int j=0;j<4;j++){
                    float AI = aiA[rt][j]+ci_, AJ = ajA[rt][j]+cj_;
                    tt[ci][rt][j] += AI*AJ;
                    cr[ci][rt][j] += AI*sbj[j] + sbi[j]*AJ;
                }
            }
        }
    }
    __syncthreads();                                       // B2

    // ---- msum (AQM/PB from LDS), write msgb over a1 ----
    short* msgb = a1;
    #pragma unroll
    for (int ci=0;ci<2;ci++){
        const int col = ci ? col1 : col0;
        #pragma unroll
        for (int rt=0;rt<4;rt++){
            #pragma unroll
            for (int j=0;j<4;j++){
                int row = rt*16+lj+j;
                float ms = bf2f(AQMb[row*128 + col])
                         + 0.25f*((float)degs[row]*tt[ci][rt][j] + cr[ci][rt][j]
                                  + bf2f(PBb[row*128 + col]));
                msgb[(C16(row, col>>3)<<3) + (col&7)] = f2bf(ms);
            }
        }
    }
    __syncthreads();                                       // B3

    // ---- OUT GEMM -> yb (frag-ordered wO) ----
    const short8* mbv = (const short8*)msgb;
    #pragma unroll
    for (int ci=0; ci<2; ci++){
        const int ctt = 2*w + ci;
        const int col = ci ? col1 : col0;
        short8 bo[4];
        #pragma unroll
        for (int ks=0;ks<4;ks++)
            bo[ks] = *(const short8*)(wO + ((long)(ctt*4+ks))*512 + lane*8);
        float ob = out_b[col];
        #pragma unroll
        for (int rt=0;rt<4;rt++){
            f32x4 ao=Z4;
            #pragma unroll
            for (int ks=0;ks<4;ks++)
                ao = mfma16(mbv[C16(rt*16+l15,(ks<<2)+lh)], bo[ks], ao);
            #pragma unroll
            for (int j=0;j<4;j++){
                int row = rt*16+lj+j;
                yb[(row<<7) + (col ^ (row&31))] = ao[j] + (float)degs[row]*ob;
            }
        }
    }
    __syncthreads();                                       // B4

    // ---- LN + exact gelu (two 32-row halves) ----
    #pragma unroll
    for (int half=0; half<2; half++){
        const int row = half*32 + (tid>>3), cs = tid&7;
        const long n = n0+row;
        float v[16]; float sum=0.f, sq=0.f;
        #pragma unroll
        for (int i=0;i<16;i++){
            v[i]=yb[(row<<7)+((cs*16+i)^(row&31))];
            sum+=v[i]; sq+=v[i]*v[i];
        }
        #pragma unroll
        for (int m=1;m<8;m<<=1){ sum+=__shfl_xor(sum,m); sq+=__shfl_xor(sq,m); }
        float mean=sum*(1.0f/128.0f);
        float rstd=rsqrtf(sq*(1.0f/128.0f)-mean*mean+1e-5f);
        if (n < NN){
            float o[16];
            #pragma unroll
            for (int i=0;i<16;i++){
                int c=cs*16+i;
                float y=(v[i]-mean)*rstd*g2[c]+b2[c];
                o[i]=0.5f*y*(1.0f+erff(y*0.70710678118f));
            }
            float* dst = outp + n*128 + cs*16;
            #pragma unroll
            for (int i=0;i<4;i++)
                ((float4*)dst)[i] = (float4){o[i*4],o[i*4+1],o[i*4+2],o[i*4+3]};
        }
    }
}

extern "C" void kernel_launch(void* const* d_in, const int* in_sizes, int n_in,
                              void* d_out, int out_size, void* d_ws, size_t ws_size,
                              hipStream_t stream)
{
    const float* x      = (const float*)d_in[0];
    const int*   eidx   = (const int*)  d_in[1];
    const float* sp_w   = (const float*)d_in[2];
    const float* sp_b   = (const float*)d_in[3];
    const float* ln1_g  = (const float*)d_in[4];
    const float* ln1_b  = (const float*)d_in[5];
    const float* pg     = (const float*)d_in[6];
    const float* amp_w  = (const float*)d_in[7];
    const float* amp_b  = (const float*)d_in[8];
    const float* ph_w   = (const float*)d_in[9];
    const float* ph_b   = (const float*)d_in[10];
    const float* ent_w  = (const float*)d_in[11];
    const float* ent_b  = (const float*)d_in[12];
    const float* q_w    = (const float*)d_in[13];
    const float* q_b    = (const float*)d_in[14];
    const float* k_w    = (const float*)d_in[15];
    const float* k_b    = (const float*)d_in[16];
    const float* v_w    = (const float*)d_in[17];
    const float* v_b    = (const float*)d_in[18];
    const float* meas_w = (const float*)d_in[19];
    const float* meas_b = (const float*)d_in[20];
    const float* out_w  = (const float*)d_in[21];
    const float* out_b  = (const float*)d_in[22];
    const float* ln2_g  = (const float*)d_in[23];
    const float* ln2_b  = (const float*)d_in[24];

    char* wsb = (char*)d_ws;
    short* qfb  = (short*)(wsb + 0);               //  25,608,192
    short* knvp = (short*)(wsb + 25608192);        // 102,432,768
    short* wAll = (short*)(wsb + 128040960);       //     180,224
    short* wCi  = (short*)(wsb + 128221184);       //     262,144
    short* wCj  = (short*)(wsb + 128483328);       //     262,144
    float* bci  = (float*)(wsb + 128745472);       //       2,048
    float* bcj  = (float*)(wsb + 128747520);       //       2,048
    int* hist   = (int*)(wsb + 128749568);         //     401,408
    int* cnt    = (int*)(wsb + 129150976);         //     401,408
    int* scanv  = (int*)(wsb + 129552384);         //     401,408
    int* bsum   = (int*)(wsb + 129953792);         //       1,024
    int* boff   = (int*)(wsb + 129954816);         //       1,024
    int* sSrc   = (int*)(wsb + 129955840);         //   2,000,000 -> 131,955,840 total

    if (ws_size < 132000000ull) return;            // diagnostic guard

    short* wQ  = wAll;
    short* wK  = wAll + 16384;
    short* wV  = wAll + 32768;
    short* wO  = wAll + 49152;
    short* wSP = wAll + 65536;
    short* wA  = wAll + 81920;
    short* wP  = wAll + 86016;

    short* aqmpb = (short*)d_out;                  // bf16 AQM|PB packed in d_out

    hipMemsetAsync(hist, 0, 401408, stream);
    hipMemsetAsync(cnt,  0, 401408, stream);

    prep_kernel<<<352, 256, 0, stream>>>(q_w, k_w, v_w, out_w, sp_w, amp_w, ph_w, wAll);
    combine_kernel<<<512, 256, 0, stream>>>(ent_w, meas_w, wCi, wCj);
    combine_bias_kernel<<<4, 256, 0, stream>>>(meas_w, ent_b, meas_b, bci, bcj);
    node_kernel<<<NNB, 512, 0, stream>>>(x, wSP, sp_b, ln1_g, ln1_b, pg,
                                         wA, amp_b, wP, ph_b, qfb);
    hist_kernel<<<(EE+255)/256, 256, 0, stream>>>(eidx, hist);
    scanA_kernel<<<196, 512, 0, stream>>>(hist, scanv, bsum);
    scanB_kernel<<<1, 256, 0, stream>>>(bsum, boff);
    scatter_kernel<<<(EE+255)/256, 256, 0, stream>>>(eidx, scanv, boff, cnt, sSrc);
    qkvpb_kernel<<<NNB, 512, 0, stream>>>(qfb, wK, k_b, wV, v_b, wQ, q_b,
                                          wCi, wCj, knvp);
    walk_kernel<<<NWB, 256, 0, stream>>>(qfb, knvp, sSrc, hist, scanv, boff, aqmpb);
    final_kernel<<<NFB2, 256, 0, stream>>>(qfb, knvp, hist,
                                           wCi, wCj, bci, bcj, wO, out_b,
                                           ln2_g, ln2_b, aqmpb, (float*)d_out);
}

// Round 23
// 442.635 us; speedup vs baseline: 1.4062x; 1.0217x over previous
//
#include <hip/hip_runtime.h>
#include <math.h>

#define NN 100000
#define EE 500000
#define NNB  1563            // 64-node blocks (qkvpb/node)
#define NFB2 1563            // final: 64 nodes/block
#define NWB  25000           // walk: 4 nodes/block

typedef __attribute__((ext_vector_type(8))) short short8;
typedef __attribute__((ext_vector_type(4))) float f32x4;
#define Z4 (f32x4){0,0,0,0}

#define C16(row, ch) (((row)<<4) + ((ch) ^ ((row)&7)))
#define E16(row, col) ((C16((row),(col)>>3)<<3) + ((col)&7))

__device__ __forceinline__ f32x4 mfma16(short8 a, short8 b, f32x4 c){
    return __builtin_amdgcn_mfma_f32_16x16x32_bf16(a, b, c, 0, 0, 0);
}
__device__ __forceinline__ short f2bf(float f){
    union { float f; unsigned u; } v; v.f = f;
    unsigned r = v.u + 0x7fffu + ((v.u >> 16) & 1u);
    return (short)(r >> 16);
}
__device__ __forceinline__ float bf2f(short s){
    union { unsigned u; float f; } v; v.u = ((unsigned)(unsigned short)s) << 16;
    return v.f;
}
__device__ __forceinline__ short8 bfrag(const short* __restrict__ W, int K, int ct, int ks, int lane){
    return *(const short8*)(W + (long)(ct*16 + (lane&15))*K + ks*32 + (lane>>4)*8);
}
// fragment-order index for a [128][128] weight: load = 1KB contiguous per wave
__device__ __forceinline__ int fragmap(int o, int k){
    return (((o>>4)*4 + (k>>5))*64 + (((k>>3)&3)*16 + (o&15)))*8 + (k&7);
}

// ---------------- prep: bf16 weights (q/k/v/out frag-ordered; sp/amp/ph linear) ----------------
__global__ __launch_bounds__(256) void prep_kernel(
    const float* __restrict__ q_w, const float* __restrict__ k_w,
    const float* __restrict__ v_w, const float* __restrict__ out_w,
    const float* __restrict__ sp_w, const float* __restrict__ amp_w,
    const float* __restrict__ ph_w, short* __restrict__ dst)
{
    int i = blockIdx.x*256 + threadIdx.x;   // 90112
    if (i >= 90112) return;
    float v; int base = -1, loc = 0;
    if      (i < 16384){ v = q_w[i];         base = 0;     loc = i; }
    else if (i < 32768){ v = k_w[i-16384];   base = 16384; loc = i-16384; }
    else if (i < 49152){ v = v_w[i-32768];   base = 32768; loc = i-32768; }
    else if (i < 65536){ v = out_w[i-49152]; base = 49152; loc = i-49152; }
    else if (i < 81920) v = sp_w[i-65536];
    else if (i < 86016) v = amp_w[i-81920];
    else                v = ph_w[i-86016];
    if (base >= 0) dst[base + fragmap(loc>>7, loc&127)] = f2bf(v);
    else           dst[i] = f2bf(v);
}

// ---------------- combined weights (frag-ordered): idx(kk,o,c) ----------------
__global__ __launch_bounds__(256) void combine_kernel(
    const float* __restrict__ ent_w, const float* __restrict__ meas_w,
    short* __restrict__ wCi, short* __restrict__ wCj)
{
    const int b = blockIdx.x;          // 512
    const int kk = b >> 7, half = (b >> 6) & 1, ot = (b >> 3) & 7, ct = b & 7;
    const int tid = threadIdx.x;
    const int o = ot*16 + (tid >> 4);
    const int c = ct*32 + (tid & 15)*2;
    const float* mrow  = meas_w + ((long)(kk*128 + o) << 7);
    const float* wbase = ent_w + (long)(half*128)*256 + c;
    float a0 = 0.f, a1 = 0.f;
    #pragma unroll 8
    for (int k = 0; k < 128; k++){
        float m = mrow[k];
        float2 wv = *(const float2*)(wbase + (long)k*256);
        a0 = fmaf(m, wv.x, a0);
        a1 = fmaf(m, wv.y, a1);
    }
    const int ct_o = o>>4, l15o = o&15;
    const int halfc = c>>7, cr = c&127;
    const int ksn = cr>>5, lhn = (cr>>3)&3, iin = cr&7;
    const long idx = ((((long)(kk*8 + ct_o)*2 + halfc)*4 + ksn)*64 + (lhn*16 + l15o))*8 + iin;
    short* dst = (half ? wCj : wCi) + idx;
    dst[0] = f2bf(a0); dst[1] = f2bf(a1);
}
__global__ __launch_bounds__(256) void combine_bias_kernel(
    const float* __restrict__ meas_w, const float* __restrict__ ent_b,
    const float* __restrict__ meas_b,
    float* __restrict__ bci, float* __restrict__ bcj)
{
    int id = blockIdx.x*256 + threadIdx.x;  // 1024
    int kk = id >> 8, half = (id >> 7) & 1, o = id & 127;
    const float* mrow = meas_w + ((long)(kk*128 + o) << 7);
    const float* eb = ent_b + half*128;
    float a = meas_b[kk*128 + o];
    #pragma unroll 8
    for (int k = 0; k < 128; k++) a = fmaf(mrow[k], eb[k], a);
    (half ? bcj : bci)[kk*128 + o] = a;
}

// ---------------- counting sort by tgt (src list only) ----------------
__global__ __launch_bounds__(256) void hist_kernel(const int* __restrict__ eidx, int* __restrict__ hist){
    int i = blockIdx.x*256 + threadIdx.x;
    if (i < EE) atomicAdd(&hist[eidx[EE+i]], 1);
}
__global__ __launch_bounds__(512) void scanA_kernel(const int* __restrict__ hist,
                                                    int* __restrict__ scanv, int* __restrict__ bsum){
    __shared__ int s[512];
    const int tid = threadIdx.x;
    const int i = blockIdx.x*512 + tid;
    int v = hist[i];
    s[tid] = v;
    __syncthreads();
    #pragma unroll
    for (int d=1; d<512; d<<=1){
        int t = (tid>=d) ? s[tid-d] : 0;
        __syncthreads();
        s[tid] += t;
        __syncthreads();
    }
    scanv[i] = s[tid] - v;
    if (tid==511) bsum[blockIdx.x] = s[511];
}
__global__ __launch_bounds__(256) void scanB_kernel(const int* __restrict__ bsum, int* __restrict__ boff){
    __shared__ int s[256];
    const int tid = threadIdx.x;
    int v = (tid<196) ? bsum[tid] : 0;
    s[tid] = v;
    __syncthreads();
    #pragma unroll
    for (int d=1; d<256; d<<=1){
        int t = (tid>=d) ? s[tid-d] : 0;
        __syncthreads();
        s[tid] += t;
        __syncthreads();
    }
    if (tid<196) boff[tid] = s[tid] - v;
}
__global__ __launch_bounds__(256) void scatter_kernel(const int* __restrict__ eidx,
    const int* __restrict__ scanv, const int* __restrict__ boff, int* __restrict__ cnt,
    int* __restrict__ sSrc)
{
    int i = blockIdx.x*256 + threadIdx.x;
    if (i >= EE) return;
    int t = eidx[EE+i], sv = eidx[i];
    int r = atomicAdd(&cnt[t], 1);
    int pos = scanv[t] + boff[t>>9] + r;
    sSrc[pos] = sv;
}

// ---------------- Stage 1: node prep (proven) ----------------
__global__ __launch_bounds__(512) void node_kernel(
    const float* __restrict__ x,
    const short* __restrict__ wSP, const float* __restrict__ sp_b,
    const float* __restrict__ ln1_g, const float* __restrict__ ln1_b,
    const float* __restrict__ pg,
    const short* __restrict__ wA, const float* __restrict__ amp_b,
    const short* __restrict__ wP, const float* __restrict__ ph_b,
    short* __restrict__ qfb)
{
    __shared__ short xb[64*128];
    __shared__ float yb[64*132];
    __shared__ short qsb[64*128];
    __shared__ float pgs[64];

    const int tid = threadIdx.x;
    const int lane = tid & 63;
    const int w    = tid >> 6;
    const int l15  = lane & 15;
    const int lj   = (lane >> 4) << 2;
    const int n0   = blockIdx.x * 64;

    if (tid < 64){
        float s = 0.f;
        #pragma unroll
        for (int r=0;r<8;r++) s += pg[r*64 + tid];
        pgs[tid] = s;
    }
    for (int t = tid; t < 1024; t += 512){
        int e = t >> 4, c8 = t & 15;
        int n = n0 + e; if (n >= NN) n = NN-1;
        const float4* xg = (const float4*)(x + (long)n*128 + c8*8);
        float4 a = xg[0], b = xg[1];
        short8 sv;
        sv[0]=f2bf(a.x); sv[1]=f2bf(a.y); sv[2]=f2bf(a.z); sv[3]=f2bf(a.w);
        sv[4]=f2bf(b.x); sv[5]=f2bf(b.y); sv[6]=f2bf(b.z); sv[7]=f2bf(b.w);
        ((short8*)xb)[C16(e, c8)] = sv;
    }
    __syncthreads();

    const short8* xbv = (const short8*)xb;
    const int col = (w<<4) + l15;

    {
        f32x4 acc[4];
        #pragma unroll
        for (int r=0;r<4;r++) acc[r]=Z4;
        #pragma unroll
        for (int ks=0; ks<4; ks++){
            short8 bw = bfrag(wSP,128,w,ks,lane);
            #pragma unroll
            for (int r=0;r<4;r++){
                int row = r*16+l15;
                acc[r] = mfma16(xbv[(row<<4) + (((ks<<2)+(lane>>4)) ^ (row&7))], bw, acc[r]);
            }
        }
        float bias = sp_b[col];
        #pragma unroll
        for (int r=0;r<4;r++){
            #pragma unroll
            for (int j=0;j<4;j++)
                yb[(r*16+lj+j)*132 + col] = acc[r][j] + bias;
        }
    }
    __syncthreads();

    {
        const int row = tid >> 3, cs = tid & 7;
        float v[16];
        float s = 0.f, sq = 0.f;
        #pragma unroll
        for (int i=0;i<16;i++){
            v[i] = yb[row*132 + cs*16 + i];
            s += v[i]; sq += v[i]*v[i];
        }
        #pragma unroll
        for (int m=1;m<8;m<<=1){ s += __shfl_xor(s,m); sq += __shfl_xor(sq,m); }
        float mean = s*(1.0f/128.0f);
        float rstd = rsqrtf(sq*(1.0f/128.0f) - mean*mean + 1e-5f);
        short8 s0, s1;
        #pragma unroll
        for (int i=0;i<16;i++){
            int c = cs*16 + i;
            float q = tanhf((v[i]-mean)*rstd*ln1_g[c] + ln1_b[c]);
            if (i<8) s0[i] = f2bf(q); else s1[i-8] = f2bf(q);
        }
        ((short8*)qsb)[C16(row, cs*2  )] = s0;
        ((short8*)qsb)[C16(row, cs*2+1)] = s1;
    }
    __syncthreads();

    {
        const short8* qv = (const short8*)qsb;
        const int isPh = w >> 2;
        const int ct   = w & 3;
        f32x4 a4[4];
        #pragma unroll
        for (int r=0;r<4;r++) a4[r]=Z4;
        #pragma unroll
        for (int ks=0; ks<2; ks++){
            short8 bw = bfrag(isPh ? wP : wA, 64, ct, ks, lane);
            #pragma unroll
            for (int r=0;r<4;r++){
                int row = r*16+l15;
                int ch = isPh*8 + (ks<<2)+(lane>>4);
                a4[r] = mfma16(qv[(row<<4) + (ch ^ (row&7))], bw, a4[r]);
            }
        }
        const int oc = ct*16 + l15;
        float bs = isPh ? ph_b[oc] : amp_b[oc];
        #pragma unroll
        for (int r=0;r<4;r++){
            #pragma unroll
            for (int j=0;j<4;j++){
                float vv = a4[r][j] + bs;
                float ov = isPh ? tanhf(vv)*3.14159265358979323846f
                                : 1.0f/(1.0f+expf(-vv));
                yb[(r*16+lj+j)*132 + isPh*64 + oc] = ov;
            }
        }
    }
    __syncthreads();

    {
        const int row = tid >> 3, cs = tid & 7;
        const int n = n0 + row;
        short8 outc, outs;
        #pragma unroll
        for (int i=0;i<8;i++){
            int c = cs*8 + i;
            float amp  = yb[row*132 + c];
            float ph   = yb[row*132 + 64 + c];
            float real = bf2f(qsb[E16(row, c)]);
            float ang  = ph + real*pgs[c];
            outc[i] = f2bf(amp * cosf(ang));
            outs[i] = f2bf(amp * sinf(ang));
        }
        if (n < NN){
            *(short8*)(qfb + (long)n*128 + cs*8)      = outc;
            *(short8*)(qfb + (long)n*128 + 64 + cs*8) = outs;
        }
    }
}

// ---------------- node GEMMs -> packed knvp[n][512] = kn | vn | pb | qn ----------------
__global__ __launch_bounds__(512) void qkvpb_kernel(
    const short* __restrict__ qfb,
    const short* __restrict__ wK, const float* __restrict__ k_b,
    const short* __restrict__ wV, const float* __restrict__ v_b,
    const short* __restrict__ wQ, const float* __restrict__ q_b,
    const short* __restrict__ wCi, const short* __restrict__ wCj,
    short* __restrict__ knvp)
{
    __shared__ short a1[64*128];
    const int tid=threadIdx.x, lane=tid&63, w=tid>>6;
    const int l15=lane&15, lh=lane>>4, lj=lh<<2;
    const long n0=(long)blockIdx.x*64;
    for (int t=tid;t<1024;t+=512){
        int e=t>>4,c8=t&15;
        ((short8*)a1)[C16(e,c8)] = ((const short8*)(qfb+(n0+e)*128))[c8];
    }
    __syncthreads();
    short8 A[4][4];
    #pragma unroll
    for (int rt=0;rt<4;rt++)
        #pragma unroll
        for (int ks=0;ks<4;ks++)
            A[rt][ks] = ((const short8*)a1)[C16(rt*16+l15, (ks<<2)+lh)];
    const int col = (w<<4)+l15;

    // K (frag-ordered loads)
    {
        f32x4 acc[4];
        #pragma unroll
        for (int rt=0;rt<4;rt++) acc[rt]=Z4;
        #pragma unroll
        for (int ks=0;ks<4;ks++){
            short8 b = *(const short8*)(wK + ((w*4+ks)*64 + lane)*8);
            #pragma unroll
            for (int rt=0;rt<4;rt++) acc[rt]=mfma16(A[rt][ks],b,acc[rt]);
        }
        float bias=k_b[col];
        #pragma unroll
        for (int rt=0;rt<4;rt++)
            #pragma unroll
            for (int j=0;j<4;j++)
                knvp[(n0+rt*16+lj+j)*512 + col]=f2bf(acc[rt][j]+bias);
    }
    // V
    {
        f32x4 acc[4];
        #pragma unroll
        for (int rt=0;rt<4;rt++) acc[rt]=Z4;
        #pragma unroll
        for (int ks=0;ks<4;ks++){
            short8 b = *(const short8*)(wV + ((w*4+ks)*64 + lane)*8);
            #pragma unroll
            for (int rt=0;rt<4;rt++) acc[rt]=mfma16(A[rt][ks],b,acc[rt]);
        }
        float bias=v_b[col];
        #pragma unroll
        for (int rt=0;rt<4;rt++)
            #pragma unroll
            for (int j=0;j<4;j++)
                knvp[(n0+rt*16+lj+j)*512 + 128 + col]=f2bf(acc[rt][j]+bias);
    }
    // Q -> slot 384
    {
        f32x4 acc[4];
        #pragma unroll
        for (int rt=0;rt<4;rt++) acc[rt]=Z4;
        #pragma unroll
        for (int ks=0;ks<4;ks++){
            short8 b = *(const short8*)(wQ + ((w*4+ks)*64 + lane)*8);
            #pragma unroll
            for (int rt=0;rt<4;rt++) acc[rt]=mfma16(A[rt][ks],b,acc[rt]);
        }
        float bias=q_b[col];
        #pragma unroll
        for (int rt=0;rt<4;rt++)
            #pragma unroll
            for (int j=0;j<4;j++)
                knvp[(n0+rt*16+lj+j)*512 + 384 + col]=f2bf(acc[rt][j]+bias);
    }
    // PB = sum_kk Bi ⊙ Bj (b-halves, frag-ordered)
    {
        f32x4 pbacc[4];
        #pragma unroll
        for (int rt=0;rt<4;rt++) pbacc[rt]=Z4;
        #pragma unroll 1
        for (int kk=0;kk<4;kk++){
            short8 bi[4], bj[4];
            #pragma unroll
            for (int ks=0;ks<4;ks++){
                long fi = (((long)(kk*8 + w)*2 + 1)*4 + ks)*512 + lane*8;
                bi[ks] = *(const short8*)(wCi + fi);
                bj[ks] = *(const short8*)(wCj + fi);
            }
            #pragma unroll
            for (int rt=0;rt<4;rt++){
                f32x4 ai=Z4, aj=Z4;
                #pragma unroll
                for (int ks=0;ks<4;ks++){
                    ai = mfma16(A[rt][ks], bi[ks], ai);
                    aj = mfma16(A[rt][ks], bj[ks], aj);
                }
                #pragma unroll
                for (int j=0;j<4;j++) pbacc[rt][j] += ai[j]*aj[j];
            }
        }
        #pragma unroll
        for (int rt=0;rt<4;rt++)
            #pragma unroll
            for (int j=0;j<4;j++)
                knvp[(n0+rt*16+lj+j)*512 + 256 + col]=f2bf(pbacc[rt][j]);
    }
}

// ---------------- walk: 1 node/wave, ZERO LDS ----------------
__global__ __launch_bounds__(256) void walk_kernel(
    const short* __restrict__ qfb, short* __restrict__ knvp,
    const int* __restrict__ sSrc, const int* __restrict__ hist,
    const int* __restrict__ scanv, const int* __restrict__ boff,
    short* __restrict__ aqmpb)
{
    const int tid=threadIdx.x, lane=tid&63, w=tid>>6;
    const int n = blockIdx.x*4 + w;
    const int g = lane >> 4;
    const int cl = (lane & 15) * 8;
    const float sc = 0.17677669529663688f;

    const int rp0 = scanv[n] + boff[n>>9];
    const int dg  = hist[n];

    float q8[8];
    {
        short8 qv = *(const short8*)(knvp + (long)n*512 + 384 + cl);
        #pragma unroll
        for (int i=0;i<8;i++) q8[i]=bf2f(qv[i]);
    }
    float aq[8], s[8], p[8];
    #pragma unroll
    for (int i=0;i<8;i++){ aq[i]=0.f; s[i]=0.f; p[i]=0.f; }

    bool vCur = (g < dg);
    int  sCur = vCur ? sSrc[rp0+g] : 0;
    const short* bCur = knvp + (long)sCur*512;
    short8 k8 = *(const short8*)(bCur + cl);
    short8 v8 = *(const short8*)(bCur + 128 + cl);
    short8 p8 = *(const short8*)(bCur + 256 + cl);
    short8 f8 = *(const short8*)(qfb + (long)sCur*128 + cl);

    #pragma unroll 1
    for (int e=0; e<dg; e+=4){
        const int en = e + 4 + g;
        const bool vN = (en < dg);
        const int  sN = vN ? sSrc[rp0+en] : 0;
        const short* bN = knvp + (long)sN*512;
        short8 kN = *(const short8*)(bN + cl);
        short8 vN8= *(const short8*)(bN + 128 + cl);
        short8 pN = *(const short8*)(bN + 256 + cl);
        short8 fN = *(const short8*)(qfb + (long)sN*128 + cl);

        float d = 0.f;
        #pragma unroll
        for (int i=0;i<8;i++) d += q8[i]*bf2f(k8[i]);
        d += __shfl_xor(d,1); d += __shfl_xor(d,2);
        d *= sc;
        float mx = fmaxf(d, __shfl_xor(d,4));
        mx = fmaxf(mx, __shfl_xor(mx,8));
        float eh = expf(d - mx);
        float den = eh;
        den += __shfl_xor(den,4); den += __shfl_xor(den,8);
        float wgt = vCur ? (eh/den) : 0.f;
        float mv  = vCur ? 1.f : 0.f;
        #pragma unroll
        for (int i=0;i<8;i++){
            aq[i] += wgt * bf2f(v8[i]);
            s[i]  += mv  * bf2f(f8[i]);
            p[i]  += mv  * bf2f(p8[i]);
        }
        k8=kN; v8=vN8; p8=pN; f8=fN; vCur=vN;
    }
    #pragma unroll
    for (int i=0;i<8;i++){
        aq[i] += __shfl_xor(aq[i],16); aq[i] += __shfl_xor(aq[i],32);
        s[i]  += __shfl_xor(s[i],16);  s[i]  += __shfl_xor(s[i],32);
        p[i]  += __shfl_xor(p[i],16);  p[i]  += __shfl_xor(p[i],32);
    }
    if (lane < 16){
        short8 av, pv, sv;
        #pragma unroll
        for (int i=0;i<8;i++){ av[i]=f2bf(aq[i]); pv[i]=f2bf(p[i]); sv[i]=f2bf(s[i]); }
        *(short8*)(aqmpb + (long)n*256 + cl)       = av;
        *(short8*)(aqmpb + (long)n*256 + 128 + cl) = pv;
        *(short8*)(knvp  + (long)n*512 + 384 + cl) = sv;
    }
}

// ---------------- final: 64 nodes/block; 48KB LDS (AQM/PB read from global) ----------------
__global__ __launch_bounds__(256) void final_kernel(
    const short* __restrict__ qfb, const short* __restrict__ knvp,
    const int* __restrict__ hist,
    const short* __restrict__ wCi, const short* __restrict__ wCj,
    const float* __restrict__ bci, const float* __restrict__ bcj,
    const short* __restrict__ wO, const float* __restrict__ out_b,
    const float* __restrict__ g2, const float* __restrict__ b2,
    const short* __restrict__ aqmpb, float* __restrict__ outp)
{
    __shared__ __align__(16) char smem[49152];
    __shared__ int degs[64];
    short* a1   = (short*)smem;            // 16 KB qf tile (swz); msgb overlay
    short* Sbf  = (short*)(smem + 16384);  // 16 KB S bf16 (swz); yb overlays after cross-GEMM
    float* yb   = (float*)(smem + 16384);  // 32 KB overlay (Sbf + pad) for OUT result

    const int tid=threadIdx.x, lane=tid&63, w=tid>>6;
    const int l15=lane&15, lh=lane>>4, lj=lh<<2;
    const long n0=(long)blockIdx.x*64;

    if (tid < 64) degs[tid] = hist[n0+tid];
    for (int t=tid;t<1024;t+=256){
        int e=t>>4,c8=t&15;
        long n = n0+e; if (n >= NN) n = NN-1;
        ((short8*)a1)[C16(e,c8)]  = ((const short8*)(qfb+n*128))[c8];
        ((short8*)Sbf)[C16(e,c8)] = *(const short8*)(knvp + n*512 + 384 + c8*8);
    }
    __syncthreads();                                       // B1

    const short8* a1v = (const short8*)a1;
    const short8* sfv = (const short8*)Sbf;
    const int col0 = (2*w)*16 + l15;
    const int col1 = (2*w+1)*16 + l15;

    // ---- cross GEMMs: frag-ordered weight loads (contiguous 1KB/wave) ----
    f32x4 tt[2][4], cr[2][4];
    #pragma unroll
    for (int ci=0;ci<2;ci++)
        #pragma unroll
        for (int rt=0;rt<4;rt++){ tt[ci][rt]=Z4; cr[ci][rt]=Z4; }

    #pragma unroll 1
    for (int kk=0; kk<4; kk++){
        #pragma unroll
        for (int ci=0; ci<2; ci++){
            const int ctt = 2*w + ci;
            const int col = ci ? col1 : col0;
            const long fb = (long)(kk*8 + ctt)*8;   // 8 ks-blocks: [0..3]=a-half, [4..7]=b-half
            short8 Pa[4], Pj[4];
            #pragma unroll
            for (int ks=0;ks<4;ks++){
                Pa[ks] = *(const short8*)(wCi + (fb + ks)*512 + lane*8);
                Pj[ks] = *(const short8*)(wCj + (fb + ks)*512 + lane*8);
            }
            f32x4 aiA[4], ajA[4];
            #pragma unroll
            for (int rt=0;rt<4;rt++){
                f32x4 ai=Z4, aj=Z4;
                #pragma unroll
                for (int ks=0;ks<4;ks++){
                    short8 fq = a1v[C16(rt*16+l15,(ks<<2)+lh)];
                    ai = mfma16(fq, Pa[ks], ai);
                    aj = mfma16(fq, Pj[ks], aj);
                }
                aiA[rt]=ai; ajA[rt]=aj;
            }
            short8 Qa[4], Qj[4];
            #pragma unroll
            for (int ks=0;ks<4;ks++){
                Qa[ks] = *(const short8*)(wCi + (fb + 4 + ks)*512 + lane*8);
                Qj[ks] = *(const short8*)(wCj + (fb + 4 + ks)*512 + lane*8);
            }
            float ci_=bci[kk*128+col], cj_=bcj[kk*128+col];
            #pragma unroll
            for (int rt=0;rt<4;rt++){
                f32x4 sbi=Z4, sbj=Z4;
                #pragma unroll
                for (int ks=0;ks<4;ks++){
                    short8 fs = sfv[C16(rt*16+l15,(ks<<2)+lh)];
                    sbi = mfma16(fs, Qa[ks], sbi);
                    sbj = mfma16(fs, Qj[ks], sbj);
                }
                #pragma unroll
                for (int j=0;j<4;j++){
                    float AI = aiA[rt][j]+ci_, AJ = ajA[rt][j]+cj_;
                    tt[ci][rt][j] += AI*AJ;
                    cr[ci][rt][j] += AI*sbj[j] + sbi[j]*AJ;
                }
            }
        }
    }
    __syncthreads();                                       // B2 (a1/Sbf reads done)

    // ---- msum (AQM/PB direct from global bf16; clamped rows), write msgb over a1 ----
    short* msgb = a1;
    #pragma unroll
    for (int ci=0;ci<2;ci++){
        const int col = ci ? col1 : col0;
        #pragma unroll
        for (int rt=0;rt<4;rt++){
            #pragma unroll
            for (int j=0;j<4;j++){
                int row = rt*16+lj+j;
                long nc = n0+row; if (nc >= NN) nc = NN-1;
                float ms = bf2f(aqmpb[nc*256 + col])
                         + 0.25f*((float)degs[row]*tt[ci][rt][j] + cr[ci][rt][j]
                                  + bf2f(aqmpb[nc*256 + 128 + col]));
                msgb[(C16(row, col>>3)<<3) + (col&7)] = f2bf(ms);
            }
        }
    }
    __syncthreads();                                       // B3

    // ---- OUT GEMM -> yb (overlays Sbf+pad) ----
    const short8* mbv = (const short8*)msgb;
    #pragma unroll
    for (int ci=0; ci<2; ci++){
        const int ctt = 2*w + ci;
        const int col = ci ? col1 : col0;
        short8 bo[4];
        #pragma unroll
        for (int ks=0;ks<4;ks++)
            bo[ks] = *(const short8*)(wO + ((long)(ctt*4+ks))*512 + lane*8);
        float ob = out_b[col];
        #pragma unroll
        for (int rt=0;rt<4;rt++){
            f32x4 ao=Z4;
            #pragma unroll
            for (int ks=0;ks<4;ks++)
                ao = mfma16(mbv[C16(rt*16+l15,(ks<<2)+lh)], bo[ks], ao);
            #pragma unroll
            for (int j=0;j<4;j++){
                int row = rt*16+lj+j;
                yb[(row<<7) + (col ^ (row&31))] = ao[j] + (float)degs[row]*ob;
            }
        }
    }
    __syncthreads();                                       // B4

    // ---- LN + exact gelu (two 32-row halves) ----
    #pragma unroll
    for (int half=0; half<2; half++){
        const int row = half*32 + (tid>>3), cs = tid&7;
        const long n = n0+row;
        float v[16]; float sum=0.f, sq=0.f;
        #pragma unroll
        for (int i=0;i<16;i++){
            v[i]=yb[(row<<7)+((cs*16+i)^(row&31))];
            sum+=v[i]; sq+=v[i]*v[i];
        }
        #pragma unroll
        for (int m=1;m<8;m<<=1){ sum+=__shfl_xor(sum,m); sq+=__shfl_xor(sq,m); }
        float mean=sum*(1.0f/128.0f);
        float rstd=rsqrtf(sq*(1.0f/128.0f)-mean*mean+1e-5f);
        if (n < NN){
            float o[16];
            #pragma unroll
            for (int i=0;i<16;i++){
                int c=cs*16+i;
                float y=(v[i]-mean)*rstd*g2[c]+b2[c];
                o[i]=0.5f*y*(1.0f+erff(y*0.70710678118f));
            }
            float* dst = outp + n*128 + cs*16;
            #pragma unroll
            for (int i=0;i<4;i++)
                ((float4*)dst)[i] = (float4){o[i*4],o[i*4+1],o[i*4+2],o[i*4+3]};
        }
    }
}

extern "C" void kernel_launch(void* const* d_in, const int* in_sizes, int n_in,
                              void* d_out, int out_size, void* d_ws, size_t ws_size,
                              hipStream_t stream)
{
    const float* x      = (const float*)d_in[0];
    const int*   eidx   = (const int*)  d_in[1];
    const float* sp_w   = (const float*)d_in[2];
    const float* sp_b   = (const float*)d_in[3];
    const float* ln1_g  = (const float*)d_in[4];
    const float* ln1_b  = (const float*)d_in[5];
    const float* pg     = (const float*)d_in[6];
    const float* amp_w  = (const float*)d_in[7];
    const float* amp_b  = (const float*)d_in[8];
    const float* ph_w   = (const float*)d_in[9];
    const float* ph_b   = (const float*)d_in[10];
    const float* ent_w  = (const float*)d_in[11];
    const float* ent_b  = (const float*)d_in[12];
    const float* q_w    = (const float*)d_in[13];
    const float* q_b    = (const float*)d_in[14];
    const float* k_w    = (const float*)d_in[15];
    const float* k_b    = (const float*)d_in[16];
    const float* v_w    = (const float*)d_in[17];
    const float* v_b    = (const float*)d_in[18];
    const float* meas_w = (const float*)d_in[19];
    const float* meas_b = (const float*)d_in[20];
    const float* out_w  = (const float*)d_in[21];
    const float* out_b  = (const float*)d_in[22];
    const float* ln2_g  = (const float*)d_in[23];
    const float* ln2_b  = (const float*)d_in[24];

    char* wsb = (char*)d_ws;
    short* qfb  = (short*)(wsb + 0);               //  25,608,192
    short* knvp = (short*)(wsb + 25608192);        // 102,432,768
    short* wAll = (short*)(wsb + 128040960);       //     180,224
    short* wCi  = (short*)(wsb + 128221184);       //     262,144
    short* wCj  = (short*)(wsb + 128483328);       //     262,144
    float* bci  = (float*)(wsb + 128745472);       //       2,048
    float* bcj  = (float*)(wsb + 128747520);       //       2,048
    int* hist   = (int*)(wsb + 128749568);         //     401,408
    int* cnt    = (int*)(wsb + 129150976);         //     401,408
    int* scanv  = (int*)(wsb + 129552384);         //     401,408
    int* bsum   = (int*)(wsb + 129953792);         //       1,024
    int* boff   = (int*)(wsb + 129954816);         //       1,024
    int* sSrc   = (int*)(wsb + 129955840);         //   2,000,000 -> 131,955,840 total

    if (ws_size < 132000000ull) return;            // diagnostic guard

    short* wQ  = wAll;
    short* wK  = wAll + 16384;
    short* wV  = wAll + 32768;
    short* wO  = wAll + 49152;
    short* wSP = wAll + 65536;
    short* wA  = wAll + 81920;
    short* wP  = wAll + 86016;

    short* aqmpb = (short*)d_out;                  // bf16 AQM|PB packed in d_out

    hipMemsetAsync(hist, 0, 401408, stream);
    hipMemsetAsync(cnt,  0, 401408, stream);

    prep_kernel<<<352, 256, 0, stream>>>(q_w, k_w, v_w, out_w, sp_w, amp_w, ph_w, wAll);
    combine_kernel<<<512, 256, 0, stream>>>(ent_w, meas_w, wCi, wCj);
    combine_bias_kernel<<<4, 256, 0, stream>>>(meas_w, ent_b, meas_b, bci, bcj);
    node_kernel<<<NNB, 512, 0, stream>>>(x, wSP, sp_b, ln1_g, ln1_b, pg,
                                         wA, amp_b, wP, ph_b, qfb);
    hist_kernel<<<(EE+255)/256, 256, 0, stream>>>(eidx, hist);
    scanA_kernel<<<196, 512, 0, stream>>>(hist, scanv, bsum);
    scanB_kernel<<<1, 256, 0, stream>>>(bsum, boff);
    scatter_kernel<<<(EE+255)/256, 256, 0, stream>>>(eidx, scanv, boff, cnt, sSrc);
    qkvpb_kernel<<<NNB, 512, 0, stream>>>(qfb, wK, k_b, wV, v_b, wQ, q_b,
                                          wCi, wCj, knvp);
    walk_kernel<<<NWB, 256, 0, stream>>>(qfb, knvp, sSrc, hist, scanv, boff, aqmpb);
    final_kernel<<<NFB2, 256, 0, stream>>>(qfb, knvp, hist,
                                           wCi, wCj, bci, bcj, wO, out_b,
                                           ln2_g, ln2_b, aqmpb, (float*)d_out);
}

// Round 24
// 442.577 us; speedup vs baseline: 1.4064x; 1.0001x over previous
//
#include <hip/hip_runtime.h>
#include <math.h>

#define NN 100000
#define EE 500000
#define NNB  1563            // 64-node blocks (qkvpb/node)
#define NFB2 1563            // final: 64 nodes/block
#define NWB  25000           // walk: 4 nodes/block

typedef __attribute__((ext_vector_type(8))) short short8;
typedef __attribute__((ext_vector_type(4))) float f32x4;
#define Z4 (f32x4){0,0,0,0}

#define C16(row, ch) (((row)<<4) + ((ch) ^ ((row)&7)))
#define E16(row, col) ((C16((row),(col)>>3)<<3) + ((col)&7))

__device__ __forceinline__ f32x4 mfma16(short8 a, short8 b, f32x4 c){
    return __builtin_amdgcn_mfma_f32_16x16x32_bf16(a, b, c, 0, 0, 0);
}
__device__ __forceinline__ short f2bf(float f){
    union { float f; unsigned u; } v; v.f = f;
    unsigned r = v.u + 0x7fffu + ((v.u >> 16) & 1u);
    return (short)(r >> 16);
}
__device__ __forceinline__ float bf2f(short s){
    union { unsigned u; float f; } v; v.u = ((unsigned)(unsigned short)s) << 16;
    return v.f;
}
__device__ __forceinline__ short8 bfrag(const short* __restrict__ W, int K, int ct, int ks, int lane){
    return *(const short8*)(W + (long)(ct*16 + (lane&15))*K + ks*32 + (lane>>4)*8);
}
// fragment-order index for a [128][128] weight: load = 1KB contiguous per wave
__device__ __forceinline__ int fragmap(int o, int k){
    return (((o>>4)*4 + (k>>5))*64 + (((k>>3)&3)*16 + (o&15)))*8 + (k&7);
}

// ---------------- prep: bf16 weights (q/k/v/out frag-ordered; sp/amp/ph linear) ----------------
__global__ __launch_bounds__(256) void prep_kernel(
    const float* __restrict__ q_w, const float* __restrict__ k_w,
    const float* __restrict__ v_w, const float* __restrict__ out_w,
    const float* __restrict__ sp_w, const float* __restrict__ amp_w,
    const float* __restrict__ ph_w, short* __restrict__ dst)
{
    int i = blockIdx.x*256 + threadIdx.x;   // 90112
    if (i >= 90112) return;
    float v; int base = -1, loc = 0;
    if      (i < 16384){ v = q_w[i];         base = 0;     loc = i; }
    else if (i < 32768){ v = k_w[i-16384];   base = 16384; loc = i-16384; }
    else if (i < 49152){ v = v_w[i-32768];   base = 32768; loc = i-32768; }
    else if (i < 65536){ v = out_w[i-49152]; base = 49152; loc = i-49152; }
    else if (i < 81920) v = sp_w[i-65536];
    else if (i < 86016) v = amp_w[i-81920];
    else                v = ph_w[i-86016];
    if (base >= 0) dst[base + fragmap(loc>>7, loc&127)] = f2bf(v);
    else           dst[i] = f2bf(v);
}

// ---------------- combined weights (frag-ordered) ----------------
__global__ __launch_bounds__(256) void combine_kernel(
    const float* __restrict__ ent_w, const float* __restrict__ meas_w,
    short* __restrict__ wCi, short* __restrict__ wCj)
{
    const int b = blockIdx.x;          // 512
    const int kk = b >> 7, half = (b >> 6) & 1, ot = (b >> 3) & 7, ct = b & 7;
    const int tid = threadIdx.x;
    const int o = ot*16 + (tid >> 4);
    const int c = ct*32 + (tid & 15)*2;
    const float* mrow  = meas_w + ((long)(kk*128 + o) << 7);
    const float* wbase = ent_w + (long)(half*128)*256 + c;
    float a0 = 0.f, a1 = 0.f;
    #pragma unroll 8
    for (int k = 0; k < 128; k++){
        float m = mrow[k];
        float2 wv = *(const float2*)(wbase + (long)k*256);
        a0 = fmaf(m, wv.x, a0);
        a1 = fmaf(m, wv.y, a1);
    }
    const int ct_o = o>>4, l15o = o&15;
    const int halfc = c>>7, cr = c&127;
    const int ksn = cr>>5, lhn = (cr>>3)&3, iin = cr&7;
    const long idx = ((((long)(kk*8 + ct_o)*2 + halfc)*4 + ksn)*64 + (lhn*16 + l15o))*8 + iin;
    short* dst = (half ? wCj : wCi) + idx;
    dst[0] = f2bf(a0); dst[1] = f2bf(a1);
}
__global__ __launch_bounds__(256) void combine_bias_kernel(
    const float* __restrict__ meas_w, const float* __restrict__ ent_b,
    const float* __restrict__ meas_b,
    float* __restrict__ bci, float* __restrict__ bcj)
{
    int id = blockIdx.x*256 + threadIdx.x;  // 1024
    int kk = id >> 8, half = (id >> 7) & 1, o = id & 127;
    const float* mrow = meas_w + ((long)(kk*128 + o) << 7);
    const float* eb = ent_b + half*128;
    float a = meas_b[kk*128 + o];
    #pragma unroll 8
    for (int k = 0; k < 128; k++) a = fmaf(mrow[k], eb[k], a);
    (half ? bcj : bci)[kk*128 + o] = a;
}

// ---------------- counting sort by tgt (src list only) ----------------
__global__ __launch_bounds__(256) void hist_kernel(const int* __restrict__ eidx, int* __restrict__ hist){
    int i = blockIdx.x*256 + threadIdx.x;
    if (i < EE) atomicAdd(&hist[eidx[EE+i]], 1);
}
__global__ __launch_bounds__(512) void scanA_kernel(const int* __restrict__ hist,
                                                    int* __restrict__ scanv, int* __restrict__ bsum){
    __shared__ int s[512];
    const int tid = threadIdx.x;
    const int i = blockIdx.x*512 + tid;
    int v = hist[i];
    s[tid] = v;
    __syncthreads();
    #pragma unroll
    for (int d=1; d<512; d<<=1){
        int t = (tid>=d) ? s[tid-d] : 0;
        __syncthreads();
        s[tid] += t;
        __syncthreads();
    }
    scanv[i] = s[tid] - v;
    if (tid==511) bsum[blockIdx.x] = s[511];
}
__global__ __launch_bounds__(256) void scanB_kernel(const int* __restrict__ bsum, int* __restrict__ boff){
    __shared__ int s[256];
    const int tid = threadIdx.x;
    int v = (tid<196) ? bsum[tid] : 0;
    s[tid] = v;
    __syncthreads();
    #pragma unroll
    for (int d=1; d<256; d<<=1){
        int t = (tid>=d) ? s[tid-d] : 0;
        __syncthreads();
        s[tid] += t;
        __syncthreads();
    }
    if (tid<196) boff[tid] = s[tid] - v;
}
__global__ __launch_bounds__(256) void scatter_kernel(const int* __restrict__ eidx,
    const int* __restrict__ scanv, const int* __restrict__ boff, int* __restrict__ cnt,
    int* __restrict__ sSrc)
{
    int i = blockIdx.x*256 + threadIdx.x;
    if (i >= EE) return;
    int t = eidx[EE+i], sv = eidx[i];
    int r = atomicAdd(&cnt[t], 1);
    int pos = scanv[t] + boff[t>>9] + r;
    sSrc[pos] = sv;
}

// ---------------- Stage 1: node prep (proven) ----------------
__global__ __launch_bounds__(512) void node_kernel(
    const float* __restrict__ x,
    const short* __restrict__ wSP, const float* __restrict__ sp_b,
    const float* __restrict__ ln1_g, const float* __restrict__ ln1_b,
    const float* __restrict__ pg,
    const short* __restrict__ wA, const float* __restrict__ amp_b,
    const short* __restrict__ wP, const float* __restrict__ ph_b,
    short* __restrict__ qfb)
{
    __shared__ short xb[64*128];
    __shared__ float yb[64*132];
    __shared__ short qsb[64*128];
    __shared__ float pgs[64];

    const int tid = threadIdx.x;
    const int lane = tid & 63;
    const int w    = tid >> 6;
    const int l15  = lane & 15;
    const int lj   = (lane >> 4) << 2;
    const int n0   = blockIdx.x * 64;

    if (tid < 64){
        float s = 0.f;
        #pragma unroll
        for (int r=0;r<8;r++) s += pg[r*64 + tid];
        pgs[tid] = s;
    }
    for (int t = tid; t < 1024; t += 512){
        int e = t >> 4, c8 = t & 15;
        int n = n0 + e; if (n >= NN) n = NN-1;
        const float4* xg = (const float4*)(x + (long)n*128 + c8*8);
        float4 a = xg[0], b = xg[1];
        short8 sv;
        sv[0]=f2bf(a.x); sv[1]=f2bf(a.y); sv[2]=f2bf(a.z); sv[3]=f2bf(a.w);
        sv[4]=f2bf(b.x); sv[5]=f2bf(b.y); sv[6]=f2bf(b.z); sv[7]=f2bf(b.w);
        ((short8*)xb)[C16(e, c8)] = sv;
    }
    __syncthreads();

    const short8* xbv = (const short8*)xb;
    const int col = (w<<4) + l15;

    {
        f32x4 acc[4];
        #pragma unroll
        for (int r=0;r<4;r++) acc[r]=Z4;
        #pragma unroll
        for (int ks=0; ks<4; ks++){
            short8 bw = bfrag(wSP,128,w,ks,lane);
            #pragma unroll
            for (int r=0;r<4;r++){
                int row = r*16+l15;
                acc[r] = mfma16(xbv[(row<<4) + (((ks<<2)+(lane>>4)) ^ (row&7))], bw, acc[r]);
            }
        }
        float bias = sp_b[col];
        #pragma unroll
        for (int r=0;r<4;r++){
            #pragma unroll
            for (int j=0;j<4;j++)
                yb[(r*16+lj+j)*132 + col] = acc[r][j] + bias;
        }
    }
    __syncthreads();

    {
        const int row = tid >> 3, cs = tid & 7;
        float v[16];
        float s = 0.f, sq = 0.f;
        #pragma unroll
        for (int i=0;i<16;i++){
            v[i] = yb[row*132 + cs*16 + i];
            s += v[i]; sq += v[i]*v[i];
        }
        #pragma unroll
        for (int m=1;m<8;m<<=1){ s += __shfl_xor(s,m); sq += __shfl_xor(sq,m); }
        float mean = s*(1.0f/128.0f);
        float rstd = rsqrtf(sq*(1.0f/128.0f) - mean*mean + 1e-5f);
        short8 s0, s1;
        #pragma unroll
        for (int i=0;i<16;i++){
            int c = cs*16 + i;
            float q = tanhf((v[i]-mean)*rstd*ln1_g[c] + ln1_b[c]);
            if (i<8) s0[i] = f2bf(q); else s1[i-8] = f2bf(q);
        }
        ((short8*)qsb)[C16(row, cs*2  )] = s0;
        ((short8*)qsb)[C16(row, cs*2+1)] = s1;
    }
    __syncthreads();

    {
        const short8* qv = (const short8*)qsb;
        const int isPh = w >> 2;
        const int ct   = w & 3;
        f32x4 a4[4];
        #pragma unroll
        for (int r=0;r<4;r++) a4[r]=Z4;
        #pragma unroll
        for (int ks=0; ks<2; ks++){
            short8 bw = bfrag(isPh ? wP : wA, 64, ct, ks, lane);
            #pragma unroll
            for (int r=0;r<4;r++){
                int row = r*16+l15;
                int ch = isPh*8 + (ks<<2)+(lane>>4);
                a4[r] = mfma16(qv[(row<<4) + (ch ^ (row&7))], bw, a4[r]);
            }
        }
        const int oc = ct*16 + l15;
        float bs = isPh ? ph_b[oc] : amp_b[oc];
        #pragma unroll
        for (int r=0;r<4;r++){
            #pragma unroll
            for (int j=0;j<4;j++){
                float vv = a4[r][j] + bs;
                float ov = isPh ? tanhf(vv)*3.14159265358979323846f
                                : 1.0f/(1.0f+expf(-vv));
                yb[(r*16+lj+j)*132 + isPh*64 + oc] = ov;
            }
        }
    }
    __syncthreads();

    {
        const int row = tid >> 3, cs = tid & 7;
        const int n = n0 + row;
        short8 outc, outs;
        #pragma unroll
        for (int i=0;i<8;i++){
            int c = cs*8 + i;
            float amp  = yb[row*132 + c];
            float ph   = yb[row*132 + 64 + c];
            float real = bf2f(qsb[E16(row, c)]);
            float ang  = ph + real*pgs[c];
            outc[i] = f2bf(amp * cosf(ang));
            outs[i] = f2bf(amp * sinf(ang));
        }
        if (n < NN){
            *(short8*)(qfb + (long)n*128 + cs*8)      = outc;
            *(short8*)(qfb + (long)n*128 + 64 + cs*8) = outs;
        }
    }
}

// ---------------- node GEMMs -> packed knvp[n][512] = kn | vn | pb | qn ----------------
__global__ __launch_bounds__(512) void qkvpb_kernel(
    const short* __restrict__ qfb,
    const short* __restrict__ wK, const float* __restrict__ k_b,
    const short* __restrict__ wV, const float* __restrict__ v_b,
    const short* __restrict__ wQ, const float* __restrict__ q_b,
    const short* __restrict__ wCi, const short* __restrict__ wCj,
    short* __restrict__ knvp)
{
    __shared__ short a1[64*128];
    const int tid=threadIdx.x, lane=tid&63, w=tid>>6;
    const int l15=lane&15, lh=lane>>4, lj=lh<<2;
    const long n0=(long)blockIdx.x*64;
    for (int t=tid;t<1024;t+=512){
        int e=t>>4,c8=t&15;
        ((short8*)a1)[C16(e,c8)] = ((const short8*)(qfb+(n0+e)*128))[c8];
    }
    __syncthreads();
    short8 A[4][4];
    #pragma unroll
    for (int rt=0;rt<4;rt++)
        #pragma unroll
        for (int ks=0;ks<4;ks++)
            A[rt][ks] = ((const short8*)a1)[C16(rt*16+l15, (ks<<2)+lh)];
    const int col = (w<<4)+l15;

    // K (frag-ordered loads)
    {
        f32x4 acc[4];
        #pragma unroll
        for (int rt=0;rt<4;rt++) acc[rt]=Z4;
        #pragma unroll
        for (int ks=0;ks<4;ks++){
            short8 b = *(const short8*)(wK + ((w*4+ks)*64 + lane)*8);
            #pragma unroll
            for (int rt=0;rt<4;rt++) acc[rt]=mfma16(A[rt][ks],b,acc[rt]);
        }
        float bias=k_b[col];
        #pragma unroll
        for (int rt=0;rt<4;rt++)
            #pragma unroll
            for (int j=0;j<4;j++)
                knvp[(n0+rt*16+lj+j)*512 + col]=f2bf(acc[rt][j]+bias);
    }
    // V
    {
        f32x4 acc[4];
        #pragma unroll
        for (int rt=0;rt<4;rt++) acc[rt]=Z4;
        #pragma unroll
        for (int ks=0;ks<4;ks++){
            short8 b = *(const short8*)(wV + ((w*4+ks)*64 + lane)*8);
            #pragma unroll
            for (int rt=0;rt<4;rt++) acc[rt]=mfma16(A[rt][ks],b,acc[rt]);
        }
        float bias=v_b[col];
        #pragma unroll
        for (int rt=0;rt<4;rt++)
            #pragma unroll
            for (int j=0;j<4;j++)
                knvp[(n0+rt*16+lj+j)*512 + 128 + col]=f2bf(acc[rt][j]+bias);
    }
    // Q -> slot 384
    {
        f32x4 acc[4];
        #pragma unroll
        for (int rt=0;rt<4;rt++) acc[rt]=Z4;
        #pragma unroll
        for (int ks=0;ks<4;ks++){
            short8 b = *(const short8*)(wQ + ((w*4+ks)*64 + lane)*8);
            #pragma unroll
            for (int rt=0;rt<4;rt++) acc[rt]=mfma16(A[rt][ks],b,acc[rt]);
        }
        float bias=q_b[col];
        #pragma unroll
        for (int rt=0;rt<4;rt++)
            #pragma unroll
            for (int j=0;j<4;j++)
                knvp[(n0+rt*16+lj+j)*512 + 384 + col]=f2bf(acc[rt][j]+bias);
    }
    // PB = sum_kk Bi ⊙ Bj (b-halves, frag-ordered)
    {
        f32x4 pbacc[4];
        #pragma unroll
        for (int rt=0;rt<4;rt++) pbacc[rt]=Z4;
        #pragma unroll 1
        for (int kk=0;kk<4;kk++){
            short8 bi[4], bj[4];
            #pragma unroll
            for (int ks=0;ks<4;ks++){
                long fi = (((long)(kk*8 + w)*2 + 1)*4 + ks)*512 + lane*8;
                bi[ks] = *(const short8*)(wCi + fi);
                bj[ks] = *(const short8*)(wCj + fi);
            }
            #pragma unroll
            for (int rt=0;rt<4;rt++){
                f32x4 ai=Z4, aj=Z4;
                #pragma unroll
                for (int ks=0;ks<4;ks++){
                    ai = mfma16(A[rt][ks], bi[ks], ai);
                    aj = mfma16(A[rt][ks], bj[ks], aj);
                }
                #pragma unroll
                for (int j=0;j<4;j++) pbacc[rt][j] += ai[j]*aj[j];
            }
        }
        #pragma unroll
        for (int rt=0;rt<4;rt++)
            #pragma unroll
            for (int j=0;j<4;j++)
                knvp[(n0+rt*16+lj+j)*512 + 256 + col]=f2bf(pbacc[rt][j]);
    }
}

// ---------------- walk: 1 node/wave, ZERO LDS ----------------
__global__ __launch_bounds__(256) void walk_kernel(
    const short* __restrict__ qfb, short* __restrict__ knvp,
    const int* __restrict__ sSrc, const int* __restrict__ hist,
    const int* __restrict__ scanv, const int* __restrict__ boff,
    short* __restrict__ aqmpb)
{
    const int tid=threadIdx.x, lane=tid&63, w=tid>>6;
    const int n = blockIdx.x*4 + w;
    const int g = lane >> 4;
    const int cl = (lane & 15) * 8;
    const float sc = 0.17677669529663688f;

    const int rp0 = scanv[n] + boff[n>>9];
    const int dg  = hist[n];

    float q8[8];
    {
        short8 qv = *(const short8*)(knvp + (long)n*512 + 384 + cl);
        #pragma unroll
        for (int i=0;i<8;i++) q8[i]=bf2f(qv[i]);
    }
    float aq[8], s[8], p[8];
    #pragma unroll
    for (int i=0;i<8;i++){ aq[i]=0.f; s[i]=0.f; p[i]=0.f; }

    bool vCur = (g < dg);
    int  sCur = vCur ? sSrc[rp0+g] : 0;
    const short* bCur = knvp + (long)sCur*512;
    short8 k8 = *(const short8*)(bCur + cl);
    short8 v8 = *(const short8*)(bCur + 128 + cl);
    short8 p8 = *(const short8*)(bCur + 256 + cl);
    short8 f8 = *(const short8*)(qfb + (long)sCur*128 + cl);

    #pragma unroll 1
    for (int e=0; e<dg; e+=4){
        const int en = e + 4 + g;
        const bool vN = (en < dg);
        const int  sN = vN ? sSrc[rp0+en] : 0;
        const short* bN = knvp + (long)sN*512;
        short8 kN = *(const short8*)(bN + cl);
        short8 vN8= *(const short8*)(bN + 128 + cl);
        short8 pN = *(const short8*)(bN + 256 + cl);
        short8 fN = *(const short8*)(qfb + (long)sN*128 + cl);

        float d = 0.f;
        #pragma unroll
        for (int i=0;i<8;i++) d += q8[i]*bf2f(k8[i]);
        d += __shfl_xor(d,1); d += __shfl_xor(d,2);
        d *= sc;
        float mx = fmaxf(d, __shfl_xor(d,4));
        mx = fmaxf(mx, __shfl_xor(mx,8));
        float eh = expf(d - mx);
        float den = eh;
        den += __shfl_xor(den,4); den += __shfl_xor(den,8);
        float wgt = vCur ? (eh/den) : 0.f;
        float mv  = vCur ? 1.f : 0.f;
        #pragma unroll
        for (int i=0;i<8;i++){
            aq[i] += wgt * bf2f(v8[i]);
            s[i]  += mv  * bf2f(f8[i]);
            p[i]  += mv  * bf2f(p8[i]);
        }
        k8=kN; v8=vN8; p8=pN; f8=fN; vCur=vN;
    }
    #pragma unroll
    for (int i=0;i<8;i++){
        aq[i] += __shfl_xor(aq[i],16); aq[i] += __shfl_xor(aq[i],32);
        s[i]  += __shfl_xor(s[i],16);  s[i]  += __shfl_xor(s[i],32);
        p[i]  += __shfl_xor(p[i],16);  p[i]  += __shfl_xor(p[i],32);
    }
    if (lane < 16){
        short8 av, pv, sv;
        #pragma unroll
        for (int i=0;i<8;i++){ av[i]=f2bf(aq[i]); pv[i]=f2bf(p[i]); sv[i]=f2bf(s[i]); }
        *(short8*)(aqmpb + (long)n*256 + cl)       = av;
        *(short8*)(aqmpb + (long)n*256 + 128 + cl) = pv;
        *(short8*)(knvp  + (long)n*512 + 384 + cl) = sv;
    }
}

// ---------------- final: 64 nodes/block; 33KB LDS (bf16 yb) ----------------
__global__ __launch_bounds__(256) void final_kernel(
    const short* __restrict__ qfb, const short* __restrict__ knvp,
    const int* __restrict__ hist,
    const short* __restrict__ wCi, const short* __restrict__ wCj,
    const float* __restrict__ bci, const float* __restrict__ bcj,
    const short* __restrict__ wO, const float* __restrict__ out_b,
    const float* __restrict__ g2, const float* __restrict__ b2,
    const short* __restrict__ aqmpb, float* __restrict__ outp)
{
    __shared__ __align__(16) char smem[32768];
    __shared__ int degs[64];
    short* a1   = (short*)smem;            // 16 KB qf tile (swz); msgb overlay
    short* Sbf  = (short*)(smem + 16384);  // 16 KB S bf16 (swz); ybh overlays after cross-GEMM
    short* ybh  = (short*)(smem + 16384);  // 16 KB bf16 OUT result (swz)

    const int tid=threadIdx.x, lane=tid&63, w=tid>>6;
    const int l15=lane&15, lh=lane>>4, lj=lh<<2;
    const long n0=(long)blockIdx.x*64;

    if (tid < 64) degs[tid] = hist[n0+tid];
    for (int t=tid;t<1024;t+=256){
        int e=t>>4,c8=t&15;
        long n = n0+e; if (n >= NN) n = NN-1;
        ((short8*)a1)[C16(e,c8)]  = ((const short8*)(qfb+n*128))[c8];
        ((short8*)Sbf)[C16(e,c8)] = *(const short8*)(knvp + n*512 + 384 + c8*8);
    }
    __syncthreads();                                       // B1

    const short8* a1v = (const short8*)a1;
    const short8* sfv = (const short8*)Sbf;
    const int col0 = (2*w)*16 + l15;
    const int col1 = (2*w+1)*16 + l15;

    // ---- cross GEMMs: frag-ordered weight loads (contiguous 1KB/wave) ----
    f32x4 tt[2][4], cr[2][4];
    #pragma unroll
    for (int ci=0;ci<2;ci++)
        #pragma unroll
        for (int rt=0;rt<4;rt++){ tt[ci][rt]=Z4; cr[ci][rt]=Z4; }

    #pragma unroll 1
    for (int kk=0; kk<4; kk++){
        #pragma unroll
        for (int ci=0; ci<2; ci++){
            const int ctt = 2*w + ci;
            const int col = ci ? col1 : col0;
            const long fb = (long)(kk*8 + ctt)*8;   // 8 ks-blocks: [0..3]=a-half, [4..7]=b-half
            short8 Pa[4], Pj[4];
            #pragma unroll
            for (int ks=0;ks<4;ks++){
                Pa[ks] = *(const short8*)(wCi + (fb + ks)*512 + lane*8);
                Pj[ks] = *(const short8*)(wCj + (fb + ks)*512 + lane*8);
            }
            f32x4 aiA[4], ajA[4];
            #pragma unroll
            for (int rt=0;rt<4;rt++){
                f32x4 ai=Z4, aj=Z4;
                #pragma unroll
                for (int ks=0;ks<4;ks++){
                    short8 fq = a1v[C16(rt*16+l15,(ks<<2)+lh)];
                    ai = mfma16(fq, Pa[ks], ai);
                    aj = mfma16(fq, Pj[ks], aj);
                }
                aiA[rt]=ai; ajA[rt]=aj;
            }
            short8 Qa[4], Qj[4];
            #pragma unroll
            for (int ks=0;ks<4;ks++){
                Qa[ks] = *(const short8*)(wCi + (fb + 4 + ks)*512 + lane*8);
                Qj[ks] = *(const short8*)(wCj + (fb + 4 + ks)*512 + lane*8);
            }
            float ci_=bci[kk*128+col], cj_=bcj[kk*128+col];
            #pragma unroll
            for (int rt=0;rt<4;rt++){
                f32x4 sbi=Z4, sbj=Z4;
                #pragma unroll
                for (int ks=0;ks<4;ks++){
                    short8 fs = sfv[C16(rt*16+l15,(ks<<2)+lh)];
                    sbi = mfma16(fs, Qa[ks], sbi);
                    sbj = mfma16(fs, Qj[ks], sbj);
                }
                #pragma unroll
                for (int j=0;j<4;j++){
                    float AI = aiA[rt][j]+ci_, AJ = ajA[rt][j]+cj_;
                    tt[ci][rt][j] += AI*AJ;
                    cr[ci][rt][j] += AI*sbj[j] + sbi[j]*AJ;
                }
            }
        }
    }
    __syncthreads();                                       // B2 (a1/Sbf reads done)

    // ---- msum (AQM/PB direct from global bf16; clamped rows), write msgb over a1 ----
    short* msgb = a1;
    #pragma unroll
    for (int ci=0;ci<2;ci++){
        const int col = ci ? col1 : col0;
        #pragma unroll
        for (int rt=0;rt<4;rt++){
            #pragma unroll
            for (int j=0;j<4;j++){
                int row = rt*16+lj+j;
                long nc = n0+row; if (nc >= NN) nc = NN-1;
                float ms = bf2f(aqmpb[nc*256 + col])
                         + 0.25f*((float)degs[row]*tt[ci][rt][j] + cr[ci][rt][j]
                                  + bf2f(aqmpb[nc*256 + 128 + col]));
                msgb[(C16(row, col>>3)<<3) + (col&7)] = f2bf(ms);
            }
        }
    }
    __syncthreads();                                       // B3

    // ---- OUT GEMM -> ybh bf16 (overlays Sbf) ----
    const short8* mbv = (const short8*)msgb;
    #pragma unroll
    for (int ci=0; ci<2; ci++){
        const int ctt = 2*w + ci;
        const int col = ci ? col1 : col0;
        short8 bo[4];
        #pragma unroll
        for (int ks=0;ks<4;ks++)
            bo[ks] = *(const short8*)(wO + ((long)(ctt*4+ks))*512 + lane*8);
        float ob = out_b[col];
        #pragma unroll
        for (int rt=0;rt<4;rt++){
            f32x4 ao=Z4;
            #pragma unroll
            for (int ks=0;ks<4;ks++)
                ao = mfma16(mbv[C16(rt*16+l15,(ks<<2)+lh)], bo[ks], ao);
            #pragma unroll
            for (int j=0;j<4;j++){
                int row = rt*16+lj+j;
                ybh[(C16(row, col>>3)<<3) + (col&7)] = f2bf(ao[j] + (float)degs[row]*ob);
            }
        }
    }
    __syncthreads();                                       // B4

    // ---- LN + exact gelu (two 32-row halves; reads bf16 ybh) ----
    const short8* ybv = (const short8*)ybh;
    #pragma unroll
    for (int half=0; half<2; half++){
        const int row = half*32 + (tid>>3), cs = tid&7;
        const long n = n0+row;
        float v[16]; float sum=0.f, sq=0.f;
        {
            short8 c0 = ybv[C16(row, cs*2)];
            short8 c1 = ybv[C16(row, cs*2+1)];
            #pragma unroll
            for (int i=0;i<8;i++){ v[i]   = bf2f(c0[i]); }
            #pragma unroll
            for (int i=0;i<8;i++){ v[8+i] = bf2f(c1[i]); }
        }
        #pragma unroll
        for (int i=0;i<16;i++){ sum+=v[i]; sq+=v[i]*v[i]; }
        #pragma unroll
        for (int m=1;m<8;m<<=1){ sum+=__shfl_xor(sum,m); sq+=__shfl_xor(sq,m); }
        float mean=sum*(1.0f/128.0f);
        float rstd=rsqrtf(sq*(1.0f/128.0f)-mean*mean+1e-5f);
        if (n < NN){
            float o[16];
            #pragma unroll
            for (int i=0;i<16;i++){
                int c=cs*16+i;
                float y=(v[i]-mean)*rstd*g2[c]+b2[c];
                o[i]=0.5f*y*(1.0f+erff(y*0.70710678118f));
            }
            float* dst = outp + n*128 + cs*16;
            #pragma unroll
            for (int i=0;i<4;i++)
                ((float4*)dst)[i] = (float4){o[i*4],o[i*4+1],o[i*4+2],o[i*4+3]};
        }
    }
}

extern "C" void kernel_launch(void* const* d_in, const int* in_sizes, int n_in,
                              void* d_out, int out_size, void* d_ws, size_t ws_size,
                              hipStream_t stream)
{
    const float* x      = (const float*)d_in[0];
    const int*   eidx   = (const int*)  d_in[1];
    const float* sp_w   = (const float*)d_in[2];
    const float* sp_b   = (const float*)d_in[3];
    const float* ln1_g  = (const float*)d_in[4];
    const float* ln1_b  = (const float*)d_in[5];
    const float* pg     = (const float*)d_in[6];
    const float* amp_w  = (const float*)d_in[7];
    const float* amp_b  = (const float*)d_in[8];
    const float* ph_w   = (const float*)d_in[9];
    const float* ph_b   = (const float*)d_in[10];
    const float* ent_w  = (const float*)d_in[11];
    const float* ent_b  = (const float*)d_in[12];
    const float* q_w    = (const float*)d_in[13];
    const float* q_b    = (const float*)d_in[14];
    const float* k_w    = (const float*)d_in[15];
    const float* k_b    = (const float*)d_in[16];
    const float* v_w    = (const float*)d_in[17];
    const float* v_b    = (const float*)d_in[18];
    const float* meas_w = (const float*)d_in[19];
    const float* meas_b = (const float*)d_in[20];
    const float* out_w  = (const float*)d_in[21];
    const float* out_b  = (const float*)d_in[22];
    const float* ln2_g  = (const float*)d_in[23];
    const float* ln2_b  = (const float*)d_in[24];

    char* wsb = (char*)d_ws;
    short* qfb  = (short*)(wsb + 0);               //  25,608,192
    short* knvp = (short*)(wsb + 25608192);        // 102,432,768
    short* wAll = (short*)(wsb + 128040960);       //     180,224
    short* wCi  = (short*)(wsb + 128221184);       //     262,144
    short* wCj  = (short*)(wsb + 128483328);       //     262,144
    float* bci  = (float*)(wsb + 128745472);       //       2,048
    float* bcj  = (float*)(wsb + 128747520);       //       2,048
    int* hist   = (int*)(wsb + 128749568);         //     401,408
    int* cnt    = (int*)(wsb + 129150976);         //     401,408
    int* scanv  = (int*)(wsb + 129552384);         //     401,408
    int* bsum   = (int*)(wsb + 129953792);         //       1,024
    int* boff   = (int*)(wsb + 129954816);         //       1,024
    int* sSrc   = (int*)(wsb + 129955840);         //   2,000,000 -> 131,955,840 total

    if (ws_size < 132000000ull) return;            // diagnostic guard

    short* wQ  = wAll;
    short* wK  = wAll + 16384;
    short* wV  = wAll + 32768;
    short* wO  = wAll + 49152;
    short* wSP = wAll + 65536;
    short* wA  = wAll + 81920;
    short* wP  = wAll + 86016;

    short* aqmpb = (short*)d_out;                  // bf16 AQM|PB packed in d_out

    hipMemsetAsync(hist, 0, 401408, stream);
    hipMemsetAsync(cnt,  0, 401408, stream);

    prep_kernel<<<352, 256, 0, stream>>>(q_w, k_w, v_w, out_w, sp_w, amp_w, ph_w, wAll);
    combine_kernel<<<512, 256, 0, stream>>>(ent_w, meas_w, wCi, wCj);
    combine_bias_kernel<<<4, 256, 0, stream>>>(meas_w, ent_b, meas_b, bci, bcj);
    node_kernel<<<NNB, 512, 0, stream>>>(x, wSP, sp_b, ln1_g, ln1_b, pg,
                                         wA, amp_b, wP, ph_b, qfb);
    hist_kernel<<<(EE+255)/256, 256, 0, stream>>>(eidx, hist);
    scanA_kernel<<<196, 512, 0, stream>>>(hist, scanv, bsum);
    scanB_kernel<<<1, 256, 0, stream>>>(bsum, boff);
    scatter_kernel<<<(EE+255)/256, 256, 0, stream>>>(eidx, scanv, boff, cnt, sSrc);
    qkvpb_kernel<<<NNB, 512, 0, stream>>>(qfb, wK, k_b, wV, v_b, wQ, q_b,
                                          wCi, wCj, knvp);
    walk_kernel<<<NWB, 256, 0, stream>>>(qfb, knvp, sSrc, hist, scanv, boff, aqmpb);
    final_kernel<<<NFB2, 256, 0, stream>>>(qfb, knvp, hist,
                                           wCi, wCj, bci, bcj, wO, out_b,
                                           ln2_g, ln2_b, aqmpb, (float*)d_out);
}